// Round 1
// 543.753 us; speedup vs baseline: 1.0559x; 1.0559x over previous
//
#include <hip/hip_runtime.h>

typedef unsigned short u16;
typedef unsigned int u32;
typedef __attribute__((ext_vector_type(4))) float f32x4;
typedef __attribute__((ext_vector_type(8))) short short8;
typedef __attribute__((ext_vector_type(4))) unsigned int u32x4;

#define DEV __device__ __forceinline__

DEV float bf2f(u16 u){ union{u32 i; float f;} x; x.i = ((u32)u)<<16; return x.f; }
DEV u16 f2bf(float f){ union{u32 i; float f;} x; x.f = f; u32 r = x.i + 0x7fffu + ((x.i>>16)&1u); return (u16)(r>>16); }

union U8 { u16 u[8]; short8 s; };

// async global -> LDS, 16B per lane (dest must be wave-uniform base + lane*16; ours is tid*16)
DEV void gl16(const u16* g, u16* l){
  __builtin_amdgcn_global_load_lds(
      (const __attribute__((address_space(1))) u32*)g,
      (__attribute__((address_space(3))) u32*)l, 16, 0, 0);
}

// =================== split x into hi/lo bf16 planes ===================
__global__ __launch_bounds__(256) void splitx_kernel(const float* __restrict__ x,
    u16* __restrict__ xh, u16* __restrict__ xl)
{
  size_t base = ((size_t)blockIdx.x*256 + threadIdx.x) * 8;   // 16384*1024/8 threads
  f32x4 a = *(const f32x4*)(x + base), b = *(const f32x4*)(x + base + 4);
  U8 h, l;
  #pragma unroll
  for (int e=0;e<4;e++){
    u16 hh = f2bf(a[e]); h.u[e]   = hh; l.u[e]   = f2bf(a[e] - bf2f(hh));
    u16 gg = f2bf(b[e]); h.u[4+e] = gg; l.u[4+e] = f2bf(b[e] - bf2f(gg));
  }
  *(short8*)(xh + base) = h.s;
  *(short8*)(xl + base) = l.s;
}

// =================== weight concat / transpose -> hi/lo bf16 planes ===================
// Wh/Wl [896][1024]: rows 0-447 Wskew^T, 448-575 Wk^T, 576-703 Wv^T, 704-831 Wq^T, 832-847 Wbeta^T, 848-895 zero
__global__ __launch_bounds__(256) void concat_kernel(
    const float* __restrict__ Wskew, const float* __restrict__ Wk, const float* __restrict__ Wv,
    const float* __restrict__ Wq, const float* __restrict__ Wbeta, const float* __restrict__ Wo,
    u16* __restrict__ Wh, u16* __restrict__ Wl, u16* __restrict__ WoT)
{
  int idx = blockIdx.x*256 + threadIdx.x;
  if (idx < 896*1024){
    int n = idx >> 10, kk = idx & 1023;
    float v;
    if (n < 448)      v = Wskew[kk*448 + n];
    else if (n < 576) v = Wk[kk*128 + (n-448)];
    else if (n < 704) v = Wv[kk*128 + (n-576)];
    else if (n < 832) v = Wq[kk*128 + (n-704)];
    else if (n < 848) v = Wbeta[kk*16 + (n-832)];
    else              v = 0.f;
    u16 h = f2bf(v);
    Wh[idx] = h;
    Wl[idx] = f2bf(v - bf2f(h));
  } else {
    int r = idx - 896*1024;
    int n = r >> 7, kk = r & 127;
    WoT[r] = f2bf(Wo[kk*1024 + n]);
  }
}

// =================== proj GEMM: global_load_lds staging, XOR-swizzled LDS, mixed precision ===================
// blockIdx.y < 4 (cols 0-511, skew + first k heads): 3-pass split-bf16 (Ah*Bh + Ah*Bl + Al*Bh).
// blockIdx.y >= 4 (cols 512-895, k/v/q/beta): 1-pass bf16 — errors inject additively (no rotation
// compounding) and are attenuated ~0.23x through W_o; adds ~1e-3 to output absmax.
// Swizzle (rule #21: linear gload_lds dest + pre-swizzled SOURCE + swizzled READ):
//   LDS[r][c] = global[r][(c ^ f(r))*8 ..], f(r) = (r&3)^((r>>2)&3)  -> per-thread constant both sides.
__global__ __launch_bounds__(256) void gemm_proj_kernel(
    const u16* __restrict__ Ah, const u16* __restrict__ Al,
    const u16* __restrict__ Bh, const u16* __restrict__ Bl,
    float* __restrict__ C, const float* __restrict__ bias)
{
  __shared__ u16 lAh[128*32]; __shared__ u16 lBh[128*32];
  __shared__ u16 lAl[128*32]; __shared__ u16 lBl[128*32];
  const int tid = threadIdx.x;
  const int wave = tid >> 6;
  const int lane = tid & 63;
  const int quad = lane >> 4, l15 = lane & 15;
  const int m0 = blockIdx.x * 128, n0 = blockIdx.y * 128;
  const bool full = (blockIdx.y < 4);
  const int wm = (wave >> 1) * 64, wn = (wave & 1) * 64;
  const int K = 1024, ldc = 896;
  // staging: thread handles rows sr and sr+64, source chunk pre-swizzled
  const int sr = tid >> 2;                     // 0..63
  const int sc = tid & 3;
  const int fS = (sr & 3) ^ ((sr >> 2) & 3);   // same for sr and sr+64
  const int scS = ((sc ^ fS) << 3);            // swizzled k-offset (elements)
  const size_t gA0 = (size_t)(m0 + sr)*K + scS, gA1 = gA0 + (size_t)64*K;
  const size_t gB0 = (size_t)(n0 + sr)*K + scS, gB1 = gB0 + (size_t)64*K;
  const int d0 = tid*8, d1 = d0 + 64*32;       // lane-linear LDS dest (byte = tid*16)
  // fragment reads: swizzled chunk, per-thread constant
  const int fR = (l15 & 3) ^ ((l15 >> 2) & 3);
  const int rq = ((quad ^ fR) << 3);

  f32x4 acc[4][4] = {};
  for (int kb = 0; kb < K; kb += 32){
    gl16(Ah + gA0 + kb, lAh + d0);
    gl16(Ah + gA1 + kb, lAh + d1);
    gl16(Bh + gB0 + kb, lBh + d0);
    gl16(Bh + gB1 + kb, lBh + d1);
    if (full){
      gl16(Al + gA0 + kb, lAl + d0);
      gl16(Al + gA1 + kb, lAl + d1);
      gl16(Bl + gB0 + kb, lBl + d0);
      gl16(Bl + gB1 + kb, lBl + d1);
    }
    __syncthreads();   // vmcnt(0) drain: async loads landed
    short8 afh[4], bfh[4];
    #pragma unroll
    for (int mi=0;mi<4;mi++) afh[mi] = *(const short8*)&lAh[(wm + mi*16 + l15)*32 + rq];
    #pragma unroll
    for (int ni=0;ni<4;ni++) bfh[ni] = *(const short8*)&lBh[(wn + ni*16 + l15)*32 + rq];
    #pragma unroll
    for (int mi=0;mi<4;mi++)
      #pragma unroll
      for (int ni=0;ni<4;ni++)
        acc[mi][ni] = __builtin_amdgcn_mfma_f32_16x16x32_bf16(afh[mi], bfh[ni], acc[mi][ni], 0,0,0);
    if (full){
      short8 afl[4], bfl[4];
      #pragma unroll
      for (int mi=0;mi<4;mi++) afl[mi] = *(const short8*)&lAl[(wm + mi*16 + l15)*32 + rq];
      #pragma unroll
      for (int ni=0;ni<4;ni++) bfl[ni] = *(const short8*)&lBl[(wn + ni*16 + l15)*32 + rq];
      #pragma unroll
      for (int mi=0;mi<4;mi++)
        #pragma unroll
        for (int ni=0;ni<4;ni++){
          acc[mi][ni] = __builtin_amdgcn_mfma_f32_16x16x32_bf16(afh[mi], bfl[ni], acc[mi][ni], 0,0,0);
          acc[mi][ni] = __builtin_amdgcn_mfma_f32_16x16x32_bf16(afl[mi], bfh[ni], acc[mi][ni], 0,0,0);
        }
    }
    __syncthreads();   // all reads done before next iteration's async loads overwrite
  }
  #pragma unroll
  for (int mi=0;mi<4;mi++){
    #pragma unroll
    for (int ni=0;ni<4;ni++){
      const int col = n0 + wn + ni*16 + l15;
      const int rb_ = m0 + wm + mi*16 + quad*4;
      #pragma unroll
      for (int r=0;r<4;r++){
        float v = acc[mi][ni][r];
        const int row = rb_ + r;
        if (col < 448) v = 0.5f * tanhf(v);
        else if (col >= 832 && col < 848) v = 1.f/(1.f + expf(-(v + bias[col-832])));
        C[(size_t)row*ldc + col] = v;
      }
    }
  }
}

// =================== output GEMM: bf16 A/Bt -> fp32 C (same staging/swizzle, K=128) ===================
__global__ __launch_bounds__(256) void gemm_out_kernel(
    const u16* __restrict__ A, const u16* __restrict__ Bt, float* __restrict__ C)
{
  __shared__ u16 ldsA[128*32];
  __shared__ u16 ldsB[128*32];
  const int tid = threadIdx.x;
  const int wave = tid >> 6;
  const int lane = tid & 63;
  const int quad = lane >> 4, l15 = lane & 15;
  const int m0 = blockIdx.x * 128, n0 = blockIdx.y * 128;
  const int wm = (wave >> 1) * 64, wn = (wave & 1) * 64;
  const int K = 128, ldc = 1024;
  const int sr = tid >> 2;
  const int sc = tid & 3;
  const int fS = (sr & 3) ^ ((sr >> 2) & 3);
  const int scS = ((sc ^ fS) << 3);
  const size_t gA0 = (size_t)(m0 + sr)*K + scS, gA1 = gA0 + (size_t)64*K;
  const size_t gB0 = (size_t)(n0 + sr)*K + scS, gB1 = gB0 + (size_t)64*K;
  const int d0 = tid*8, d1 = d0 + 64*32;
  const int fR = (l15 & 3) ^ ((l15 >> 2) & 3);
  const int rq = ((quad ^ fR) << 3);

  f32x4 acc[4][4] = {};
  for (int kb = 0; kb < K; kb += 32){
    gl16(A + gA0 + kb, ldsA + d0);
    gl16(A + gA1 + kb, ldsA + d1);
    gl16(Bt + gB0 + kb, ldsB + d0);
    gl16(Bt + gB1 + kb, ldsB + d1);
    __syncthreads();
    short8 af[4], bf8[4];
    #pragma unroll
    for (int mi=0;mi<4;mi++) af[mi] = *(const short8*)&ldsA[(wm + mi*16 + l15)*32 + rq];
    #pragma unroll
    for (int ni=0;ni<4;ni++) bf8[ni] = *(const short8*)&ldsB[(wn + ni*16 + l15)*32 + rq];
    #pragma unroll
    for (int mi=0;mi<4;mi++)
      #pragma unroll
      for (int ni=0;ni<4;ni++)
        acc[mi][ni] = __builtin_amdgcn_mfma_f32_16x16x32_bf16(af[mi], bf8[ni], acc[mi][ni], 0,0,0);
    __syncthreads();
  }
  #pragma unroll
  for (int mi=0;mi<4;mi++)
    #pragma unroll
    for (int ni=0;ni<4;ni++){
      const int col = n0 + wn + ni*16 + l15;
      const int rb_ = m0 + wm + mi*16 + quad*4;
      #pragma unroll
      for (int r=0;r<4;r++)
        C[(size_t)(rb_ + r)*ldc + col] = acc[mi][ni][r];
    }
}

// =================== expm of skew (2 lanes per matrix) ===================
__device__ constexpr int TRI_I[28] = {0,0,0,0,0,0,0, 1,1,1,1,1,1, 2,2,2,2,2, 3,3,3,3, 4,4,4, 5,5, 6};
__device__ constexpr int TRI_J[28] = {1,2,3,4,5,6,7, 2,3,4,5,6,7, 3,4,5,6,7, 4,5,6,7, 5,6,7, 6,7, 7};

DEV void pair_matmul(const float XA[4][4], const float XB[4][4], const float Mm[4][8], float Tm[4][8]){
  float Yo[4][8];
  #pragma unroll
  for (int r=0;r<4;r++)
    #pragma unroll
    for (int jj=0;jj<8;jj++) Yo[r][jj] = __shfl_xor(Mm[r][jj], 1);
  #pragma unroll
  for (int i=0;i<4;i++)
    #pragma unroll
    for (int jj=0;jj<8;jj++){
      float acc = 0.f;
      #pragma unroll
      for (int r=0;r<4;r++){ acc = fmaf(XA[i][r], Mm[r][jj], acc); acc = fmaf(XB[i][r], Yo[r][jj], acc); }
      Tm[i][jj] = acc;
    }
}

__global__ __launch_bounds__(256) void expm_kernel(const float* __restrict__ proj, float* __restrict__ O)
{
  const int tid = blockIdx.x*256 + threadIdx.x;
  const int pid = tid >> 1;     // matrix id [0, 262144)
  const int p = tid & 1;        // half: rows 4p..4p+3
  const int row = pid >> 4, h = pid & 15;
  const float* sk = proj + (size_t)row*896 + h*28;

  float Bm[4][8];
  #pragma unroll
  for (int i=0;i<4;i++)
    #pragma unroll
    for (int jj=0;jj<8;jj++) Bm[i][jj] = 0.f;
  #pragma unroll
  for (int c=0;c<28;c++){
    const int ti = TRI_I[c], tj = TRI_J[c];
    float v = sk[c] * 0.0625f;      // A/16 (scaling-and-squaring s=4)
    if (p==0){
      if (ti < 4) Bm[ti][tj] = v;
      if (tj < 4) Bm[tj][ti] = -v;
    } else {
      if (ti >= 4) Bm[ti-4][tj] = v;
      if (tj >= 4) Bm[tj-4][ti] = -v;
    }
  }
  float BA[4][4], BB[4][4];
  #pragma unroll
  for (int i=0;i<4;i++)
    #pragma unroll
    for (int r=0;r<4;r++){ float lo=Bm[i][r], hi=Bm[i][4+r]; BA[i][r] = p? hi: lo; BB[i][r] = p? lo: hi; }

  float Mm[4][8], Tm[4][8];
  #pragma unroll
  for (int i=0;i<4;i++)
    #pragma unroll
    for (int jj=0;jj<8;jj++) Mm[i][jj] = Bm[i][jj]*(1.f/6.f) + (((4*p+i)==jj)?1.f:0.f);
  const float coef[5] = {0.2f, 0.25f, 1.f/3.f, 0.5f, 1.f};
  #pragma unroll
  for (int st=0; st<5; st++){
    pair_matmul(BA, BB, Mm, Tm);
    #pragma unroll
    for (int i=0;i<4;i++)
      #pragma unroll
      for (int jj=0;jj<8;jj++) Mm[i][jj] = Tm[i][jj]*coef[st] + (((4*p+i)==jj)?1.f:0.f);
  }
  #pragma unroll
  for (int sq=0; sq<4; sq++){
    float MA[4][4], MB[4][4];
    #pragma unroll
    for (int i=0;i<4;i++)
      #pragma unroll
      for (int r=0;r<4;r++){ float lo=Mm[i][r], hi=Mm[i][4+r]; MA[i][r] = p? hi: lo; MB[i][r] = p? lo: hi; }
    pair_matmul(MA, MB, Mm, Tm);
    #pragma unroll
    for (int i=0;i<4;i++)
      #pragma unroll
      for (int jj=0;jj<8;jj++) Mm[i][jj] = Tm[i][jj];
  }
  const int b_ = row >> 12, t_ = row & 4095;
  const size_t obase = (((size_t)(b_*16 + h))*4096 + (size_t)t_)*64;
  #pragma unroll
  for (int i=0;i<4;i++){
    f32x4 lo = {Mm[i][0],Mm[i][1],Mm[i][2],Mm[i][3]};
    f32x4 hi = {Mm[i][4],Mm[i][5],Mm[i][6],Mm[i][7]};
    *(f32x4*)(O + obase + (size_t)(4*p+i)*8)     = lo;
    *(f32x4*)(O + obase + (size_t)(4*p+i)*8 + 4) = hi;
  }
}

// helpers: 8x8 matvec with 16 f32x4 regs
DEV void load16(const float* p, f32x4* M){
  #pragma unroll
  for (int q=0;q<16;q++) M[q] = *(const f32x4*)(p + 4*q);
}
DEV void rm_matvec8(const f32x4* M16, const float* x, float* res){
  #pragma unroll
  for (int i=0;i<8;i++){
    float acc = 0.f;
    #pragma unroll
    for (int a=0;a<8;a++) acc = fmaf(M16[2*i + (a>>2)][a&3], x[a], acc);
    res[i] = acc;
  }
}
DEV void cm_matvec8(const f32x4* M16, const float* x, float* res){
  #pragma unroll
  for (int i=0;i<8;i++){
    float acc = 0.f;
    #pragma unroll
    for (int a=0;a<8;a++) acc = fmaf(M16[2*a + (i>>2)][i&3], x[a], acc);
    res[i] = acc;
  }
}

// =================== C1: local prefix products within 64-step chunks ===================
__global__ __launch_bounds__(256) void chunkpfx_kernel(float* __restrict__ OR)
{
  int tid = blockIdx.x*256 + threadIdx.x;   // 32768 = 4096 tasks * 8 lanes
  int task = tid >> 3, j = tid & 7;
  int s = task >> 6, c = task & 63;
  float P[8], Pn[8];
  #pragma unroll
  for (int a=0;a<8;a++) P[a] = (a==j) ? 1.f : 0.f;
  float* base = OR + ((size_t)s*4096 + (size_t)c*64)*64;
  for (int tt=0; tt<64; tt++){
    float* slot = base + (size_t)tt*64;
    f32x4 Oc[16];
    load16(slot, Oc);              // O_t row-major
    rm_matvec8(Oc, P, Pn);         // P <- O_t * P
    #pragma unroll
    for (int a=0;a<8;a++) P[a] = Pn[a];
    f32x4 s0 = {P[0],P[1],P[2],P[3]}, s1 = {P[4],P[5],P[6],P[7]};
    *(f32x4*)(slot + j*8)     = s0;   // store col-major (same-wave: loads precede stores)
    *(f32x4*)(slot + j*8 + 4) = s1;
  }
}

// =================== C2: scan of chunk products -> Rbase_c ===================
__global__ __launch_bounds__(256) void chunkscan_kernel(const float* __restrict__ OR, float* __restrict__ Rbase)
{
  int tid = blockIdx.x*256 + threadIdx.x;   // 512 = 64 seqs * 8 lanes
  int s = tid >> 3, j = tid & 7;
  float Rb[8], Rn[8];
  #pragma unroll
  for (int a=0;a<8;a++) Rb[a] = (a==j) ? 1.f : 0.f;
  for (int c=0;c<64;c++){
    float* dst = Rbase + ((size_t)s*64 + c)*64 + j*8;
    f32x4 s0 = {Rb[0],Rb[1],Rb[2],Rb[3]}, s1 = {Rb[4],Rb[5],Rb[6],Rb[7]};
    *(f32x4*)(dst) = s0; *(f32x4*)(dst+4) = s1;     // col-major Rbase_c
    if (c < 63){
      const float* qs = OR + ((size_t)s*4096 + (size_t)(c*64+63))*64;  // Q_c col-major
      f32x4 Q[16];
      load16(qs, Q);
      cm_matvec8(Q, Rb, Rn);       // Rb <- Q_c * Rb
      #pragma unroll
      for (int a=0;a<8;a++) Rb[a] = Rn[a];
    }
  }
}

// =================== C3: compose R_t, normalize k, rotate k/v/q ===================
// scanin aliased into proj's dead skew slots: scanin(s,t) = proj + row*896 + h*28
__global__ __launch_bounds__(256) void rotate_kvq_kernel(float* __restrict__ OR, const float* __restrict__ Rbase,
    float* __restrict__ proj)
{
  int tid = blockIdx.x*256 + threadIdx.x;   // 262144
  int s = tid >> 12, t = tid & 4095;
  int c = t >> 6;
  int b = s >> 4, h = s & 15;
  int row = b*4096 + t;
  float* slot = OR + ((size_t)s*4096 + t)*64;
  f32x4 P4[16];
  load16(slot, P4);                          // P_c(t), col-major
  float* pr = proj + (size_t)row*896;
  float k[8], v[8], q[8];
  { f32x4 a = *(const f32x4*)(pr+448+h*8), b2 = *(const f32x4*)(pr+452+h*8);
    #pragma unroll
    for (int i=0;i<4;i++){ k[i]=a[i]; k[4+i]=b2[i]; } }
  { f32x4 a = *(const f32x4*)(pr+576+h*8), b2 = *(const f32x4*)(pr+580+h*8);
    #pragma unroll
    for (int i=0;i<4;i++){ v[i]=a[i]; v[4+i]=b2[i]; } }
  { f32x4 a = *(const f32x4*)(pr+704+h*8), b2 = *(const f32x4*)(pr+708+h*8);
    #pragma unroll
    for (int i=0;i<4;i++){ q[i]=a[i]; q[4+i]=b2[i]; } }
  float nn = 0.f;
  #pragma unroll
  for (int i=0;i<8;i++) nn = fmaf(k[i],k[i],nn);
  float inv = 1.f / fmaxf(sqrtf(nn), 1e-6f);
  #pragma unroll
  for (int i=0;i<8;i++) k[i] *= inv;

  const float* rb = Rbase + ((size_t)s*64 + c)*64;
  float kt[8], vt[8], qt[8];
  #pragma unroll
  for (int j=0;j<8;j++){
    float rbv[8];
    { f32x4 a = *(const f32x4*)(rb + j*8), b2 = *(const f32x4*)(rb + j*8 + 4);
      #pragma unroll
      for (int i=0;i<4;i++){ rbv[i]=a[i]; rbv[4+i]=b2[i]; } }
    float Rc[8];
    cm_matvec8(P4, rbv, Rc);        // column j of R_t = P * Rbase[:,j]
    f32x4 s0 = {Rc[0],Rc[1],Rc[2],Rc[3]}, s1 = {Rc[4],Rc[5],Rc[6],Rc[7]};
    *(f32x4*)(slot + j*8) = s0; *(f32x4*)(slot + j*8 + 4) = s1;   // R_t col-major (in place)
    float a0=0.f, a1=0.f, a2=0.f;
    #pragma unroll
    for (int i=0;i<8;i++){ a0 = fmaf(Rc[i],k[i],a0); a1 = fmaf(Rc[i],v[i],a1); a2 = fmaf(Rc[i],q[i],a2); }
    kt[j]=a0; vt[j]=a1; qt[j]=a2;
  }
  float beta = pr[832+h];
  float qk = 0.f;
  #pragma unroll
  for (int j=0;j<8;j++) qk = fmaf(kt[j], qt[j], qk);
  float* sip = pr + h*28;     // dead skew slot of this (row,h); writes <448, reads >=448
  f32x4 w0={kt[0],kt[1],kt[2],kt[3]}, w1={kt[4],kt[5],kt[6],kt[7]};
  f32x4 w2={vt[0],vt[1],vt[2],vt[3]}, w3={vt[4],vt[5],vt[6],vt[7]};
  f32x4 w4={qt[0],qt[1],qt[2],qt[3]}, w5={qt[4],qt[5],qt[6],qt[7]};
  f32x4 w6={beta, qk, 0.f, 0.f};
  *(f32x4*)(sip)=w0; *(f32x4*)(sip+4)=w1; *(f32x4*)(sip+8)=w2; *(f32x4*)(sip+12)=w3;
  *(f32x4*)(sip+16)=w4; *(f32x4*)(sip+20)=w5; *(f32x4*)(sip+24)=w6;
}

// =================== D: chunk-parallel delta scan ===================
__global__ __launch_bounds__(256) void scan_pass1_kernel(const float* __restrict__ proj,
    float* __restrict__ Mbuf, float* __restrict__ wbuf)
{
  int tid = blockIdx.x*256 + threadIdx.x;   // 32768 = 4096 tasks * 8 lanes
  int task = tid >> 3, j = tid & 7;         // task = s*64 + c
  int s = task >> 6, c = task & 63;
  int b = s >> 4, h = s & 15;
  const float* rec = proj + ((size_t)b*4096 + (size_t)c*64)*896 + h*28;
  float m[8], w[8];
  #pragma unroll
  for (int i=0;i<8;i++){ m[i] = (i==j)?1.f:0.f; w[i] = 0.f; }
  for (int tt=0; tt<64; tt++){
    const float* p = rec + (size_t)tt*896;
    f32x4 k0 = *(const f32x4*)(p), k1 = *(const f32x4*)(p+4);
    float vt = p[8+j];
    float beta = p[24];
    float s1, s2;
    s1 = ((k0[0]*m[0] + k0[1]*m[1]) + (k0[2]*m[2] + k0[3]*m[3]))
       + ((k1[0]*m[4] + k1[1]*m[5]) + (k1[2]*m[6] + k1[3]*m[7]));
    s2 = ((k0[0]*w[0] + k0[1]*w[1]) + (k0[2]*w[2] + k0[3]*w[3]))
       + ((k1[0]*w[4] + k1[1]*w[5]) + (k1[2]*w[6] + k1[3]*w[7]));
    float c1 = -beta*s1, c2 = beta*(vt - s2);
    #pragma unroll
    for (int i=0;i<4;i++){ m[i] = fmaf(k0[i], c1, m[i]); m[4+i] = fmaf(k1[i], c1, m[4+i]); }
    #pragma unroll
    for (int i=0;i<4;i++){ w[i] = fmaf(k0[i], c2, w[i]); w[4+i] = fmaf(k1[i], c2, w[4+i]); }
  }
  float* md = Mbuf + (size_t)task*64 + j*8;
  float* wd = wbuf + (size_t)task*64 + j*8;
  f32x4 m0={m[0],m[1],m[2],m[3]}, m1={m[4],m[5],m[6],m[7]};
  f32x4 w0={w[0],w[1],w[2],w[3]}, w1={w[4],w[5],w[6],w[7]};
  *(f32x4*)(md) = m0; *(f32x4*)(md+4) = m1;
  *(f32x4*)(wd) = w0; *(f32x4*)(wd+4) = w1;
}

__global__ __launch_bounds__(64) void scan_mid_kernel(const float* __restrict__ Mbuf,
    const float* __restrict__ wbuf, float* __restrict__ dstart)
{
  int tid = blockIdx.x*64 + threadIdx.x;    // 512 = 64 seqs * 8 lanes
  int s = tid >> 3, j = tid & 7;
  float d[8];
  #pragma unroll
  for (int i=0;i<8;i++) d[i] = 0.f;
  size_t base = (size_t)s*64*64;
  f32x4 M[16]; load16(Mbuf + base, M);
  f32x4 wv0 = *(const f32x4*)(wbuf + base + j*8), wv1 = *(const f32x4*)(wbuf + base + j*8 + 4);
  for (int c=0; c<64; c++){
    float* dd = dstart + base + (size_t)c*64 + j*8;
    f32x4 s0 = {d[0],d[1],d[2],d[3]}, s1 = {d[4],d[5],d[6],d[7]};
    *(f32x4*)(dd) = s0; *(f32x4*)(dd+4) = s1;
    float dn[8];
    cm_matvec8(M, d, dn);
    #pragma unroll
    for (int i=0;i<4;i++){ d[i] = dn[i] + wv0[i]; d[4+i] = dn[4+i] + wv1[i]; }
    if (c < 63){
      size_t nb = base + (size_t)(c+1)*64;
      load16(Mbuf + nb, M);
      wv0 = *(const f32x4*)(wbuf + nb + j*8); wv1 = *(const f32x4*)(wbuf + nb + j*8 + 4);
    }
  }
}

__global__ __launch_bounds__(256) void scan_pass2_kernel(const float* __restrict__ proj,
    const float* __restrict__ dstart, float* __restrict__ oo)
{
  int tid = blockIdx.x*256 + threadIdx.x;   // 32768
  int task = tid >> 3, j = tid & 7;
  int s = task >> 6, c = task & 63;
  int b = s >> 4, h = s & 15;
  const float* rec = proj + ((size_t)b*4096 + (size_t)c*64)*896 + h*28;
  float* op = oo + (((size_t)s*4096 + (size_t)c*64)*8) + j;
  float d[8];
  { const float* ds = dstart + (size_t)task*64 + j*8;
    f32x4 a = *(const f32x4*)(ds), b2 = *(const f32x4*)(ds+4);
    #pragma unroll
    for (int i=0;i<4;i++){ d[i]=a[i]; d[4+i]=b2[i]; } }
  for (int tt=0; tt<64; tt++){
    const float* p = rec + (size_t)tt*896;
    f32x4 k0 = *(const f32x4*)(p),    k1 = *(const f32x4*)(p+4);
    f32x4 q0 = *(const f32x4*)(p+16), q1 = *(const f32x4*)(p+20);
    f32x4 mb = *(const f32x4*)(p+24);           // [beta, qk, -, -]
    float vt = p[8+j];
    float kd, qd;
    kd = ((k0[0]*d[0] + k0[1]*d[1]) + (k0[2]*d[2] + k0[3]*d[3]))
       + ((k1[0]*d[4] + k1[1]*d[5]) + (k1[2]*d[6] + k1[3]*d[7]));
    qd = ((q0[0]*d[0] + q0[1]*d[1]) + (q0[2]*d[2] + q0[3]*d[3]))
       + ((q1[0]*d[4] + q1[1]*d[5]) + (q1[2]*d[6] + q1[3]*d[7]));
    float w_ = mb[0] * (vt - kd);
    #pragma unroll
    for (int i=0;i<4;i++){ d[i] = fmaf(k0[i], w_, d[i]); d[4+i] = fmaf(k1[i], w_, d[4+i]); }
    op[(size_t)tt*8] = fmaf(mb[1], w_, qd);
  }
}

// =================== E: rotate outputs back: o = R_t * o~, write bf16 for out-GEMM ===================
__global__ __launch_bounds__(256) void rotout_kernel(const float* __restrict__ OR, const float* __restrict__ oo,
                                                     u16* __restrict__ obf)
{
  int tid = blockIdx.x*256 + threadIdx.x;   // 262144
  int s = tid >> 12, t = tid & 4095;
  int b = s >> 4, h = s & 15;
  int row = b*4096 + t;
  const float* slot = OR + ((size_t)s*4096 + t)*64;
  f32x4 R4[16];
  load16(slot, R4);
  float u[8];
  { const float* up = oo + ((size_t)s*4096 + t)*8;
    f32x4 a = *(const f32x4*)(up), b2 = *(const f32x4*)(up+4);
    #pragma unroll
    for (int i=0;i<4;i++){ u[i]=a[i]; u[4+i]=b2[i]; } }
  float o[8];
  cm_matvec8(R4, u, o);
  u32 p0 = (u32)f2bf(o[0]) | ((u32)f2bf(o[1])<<16);
  u32 p1 = (u32)f2bf(o[2]) | ((u32)f2bf(o[3])<<16);
  u32 p2 = (u32)f2bf(o[4]) | ((u32)f2bf(o[5])<<16);
  u32 p3 = (u32)f2bf(o[6]) | ((u32)f2bf(o[7])<<16);
  u32x4 pk = {p0,p1,p2,p3};
  *(u32x4*)(void*)(obf + (size_t)row*128 + h*8) = pk;
}

// =================== launch ===================
extern "C" void kernel_launch(void* const* d_in, const int* in_sizes, int n_in,
                              void* d_out, int out_size, void* d_ws, size_t ws_size,
                              hipStream_t stream)
{
  const float* x     = (const float*)d_in[0];
  const float* Wskew = (const float*)d_in[1];
  const float* Wk    = (const float*)d_in[2];
  const float* Wv    = (const float*)d_in[3];
  const float* Wq    = (const float*)d_in[4];
  const float* Wbeta = (const float*)d_in[5];
  const float* bbeta = (const float*)d_in[6];
  const float* Wo    = (const float*)d_in[7];

  char* w = (char*)d_ws; size_t off = 0;
  auto alloc = [&](size_t bytes)->void*{ void* p = w + off; off += (bytes + 255) & ~(size_t)255; return p; };
  u16*   Wh     = (u16*)  alloc((size_t)896*1024*2);
  u16*   Wl     = (u16*)  alloc((size_t)896*1024*2);
  u16*   WoT    = (u16*)  alloc((size_t)1024*128*2);
  float* proj   = (float*)alloc((size_t)16384*896*4);
  float* OR     = (float*)alloc((size_t)262144*64*4);
  float* Rbase  = (float*)alloc((size_t)64*64*64*4);
  float* oo     = (float*)alloc((size_t)262144*8*4);
  float* Mbuf   = (float*)alloc((size_t)4096*64*4);
  float* wbuf   = (float*)alloc((size_t)4096*64*4);
  float* dstart = (float*)alloc((size_t)4096*64*4);
  // aliases: xh/xl live only until gemm_proj; OR is written first by expm (after)
  u16*   xh     = (u16*)OR;                       // 32 MB
  u16*   xl     = xh + (size_t)16384*1024;        // 32 MB  (OR region is 64 MB)
  u16*   obf    = (u16*)proj;   // proj fully dead after scan pass2; 4MB << 56MB

  hipLaunchKernelGGL(splitx_kernel, dim3(8192), dim3(256), 0, stream, x, xh, xl);
  hipLaunchKernelGGL(concat_kernel, dim3(4096), dim3(256), 0, stream,
                     Wskew, Wk, Wv, Wq, Wbeta, Wo, Wh, Wl, WoT);
  hipLaunchKernelGGL(gemm_proj_kernel, dim3(128,7), dim3(256), 0, stream,
                     xh, xl, Wh, Wl, proj, bbeta);
  hipLaunchKernelGGL(expm_kernel, dim3(2048), dim3(256), 0, stream, proj, OR);
  hipLaunchKernelGGL(chunkpfx_kernel, dim3(128), dim3(256), 0, stream, OR);
  hipLaunchKernelGGL(chunkscan_kernel, dim3(2), dim3(256), 0, stream, OR, Rbase);
  hipLaunchKernelGGL(rotate_kvq_kernel, dim3(1024), dim3(256), 0, stream, OR, Rbase, proj);
  hipLaunchKernelGGL(scan_pass1_kernel, dim3(128), dim3(256), 0, stream, proj, Mbuf, wbuf);
  hipLaunchKernelGGL(scan_mid_kernel, dim3(8), dim3(64), 0, stream, Mbuf, wbuf, dstart);
  hipLaunchKernelGGL(scan_pass2_kernel, dim3(128), dim3(256), 0, stream, proj, dstart, oo);
  hipLaunchKernelGGL(rotout_kernel, dim3(1024), dim3(256), 0, stream, OR, oo, obf);
  hipLaunchKernelGGL(gemm_out_kernel, dim3(128,8), dim3(256), 0, stream,
                     obf, WoT, (float*)d_out);
}

// Round 2
// 527.702 us; speedup vs baseline: 1.0880x; 1.0304x over previous
//
#include <hip/hip_runtime.h>

typedef unsigned short u16;
typedef unsigned int u32;
typedef __attribute__((ext_vector_type(4))) float f32x4;
typedef __attribute__((ext_vector_type(8))) short short8;
typedef __attribute__((ext_vector_type(4))) unsigned int u32x4;

#define DEV __device__ __forceinline__

DEV float bf2f(u16 u){ union{u32 i; float f;} x; x.i = ((u32)u)<<16; return x.f; }
DEV u16 f2bf(float f){ union{u32 i; float f;} x; x.f = f; u32 r = x.i + 0x7fffu + ((x.i>>16)&1u); return (u16)(r>>16); }

union U8 { u16 u[8]; short8 s; };

// async global -> LDS, 16B per lane (dest must be wave-uniform base + lane*16; ours is tid*16)
DEV void gl16(const u16* g, u16* l){
  __builtin_amdgcn_global_load_lds(
      (const __attribute__((address_space(1))) u32*)g,
      (__attribute__((address_space(3))) u32*)l, 16, 0, 0);
}

// fast tanh/sigmoid via v_exp + v_rcp (err ~1e-6, dwarfed by bf16 input rounding)
DEV float fast_htanh(float v){           // 0.5*tanh(v)
  float vc = fminf(fmaxf(v, -15.f), 15.f);
  float e = __expf(2.f*vc);
  return 0.5f*(e - 1.f)*__builtin_amdgcn_rcpf(e + 1.f);
}
DEV float fast_sigmoid(float v){
  float e = __expf(-v);
  return __builtin_amdgcn_rcpf(1.f + e);
}

// =================== split x into hi/lo bf16 planes ===================
__global__ __launch_bounds__(256) void splitx_kernel(const float* __restrict__ x,
    u16* __restrict__ xh, u16* __restrict__ xl)
{
  size_t base = ((size_t)blockIdx.x*256 + threadIdx.x) * 8;   // 16384*1024/8 threads
  f32x4 a = *(const f32x4*)(x + base), b = *(const f32x4*)(x + base + 4);
  U8 h, l;
  #pragma unroll
  for (int e=0;e<4;e++){
    u16 hh = f2bf(a[e]); h.u[e]   = hh; l.u[e]   = f2bf(a[e] - bf2f(hh));
    u16 gg = f2bf(b[e]); h.u[4+e] = gg; l.u[4+e] = f2bf(b[e] - bf2f(gg));
  }
  *(short8*)(xh + base) = h.s;
  *(short8*)(xl + base) = l.s;
}

// =================== weight concat / transpose -> hi/lo bf16 planes ===================
// Wh/Wl [896][1024]: rows 0-447 Wskew^T, 448-575 Wk^T, 576-703 Wv^T, 704-831 Wq^T, 832-847 Wbeta^T, 848-895 zero
__global__ __launch_bounds__(256) void concat_kernel(
    const float* __restrict__ Wskew, const float* __restrict__ Wk, const float* __restrict__ Wv,
    const float* __restrict__ Wq, const float* __restrict__ Wbeta, const float* __restrict__ Wo,
    u16* __restrict__ Wh, u16* __restrict__ Wl, u16* __restrict__ WoT)
{
  int idx = blockIdx.x*256 + threadIdx.x;
  if (idx < 896*1024){
    int n = idx >> 10, kk = idx & 1023;
    float v;
    if (n < 448)      v = Wskew[kk*448 + n];
    else if (n < 576) v = Wk[kk*128 + (n-448)];
    else if (n < 704) v = Wv[kk*128 + (n-576)];
    else if (n < 832) v = Wq[kk*128 + (n-704)];
    else if (n < 848) v = Wbeta[kk*16 + (n-832)];
    else              v = 0.f;
    u16 h = f2bf(v);
    Wh[idx] = h;
    Wl[idx] = f2bf(v - bf2f(h));
  } else {
    int r = idx - 896*1024;
    int n = r >> 7, kk = r & 127;
    WoT[r] = f2bf(Wo[kk*1024 + n]);
  }
}

// =================== proj GEMM: double-buffered global_load_lds pipeline ===================
// 2-phase schedule (catalog T3-minimum): STAGE(next) -> ds_read+MFMA(cur) -> one __syncthreads
// per iter (vmcnt(0)+barrier). The drained loads had the whole compute phase to land.
// Precision zones: cols 0-447 (skew) 3-pass split-bf16; cols 448+ (k/v/q/beta) 1-pass bf16.
// wantLow is wave-uniform: block y=3's wn=64 half (cols 448-511, normalized k-heads) skips low.
// Swizzle (rule #21): linear gload_lds dest + pre-swizzled SOURCE + swizzled READ,
//   f(r) = (r&3)^((r>>2)&3), per-thread constant on both sides.
__global__ __launch_bounds__(256) void gemm_proj_kernel(
    const u16* __restrict__ Ah, const u16* __restrict__ Al,
    const u16* __restrict__ Bh, const u16* __restrict__ Bl,
    float* __restrict__ C, const float* __restrict__ bias)
{
  // [buf(2)][plane(4)][4096 u16]: planes Ah, Bh, Al, Bl; 64 KiB total
  __shared__ u16 L[2*4*4096];
  const int tid = threadIdx.x;
  const int wave = tid >> 6;
  const int lane = tid & 63;
  const int quad = lane >> 4, l15 = lane & 15;
  const int m0 = blockIdx.x * 128, n0 = blockIdx.y * 128;
  const bool full = (blockIdx.y < 4);
  const int wm = (wave >> 1) * 64, wn = (wave & 1) * 64;
  const bool wantLow = full && !(blockIdx.y == 3 && wn == 64);
  const bool skipBl1 = (blockIdx.y == 3);     // Bl rows 64-127 (cols 448-511) unused
  const int K = 1024, ldc = 896;
  const int sr = tid >> 2;                     // staging row 0..63 (and +64)
  const int sc = tid & 3;
  const int fS = (sr & 3) ^ ((sr >> 2) & 3);
  const int scS = ((sc ^ fS) << 3);            // swizzled k-offset (elements)
  const size_t gA0 = (size_t)(m0 + sr)*K + scS, gA1 = gA0 + (size_t)64*K;
  const size_t gB0 = (size_t)(n0 + sr)*K + scS, gB1 = gB0 + (size_t)64*K;
  const int d0 = tid*8, d1 = d0 + 2048;        // lane-linear LDS dest (byte = tid*16)
  const int fR = (l15 & 3) ^ ((l15 >> 2) & 3);
  const int rq = ((quad ^ fR) << 3);

  auto STAGE = [&](int buf, int kb){
    u16* Lb = L + buf*16384;
    gl16(Ah + gA0 + kb, Lb + d0);
    gl16(Ah + gA1 + kb, Lb + d1);
    gl16(Bh + gB0 + kb, Lb + 4096 + d0);
    gl16(Bh + gB1 + kb, Lb + 4096 + d1);
    if (full){
      gl16(Al + gA0 + kb, Lb + 8192 + d0);
      gl16(Al + gA1 + kb, Lb + 8192 + d1);
      gl16(Bl + gB0 + kb, Lb + 12288 + d0);
      if (!skipBl1) gl16(Bl + gB1 + kb, Lb + 12288 + d1);
    }
  };

  f32x4 acc[4][4] = {};
  STAGE(0, 0);
  __syncthreads();                 // drain prologue loads
  int cur = 0;
  for (int kb = 0; kb < K; kb += 32){
    if (kb + 32 < K) STAGE(cur^1, kb + 32);    // issue next-tile loads FIRST
    u16* Lb = L + cur*16384;
    short8 afh[4], bfh[4];
    #pragma unroll
    for (int mi=0;mi<4;mi++) afh[mi] = *(const short8*)&Lb[(wm + mi*16 + l15)*32 + rq];
    #pragma unroll
    for (int ni=0;ni<4;ni++) bfh[ni] = *(const short8*)&Lb[4096 + (wn + ni*16 + l15)*32 + rq];
    #pragma unroll
    for (int mi=0;mi<4;mi++)
      #pragma unroll
      for (int ni=0;ni<4;ni++)
        acc[mi][ni] = __builtin_amdgcn_mfma_f32_16x16x32_bf16(afh[mi], bfh[ni], acc[mi][ni], 0,0,0);
    if (wantLow){
      short8 afl[4], bfl[4];
      #pragma unroll
      for (int mi=0;mi<4;mi++) afl[mi] = *(const short8*)&Lb[8192 + (wm + mi*16 + l15)*32 + rq];
      #pragma unroll
      for (int ni=0;ni<4;ni++) bfl[ni] = *(const short8*)&Lb[12288 + (wn + ni*16 + l15)*32 + rq];
      #pragma unroll
      for (int mi=0;mi<4;mi++)
        #pragma unroll
        for (int ni=0;ni<4;ni++){
          acc[mi][ni] = __builtin_amdgcn_mfma_f32_16x16x32_bf16(afh[mi], bfl[ni], acc[mi][ni], 0,0,0);
          acc[mi][ni] = __builtin_amdgcn_mfma_f32_16x16x32_bf16(afl[mi], bfh[ni], acc[mi][ni], 0,0,0);
        }
    }
    __syncthreads();               // vmcnt(0)+barrier: next buffer ready, cur reads done
    cur ^= 1;
  }
  #pragma unroll
  for (int mi=0;mi<4;mi++){
    #pragma unroll
    for (int ni=0;ni<4;ni++){
      const int col = n0 + wn + ni*16 + l15;
      const int rb_ = m0 + wm + mi*16 + quad*4;
      #pragma unroll
      for (int r=0;r<4;r++){
        float v = acc[mi][ni][r];
        const int row = rb_ + r;
        if (col < 448) v = fast_htanh(v);
        else if (col >= 832 && col < 848) v = fast_sigmoid(v + bias[col-832]);
        C[(size_t)row*ldc + col] = v;
      }
    }
  }
}

// =================== output GEMM: bf16 A/Bt -> fp32 C (same dbuf pipeline, K=128) ===================
__global__ __launch_bounds__(256) void gemm_out_kernel(
    const u16* __restrict__ A, const u16* __restrict__ Bt, float* __restrict__ C)
{
  __shared__ u16 L[2*2*4096];     // [buf(2)][plane A,B][4096 u16]; 32 KiB
  const int tid = threadIdx.x;
  const int wave = tid >> 6;
  const int lane = tid & 63;
  const int quad = lane >> 4, l15 = lane & 15;
  const int m0 = blockIdx.x * 128, n0 = blockIdx.y * 128;
  const int wm = (wave >> 1) * 64, wn = (wave & 1) * 64;
  const int K = 128, ldc = 1024;
  const int sr = tid >> 2;
  const int sc = tid & 3;
  const int fS = (sr & 3) ^ ((sr >> 2) & 3);
  const int scS = ((sc ^ fS) << 3);
  const size_t gA0 = (size_t)(m0 + sr)*K + scS, gA1 = gA0 + (size_t)64*K;
  const size_t gB0 = (size_t)(n0 + sr)*K + scS, gB1 = gB0 + (size_t)64*K;
  const int d0 = tid*8, d1 = d0 + 2048;
  const int fR = (l15 & 3) ^ ((l15 >> 2) & 3);
  const int rq = ((quad ^ fR) << 3);

  auto STAGE = [&](int buf, int kb){
    u16* Lb = L + buf*8192;
    gl16(A  + gA0 + kb, Lb + d0);
    gl16(A  + gA1 + kb, Lb + d1);
    gl16(Bt + gB0 + kb, Lb + 4096 + d0);
    gl16(Bt + gB1 + kb, Lb + 4096 + d1);
  };

  f32x4 acc[4][4] = {};
  STAGE(0, 0);
  __syncthreads();
  int cur = 0;
  for (int kb = 0; kb < K; kb += 32){
    if (kb + 32 < K) STAGE(cur^1, kb + 32);
    u16* Lb = L + cur*8192;
    short8 af[4], bf8[4];
    #pragma unroll
    for (int mi=0;mi<4;mi++) af[mi] = *(const short8*)&Lb[(wm + mi*16 + l15)*32 + rq];
    #pragma unroll
    for (int ni=0;ni<4;ni++) bf8[ni] = *(const short8*)&Lb[4096 + (wn + ni*16 + l15)*32 + rq];
    #pragma unroll
    for (int mi=0;mi<4;mi++)
      #pragma unroll
      for (int ni=0;ni<4;ni++)
        acc[mi][ni] = __builtin_amdgcn_mfma_f32_16x16x32_bf16(af[mi], bf8[ni], acc[mi][ni], 0,0,0);
    __syncthreads();
    cur ^= 1;
  }
  #pragma unroll
  for (int mi=0;mi<4;mi++)
    #pragma unroll
    for (int ni=0;ni<4;ni++){
      const int col = n0 + wn + ni*16 + l15;
      const int rb_ = m0 + wm + mi*16 + quad*4;
      #pragma unroll
      for (int r=0;r<4;r++)
        C[(size_t)(rb_ + r)*ldc + col] = acc[mi][ni][r];
    }
}

// =================== expm of skew (2 lanes per matrix) ===================
__device__ constexpr int TRI_I[28] = {0,0,0,0,0,0,0, 1,1,1,1,1,1, 2,2,2,2,2, 3,3,3,3, 4,4,4, 5,5, 6};
__device__ constexpr int TRI_J[28] = {1,2,3,4,5,6,7, 2,3,4,5,6,7, 3,4,5,6,7, 4,5,6,7, 5,6,7, 6,7, 7};

DEV void pair_matmul(const float XA[4][4], const float XB[4][4], const float Mm[4][8], float Tm[4][8]){
  float Yo[4][8];
  #pragma unroll
  for (int r=0;r<4;r++)
    #pragma unroll
    for (int jj=0;jj<8;jj++) Yo[r][jj] = __shfl_xor(Mm[r][jj], 1);
  #pragma unroll
  for (int i=0;i<4;i++)
    #pragma unroll
    for (int jj=0;jj<8;jj++){
      float acc = 0.f;
      #pragma unroll
      for (int r=0;r<4;r++){ acc = fmaf(XA[i][r], Mm[r][jj], acc); acc = fmaf(XB[i][r], Yo[r][jj], acc); }
      Tm[i][jj] = acc;
    }
}

__global__ __launch_bounds__(256) void expm_kernel(const float* __restrict__ proj, float* __restrict__ O)
{
  const int tid = blockIdx.x*256 + threadIdx.x;
  const int pid = tid >> 1;     // matrix id [0, 262144)
  const int p = tid & 1;        // half: rows 4p..4p+3
  const int row = pid >> 4, h = pid & 15;
  const float* sk = proj + (size_t)row*896 + h*28;

  float Bm[4][8];
  #pragma unroll
  for (int i=0;i<4;i++)
    #pragma unroll
    for (int jj=0;jj<8;jj++) Bm[i][jj] = 0.f;
  #pragma unroll
  for (int c=0;c<28;c++){
    const int ti = TRI_I[c], tj = TRI_J[c];
    float v = sk[c] * 0.0625f;      // A/16 (scaling-and-squaring s=4)
    if (p==0){
      if (ti < 4) Bm[ti][tj] = v;
      if (tj < 4) Bm[tj][ti] = -v;
    } else {
      if (ti >= 4) Bm[ti-4][tj] = v;
      if (tj >= 4) Bm[tj-4][ti] = -v;
    }
  }
  float BA[4][4], BB[4][4];
  #pragma unroll
  for (int i=0;i<4;i++)
    #pragma unroll
    for (int r=0;r<4;r++){ float lo=Bm[i][r], hi=Bm[i][4+r]; BA[i][r] = p? hi: lo; BB[i][r] = p? lo: hi; }

  float Mm[4][8], Tm[4][8];
  #pragma unroll
  for (int i=0;i<4;i++)
    #pragma unroll
    for (int jj=0;jj<8;jj++) Mm[i][jj] = Bm[i][jj]*(1.f/6.f) + (((4*p+i)==jj)?1.f:0.f);
  const float coef[5] = {0.2f, 0.25f, 1.f/3.f, 0.5f, 1.f};
  #pragma unroll
  for (int st=0; st<5; st++){
    pair_matmul(BA, BB, Mm, Tm);
    #pragma unroll
    for (int i=0;i<4;i++)
      #pragma unroll
      for (int jj=0;jj<8;jj++) Mm[i][jj] = Tm[i][jj]*coef[st] + (((4*p+i)==jj)?1.f:0.f);
  }
  #pragma unroll
  for (int sq=0; sq<4; sq++){
    float MA[4][4], MB[4][4];
    #pragma unroll
    for (int i=0;i<4;i++)
      #pragma unroll
      for (int r=0;r<4;r++){ float lo=Mm[i][r], hi=Mm[i][4+r]; MA[i][r] = p? hi: lo; MB[i][r] = p? lo: hi; }
    pair_matmul(MA, MB, Mm, Tm);
    #pragma unroll
    for (int i=0;i<4;i++)
      #pragma unroll
      for (int jj=0;jj<8;jj++) Mm[i][jj] = Tm[i][jj];
  }
  const int b_ = row >> 12, t_ = row & 4095;
  const size_t obase = (((size_t)(b_*16 + h))*4096 + (size_t)t_)*64;
  #pragma unroll
  for (int i=0;i<4;i++){
    f32x4 lo = {Mm[i][0],Mm[i][1],Mm[i][2],Mm[i][3]};
    f32x4 hi = {Mm[i][4],Mm[i][5],Mm[i][6],Mm[i][7]};
    *(f32x4*)(O + obase + (size_t)(4*p+i)*8)     = lo;
    *(f32x4*)(O + obase + (size_t)(4*p+i)*8 + 4) = hi;
  }
}

// helpers: 8x8 matvec with 16 f32x4 regs
DEV void load16(const float* p, f32x4* M){
  #pragma unroll
  for (int q=0;q<16;q++) M[q] = *(const f32x4*)(p + 4*q);
}
DEV void rm_matvec8(const f32x4* M16, const float* x, float* res){
  #pragma unroll
  for (int i=0;i<8;i++){
    float acc = 0.f;
    #pragma unroll
    for (int a=0;a<8;a++) acc = fmaf(M16[2*i + (a>>2)][a&3], x[a], acc);
    res[i] = acc;
  }
}
DEV void cm_matvec8(const f32x4* M16, const float* x, float* res){
  #pragma unroll
  for (int i=0;i<8;i++){
    float acc = 0.f;
    #pragma unroll
    for (int a=0;a<8;a++) acc = fmaf(M16[2*a + (i>>2)][i&3], x[a], acc);
    res[i] = acc;
  }
}

// =================== C1: local prefix products within 64-step chunks ===================
__global__ __launch_bounds__(256) void chunkpfx_kernel(float* __restrict__ OR)
{
  int tid = blockIdx.x*256 + threadIdx.x;   // 32768 = 4096 tasks * 8 lanes
  int task = tid >> 3, j = tid & 7;
  int s = task >> 6, c = task & 63;
  float P[8], Pn[8];
  #pragma unroll
  for (int a=0;a<8;a++) P[a] = (a==j) ? 1.f : 0.f;
  float* base = OR + ((size_t)s*4096 + (size_t)c*64)*64;
  for (int tt=0; tt<64; tt++){
    float* slot = base + (size_t)tt*64;
    f32x4 Oc[16];
    load16(slot, Oc);              // O_t row-major
    rm_matvec8(Oc, P, Pn);         // P <- O_t * P
    #pragma unroll
    for (int a=0;a<8;a++) P[a] = Pn[a];
    f32x4 s0 = {P[0],P[1],P[2],P[3]}, s1 = {P[4],P[5],P[6],P[7]};
    *(f32x4*)(slot + j*8)     = s0;   // store col-major (same-wave: loads precede stores)
    *(f32x4*)(slot + j*8 + 4) = s1;
  }
}

// =================== C2: scan of chunk products -> Rbase_c ===================
__global__ __launch_bounds__(256) void chunkscan_kernel(const float* __restrict__ OR, float* __restrict__ Rbase)
{
  int tid = blockIdx.x*256 + threadIdx.x;   // 512 = 64 seqs * 8 lanes
  int s = tid >> 3, j = tid & 7;
  float Rb[8], Rn[8];
  #pragma unroll
  for (int a=0;a<8;a++) Rb[a] = (a==j) ? 1.f : 0.f;
  for (int c=0;c<64;c++){
    float* dst = Rbase + ((size_t)s*64 + c)*64 + j*8;
    f32x4 s0 = {Rb[0],Rb[1],Rb[2],Rb[3]}, s1 = {Rb[4],Rb[5],Rb[6],Rb[7]};
    *(f32x4*)(dst) = s0; *(f32x4*)(dst+4) = s1;     // col-major Rbase_c
    if (c < 63){
      const float* qs = OR + ((size_t)s*4096 + (size_t)(c*64+63))*64;  // Q_c col-major
      f32x4 Q[16];
      load16(qs, Q);
      cm_matvec8(Q, Rb, Rn);       // Rb <- Q_c * Rb
      #pragma unroll
      for (int a=0;a<8;a++) Rb[a] = Rn[a];
    }
  }
}

// =================== C3: compose R_t, normalize k, rotate k/v/q ===================
// scanin aliased into proj's dead skew slots: scanin(s,t) = proj + row*896 + h*28
__global__ __launch_bounds__(256) void rotate_kvq_kernel(float* __restrict__ OR, const float* __restrict__ Rbase,
    float* __restrict__ proj)
{
  int tid = blockIdx.x*256 + threadIdx.x;   // 262144
  int s = tid >> 12, t = tid & 4095;
  int c = t >> 6;
  int b = s >> 4, h = s & 15;
  int row = b*4096 + t;
  float* slot = OR + ((size_t)s*4096 + t)*64;
  f32x4 P4[16];
  load16(slot, P4);                          // P_c(t), col-major
  float* pr = proj + (size_t)row*896;
  float k[8], v[8], q[8];
  { f32x4 a = *(const f32x4*)(pr+448+h*8), b2 = *(const f32x4*)(pr+452+h*8);
    #pragma unroll
    for (int i=0;i<4;i++){ k[i]=a[i]; k[4+i]=b2[i]; } }
  { f32x4 a = *(const f32x4*)(pr+576+h*8), b2 = *(const f32x4*)(pr+580+h*8);
    #pragma unroll
    for (int i=0;i<4;i++){ v[i]=a[i]; v[4+i]=b2[i]; } }
  { f32x4 a = *(const f32x4*)(pr+704+h*8), b2 = *(const f32x4*)(pr+708+h*8);
    #pragma unroll
    for (int i=0;i<4;i++){ q[i]=a[i]; q[4+i]=b2[i]; } }
  float nn = 0.f;
  #pragma unroll
  for (int i=0;i<8;i++) nn = fmaf(k[i],k[i],nn);
  float inv = 1.f / fmaxf(sqrtf(nn), 1e-6f);
  #pragma unroll
  for (int i=0;i<8;i++) k[i] *= inv;

  const float* rb = Rbase + ((size_t)s*64 + c)*64;
  float kt[8], vt[8], qt[8];
  #pragma unroll
  for (int j=0;j<8;j++){
    float rbv[8];
    { f32x4 a = *(const f32x4*)(rb + j*8), b2 = *(const f32x4*)(rb + j*8 + 4);
      #pragma unroll
      for (int i=0;i<4;i++){ rbv[i]=a[i]; rbv[4+i]=b2[i]; } }
    float Rc[8];
    cm_matvec8(P4, rbv, Rc);        // column j of R_t = P * Rbase[:,j]
    f32x4 s0 = {Rc[0],Rc[1],Rc[2],Rc[3]}, s1 = {Rc[4],Rc[5],Rc[6],Rc[7]};
    *(f32x4*)(slot + j*8) = s0; *(f32x4*)(slot + j*8 + 4) = s1;   // R_t col-major (in place)
    float a0=0.f, a1=0.f, a2=0.f;
    #pragma unroll
    for (int i=0;i<8;i++){ a0 = fmaf(Rc[i],k[i],a0); a1 = fmaf(Rc[i],v[i],a1); a2 = fmaf(Rc[i],q[i],a2); }
    kt[j]=a0; vt[j]=a1; qt[j]=a2;
  }
  float beta = pr[832+h];
  float qk = 0.f;
  #pragma unroll
  for (int j=0;j<8;j++) qk = fmaf(kt[j], qt[j], qk);
  float* sip = pr + h*28;     // dead skew slot of this (row,h); writes <448, reads >=448
  f32x4 w0={kt[0],kt[1],kt[2],kt[3]}, w1={kt[4],kt[5],kt[6],kt[7]};
  f32x4 w2={vt[0],vt[1],vt[2],vt[3]}, w3={vt[4],vt[5],vt[6],vt[7]};
  f32x4 w4={qt[0],qt[1],qt[2],qt[3]}, w5={qt[4],qt[5],qt[6],qt[7]};
  f32x4 w6={beta, qk, 0.f, 0.f};
  *(f32x4*)(sip)=w0; *(f32x4*)(sip+4)=w1; *(f32x4*)(sip+8)=w2; *(f32x4*)(sip+12)=w3;
  *(f32x4*)(sip+16)=w4; *(f32x4*)(sip+20)=w5; *(f32x4*)(sip+24)=w6;
}

// =================== D: chunk-parallel delta scan ===================
__global__ __launch_bounds__(256) void scan_pass1_kernel(const float* __restrict__ proj,
    float* __restrict__ Mbuf, float* __restrict__ wbuf)
{
  int tid = blockIdx.x*256 + threadIdx.x;   // 32768 = 4096 tasks * 8 lanes
  int task = tid >> 3, j = tid & 7;         // task = s*64 + c
  int s = task >> 6, c = task & 63;
  int b = s >> 4, h = s & 15;
  const float* rec = proj + ((size_t)b*4096 + (size_t)c*64)*896 + h*28;
  float m[8], w[8];
  #pragma unroll
  for (int i=0;i<8;i++){ m[i] = (i==j)?1.f:0.f; w[i] = 0.f; }
  for (int tt=0; tt<64; tt++){
    const float* p = rec + (size_t)tt*896;
    f32x4 k0 = *(const f32x4*)(p), k1 = *(const f32x4*)(p+4);
    float vt = p[8+j];
    float beta = p[24];
    float s1, s2;
    s1 = ((k0[0]*m[0] + k0[1]*m[1]) + (k0[2]*m[2] + k0[3]*m[3]))
       + ((k1[0]*m[4] + k1[1]*m[5]) + (k1[2]*m[6] + k1[3]*m[7]));
    s2 = ((k0[0]*w[0] + k0[1]*w[1]) + (k0[2]*w[2] + k0[3]*w[3]))
       + ((k1[0]*w[4] + k1[1]*w[5]) + (k1[2]*w[6] + k1[3]*w[7]));
    float c1 = -beta*s1, c2 = beta*(vt - s2);
    #pragma unroll
    for (int i=0;i<4;i++){ m[i] = fmaf(k0[i], c1, m[i]); m[4+i] = fmaf(k1[i], c1, m[4+i]); }
    #pragma unroll
    for (int i=0;i<4;i++){ w[i] = fmaf(k0[i], c2, w[i]); w[4+i] = fmaf(k1[i], c2, w[4+i]); }
  }
  float* md = Mbuf + (size_t)task*64 + j*8;
  float* wd = wbuf + (size_t)task*64 + j*8;
  f32x4 m0={m[0],m[1],m[2],m[3]}, m1={m[4],m[5],m[6],m[7]};
  f32x4 w0={w[0],w[1],w[2],w[3]}, w1={w[4],w[5],w[6],w[7]};
  *(f32x4*)(md) = m0; *(f32x4*)(md+4) = m1;
  *(f32x4*)(wd) = w0; *(f32x4*)(wd+4) = w1;
}

__global__ __launch_bounds__(64) void scan_mid_kernel(const float* __restrict__ Mbuf,
    const float* __restrict__ wbuf, float* __restrict__ dstart)
{
  int tid = blockIdx.x*64 + threadIdx.x;    // 512 = 64 seqs * 8 lanes
  int s = tid >> 3, j = tid & 7;
  float d[8];
  #pragma unroll
  for (int i=0;i<8;i++) d[i] = 0.f;
  size_t base = (size_t)s*64*64;
  f32x4 M[16]; load16(Mbuf + base, M);
  f32x4 wv0 = *(const f32x4*)(wbuf + base + j*8), wv1 = *(const f32x4*)(wbuf + base + j*8 + 4);
  for (int c=0; c<64; c++){
    float* dd = dstart + base + (size_t)c*64 + j*8;
    f32x4 s0 = {d[0],d[1],d[2],d[3]}, s1 = {d[4],d[5],d[6],d[7]};
    *(f32x4*)(dd) = s0; *(f32x4*)(dd+4) = s1;
    float dn[8];
    cm_matvec8(M, d, dn);
    #pragma unroll
    for (int i=0;i<4;i++){ d[i] = dn[i] + wv0[i]; d[4+i] = dn[4+i] + wv1[i]; }
    if (c < 63){
      size_t nb = base + (size_t)(c+1)*64;
      load16(Mbuf + nb, M);
      wv0 = *(const f32x4*)(wbuf + nb + j*8); wv1 = *(const f32x4*)(wbuf + nb + j*8 + 4);
    }
  }
}

__global__ __launch_bounds__(256) void scan_pass2_kernel(const float* __restrict__ proj,
    const float* __restrict__ dstart, float* __restrict__ oo)
{
  int tid = blockIdx.x*256 + threadIdx.x;   // 32768
  int task = tid >> 3, j = tid & 7;
  int s = task >> 6, c = task & 63;
  int b = s >> 4, h = s & 15;
  const float* rec = proj + ((size_t)b*4096 + (size_t)c*64)*896 + h*28;
  float* op = oo + (((size_t)s*4096 + (size_t)c*64)*8) + j;
  float d[8];
  { const float* ds = dstart + (size_t)task*64 + j*8;
    f32x4 a = *(const f32x4*)(ds), b2 = *(const f32x4*)(ds+4);
    #pragma unroll
    for (int i=0;i<4;i++){ d[i]=a[i]; d[4+i]=b2[i]; } }
  for (int tt=0; tt<64; tt++){
    const float* p = rec + (size_t)tt*896;
    f32x4 k0 = *(const f32x4*)(p),    k1 = *(const f32x4*)(p+4);
    f32x4 q0 = *(const f32x4*)(p+16), q1 = *(const f32x4*)(p+20);
    f32x4 mb = *(const f32x4*)(p+24);           // [beta, qk, -, -]
    float vt = p[8+j];
    float kd, qd;
    kd = ((k0[0]*d[0] + k0[1]*d[1]) + (k0[2]*d[2] + k0[3]*d[3]))
       + ((k1[0]*d[4] + k1[1]*d[5]) + (k1[2]*d[6] + k1[3]*d[7]));
    qd = ((q0[0]*d[0] + q0[1]*d[1]) + (q0[2]*d[2] + q0[3]*d[3]))
       + ((q1[0]*d[4] + q1[1]*d[5]) + (q1[2]*d[6] + q1[3]*d[7]));
    float w_ = mb[0] * (vt - kd);
    #pragma unroll
    for (int i=0;i<4;i++){ d[i] = fmaf(k0[i], w_, d[i]); d[4+i] = fmaf(k1[i], w_, d[4+i]); }
    op[(size_t)tt*8] = fmaf(mb[1], w_, qd);
  }
}

// =================== E: rotate outputs back: o = R_t * o~, write bf16 for out-GEMM ===================
__global__ __launch_bounds__(256) void rotout_kernel(const float* __restrict__ OR, const float* __restrict__ oo,
                                                     u16* __restrict__ obf)
{
  int tid = blockIdx.x*256 + threadIdx.x;   // 262144
  int s = tid >> 12, t = tid & 4095;
  int b = s >> 4, h = s & 15;
  int row = b*4096 + t;
  const float* slot = OR + ((size_t)s*4096 + t)*64;
  f32x4 R4[16];
  load16(slot, R4);
  float u[8];
  { const float* up = oo + ((size_t)s*4096 + t)*8;
    f32x4 a = *(const f32x4*)(up), b2 = *(const f32x4*)(up+4);
    #pragma unroll
    for (int i=0;i<4;i++){ u[i]=a[i]; u[4+i]=b2[i]; } }
  float o[8];
  cm_matvec8(R4, u, o);
  u32 p0 = (u32)f2bf(o[0]) | ((u32)f2bf(o[1])<<16);
  u32 p1 = (u32)f2bf(o[2]) | ((u32)f2bf(o[3])<<16);
  u32 p2 = (u32)f2bf(o[4]) | ((u32)f2bf(o[5])<<16);
  u32 p3 = (u32)f2bf(o[6]) | ((u32)f2bf(o[7])<<16);
  u32x4 pk = {p0,p1,p2,p3};
  *(u32x4*)(void*)(obf + (size_t)row*128 + h*8) = pk;
}

// =================== launch ===================
extern "C" void kernel_launch(void* const* d_in, const int* in_sizes, int n_in,
                              void* d_out, int out_size, void* d_ws, size_t ws_size,
                              hipStream_t stream)
{
  const float* x     = (const float*)d_in[0];
  const float* Wskew = (const float*)d_in[1];
  const float* Wk    = (const float*)d_in[2];
  const float* Wv    = (const float*)d_in[3];
  const float* Wq    = (const float*)d_in[4];
  const float* Wbeta = (const float*)d_in[5];
  const float* bbeta = (const float*)d_in[6];
  const float* Wo    = (const float*)d_in[7];

  char* w = (char*)d_ws; size_t off = 0;
  auto alloc = [&](size_t bytes)->void*{ void* p = w + off; off += (bytes + 255) & ~(size_t)255; return p; };
  u16*   Wh     = (u16*)  alloc((size_t)896*1024*2);
  u16*   Wl     = (u16*)  alloc((size_t)896*1024*2);
  u16*   WoT    = (u16*)  alloc((size_t)1024*128*2);
  float* proj   = (float*)alloc((size_t)16384*896*4);
  float* OR     = (float*)alloc((size_t)262144*64*4);
  float* Rbase  = (float*)alloc((size_t)64*64*64*4);
  float* oo     = (float*)alloc((size_t)262144*8*4);
  float* Mbuf   = (float*)alloc((size_t)4096*64*4);
  float* wbuf   = (float*)alloc((size_t)4096*64*4);
  float* dstart = (float*)alloc((size_t)4096*64*4);
  // aliases: xh/xl live only until gemm_proj; OR is written first by expm (after)
  u16*   xh     = (u16*)OR;                       // 32 MB
  u16*   xl     = xh + (size_t)16384*1024;        // 32 MB  (OR region is 64 MB)
  u16*   obf    = (u16*)proj;   // proj fully dead after scan pass2; 4MB << 56MB

  hipLaunchKernelGGL(splitx_kernel, dim3(8192), dim3(256), 0, stream, x, xh, xl);
  hipLaunchKernelGGL(concat_kernel, dim3(4096), dim3(256), 0, stream,
                     Wskew, Wk, Wv, Wq, Wbeta, Wo, Wh, Wl, WoT);
  hipLaunchKernelGGL(gemm_proj_kernel, dim3(128,7), dim3(256), 0, stream,
                     xh, xl, Wh, Wl, proj, bbeta);
  hipLaunchKernelGGL(expm_kernel, dim3(2048), dim3(256), 0, stream, proj, OR);
  hipLaunchKernelGGL(chunkpfx_kernel, dim3(128), dim3(256), 0, stream, OR);
  hipLaunchKernelGGL(chunkscan_kernel, dim3(2), dim3(256), 0, stream, OR, Rbase);
  hipLaunchKernelGGL(rotate_kvq_kernel, dim3(1024), dim3(256), 0, stream, OR, Rbase, proj);
  hipLaunchKernelGGL(scan_pass1_kernel, dim3(128), dim3(256), 0, stream, proj, Mbuf, wbuf);
  hipLaunchKernelGGL(scan_mid_kernel, dim3(8), dim3(64), 0, stream, Mbuf, wbuf, dstart);
  hipLaunchKernelGGL(scan_pass2_kernel, dim3(128), dim3(256), 0, stream, proj, dstart, oo);
  hipLaunchKernelGGL(rotout_kernel, dim3(1024), dim3(256), 0, stream, OR, oo, obf);
  hipLaunchKernelGGL(gemm_out_kernel, dim3(128,8), dim3(256), 0, stream,
                     obf, WoT, (float*)d_out);
}

// Round 3
// 512.874 us; speedup vs baseline: 1.1195x; 1.0289x over previous
//
#include <hip/hip_runtime.h>

typedef unsigned short u16;
typedef unsigned int u32;
typedef __attribute__((ext_vector_type(4))) float f32x4;
typedef __attribute__((ext_vector_type(8))) short short8;
typedef __attribute__((ext_vector_type(4))) unsigned int u32x4;

#define DEV __device__ __forceinline__

DEV float bf2f(u16 u){ union{u32 i; float f;} x; x.i = ((u32)u)<<16; return x.f; }
DEV u16 f2bf(float f){ union{u32 i; float f;} x; x.f = f; u32 r = x.i + 0x7fffu + ((x.i>>16)&1u); return (u16)(r>>16); }

union U8 { u16 u[8]; short8 s; };

// async global -> LDS, 16B per lane (dest must be wave-uniform base + lane*16; ours is tid*16)
DEV void gl16(const u16* g, u16* l){
  __builtin_amdgcn_global_load_lds(
      (const __attribute__((address_space(1))) u32*)g,
      (__attribute__((address_space(3))) u32*)l, 16, 0, 0);
}

// fast tanh/sigmoid via v_exp + v_rcp (err ~1e-6, dwarfed by bf16 input rounding)
DEV float fast_htanh(float v){           // 0.5*tanh(v)
  float vc = fminf(fmaxf(v, -15.f), 15.f);
  float e = __expf(2.f*vc);
  return 0.5f*(e - 1.f)*__builtin_amdgcn_rcpf(e + 1.f);
}
DEV float fast_sigmoid(float v){
  float e = __expf(-v);
  return __builtin_amdgcn_rcpf(1.f + e);
}

// =================== split x into hi/lo bf16 planes ===================
__global__ __launch_bounds__(256) void splitx_kernel(const float* __restrict__ x,
    u16* __restrict__ xh, u16* __restrict__ xl)
{
  size_t base = ((size_t)blockIdx.x*256 + threadIdx.x) * 8;   // 16384*1024/8 threads
  f32x4 a = *(const f32x4*)(x + base), b = *(const f32x4*)(x + base + 4);
  U8 h, l;
  #pragma unroll
  for (int e=0;e<4;e++){
    u16 hh = f2bf(a[e]); h.u[e]   = hh; l.u[e]   = f2bf(a[e] - bf2f(hh));
    u16 gg = f2bf(b[e]); h.u[4+e] = gg; l.u[4+e] = f2bf(b[e] - bf2f(gg));
  }
  *(short8*)(xh + base) = h.s;
  *(short8*)(xl + base) = l.s;
}

// =================== weight concat / transpose -> hi/lo bf16 planes ===================
__global__ __launch_bounds__(256) void concat_kernel(
    const float* __restrict__ Wskew, const float* __restrict__ Wk, const float* __restrict__ Wv,
    const float* __restrict__ Wq, const float* __restrict__ Wbeta, const float* __restrict__ Wo,
    u16* __restrict__ Wh, u16* __restrict__ Wl, u16* __restrict__ WoT)
{
  int idx = blockIdx.x*256 + threadIdx.x;
  if (idx < 896*1024){
    int n = idx >> 10, kk = idx & 1023;
    float v;
    if (n < 448)      v = Wskew[kk*448 + n];
    else if (n < 576) v = Wk[kk*128 + (n-448)];
    else if (n < 704) v = Wv[kk*128 + (n-576)];
    else if (n < 832) v = Wq[kk*128 + (n-704)];
    else if (n < 848) v = Wbeta[kk*16 + (n-832)];
    else              v = 0.f;
    u16 h = f2bf(v);
    Wh[idx] = h;
    Wl[idx] = f2bf(v - bf2f(h));
  } else {
    int r = idx - 896*1024;
    int n = r >> 7, kk = r & 127;
    WoT[r] = f2bf(Wo[kk*1024 + n]);
  }
}

// =================== proj GEMM: double-buffered global_load_lds pipeline ===================
__global__ __launch_bounds__(256) void gemm_proj_kernel(
    const u16* __restrict__ Ah, const u16* __restrict__ Al,
    const u16* __restrict__ Bh, const u16* __restrict__ Bl,
    float* __restrict__ C, const float* __restrict__ bias)
{
  __shared__ u16 L[2*4*4096];
  const int tid = threadIdx.x;
  const int wave = tid >> 6;
  const int lane = tid & 63;
  const int quad = lane >> 4, l15 = lane & 15;
  const int m0 = blockIdx.x * 128, n0 = blockIdx.y * 128;
  const bool full = (blockIdx.y < 4);
  const int wm = (wave >> 1) * 64, wn = (wave & 1) * 64;
  const bool wantLow = full && !(blockIdx.y == 3 && wn == 64);
  const bool skipBl1 = (blockIdx.y == 3);
  const int K = 1024, ldc = 896;
  const int sr = tid >> 2;
  const int sc = tid & 3;
  const int fS = (sr & 3) ^ ((sr >> 2) & 3);
  const int scS = ((sc ^ fS) << 3);
  const size_t gA0 = (size_t)(m0 + sr)*K + scS, gA1 = gA0 + (size_t)64*K;
  const size_t gB0 = (size_t)(n0 + sr)*K + scS, gB1 = gB0 + (size_t)64*K;
  const int d0 = tid*8, d1 = d0 + 2048;
  const int fR = (l15 & 3) ^ ((l15 >> 2) & 3);
  const int rq = ((quad ^ fR) << 3);

  auto STAGE = [&](int buf, int kb){
    u16* Lb = L + buf*16384;
    gl16(Ah + gA0 + kb, Lb + d0);
    gl16(Ah + gA1 + kb, Lb + d1);
    gl16(Bh + gB0 + kb, Lb + 4096 + d0);
    gl16(Bh + gB1 + kb, Lb + 4096 + d1);
    if (full){
      gl16(Al + gA0 + kb, Lb + 8192 + d0);
      gl16(Al + gA1 + kb, Lb + 8192 + d1);
      gl16(Bl + gB0 + kb, Lb + 12288 + d0);
      if (!skipBl1) gl16(Bl + gB1 + kb, Lb + 12288 + d1);
    }
  };

  f32x4 acc[4][4] = {};
  STAGE(0, 0);
  __syncthreads();
  int cur = 0;
  for (int kb = 0; kb < K; kb += 32){
    if (kb + 32 < K) STAGE(cur^1, kb + 32);
    u16* Lb = L + cur*16384;
    short8 afh[4], bfh[4];
    #pragma unroll
    for (int mi=0;mi<4;mi++) afh[mi] = *(const short8*)&Lb[(wm + mi*16 + l15)*32 + rq];
    #pragma unroll
    for (int ni=0;ni<4;ni++) bfh[ni] = *(const short8*)&Lb[4096 + (wn + ni*16 + l15)*32 + rq];
    #pragma unroll
    for (int mi=0;mi<4;mi++)
      #pragma unroll
      for (int ni=0;ni<4;ni++)
        acc[mi][ni] = __builtin_amdgcn_mfma_f32_16x16x32_bf16(afh[mi], bfh[ni], acc[mi][ni], 0,0,0);
    if (wantLow){
      short8 afl[4], bfl[4];
      #pragma unroll
      for (int mi=0;mi<4;mi++) afl[mi] = *(const short8*)&Lb[8192 + (wm + mi*16 + l15)*32 + rq];
      #pragma unroll
      for (int ni=0;ni<4;ni++) bfl[ni] = *(const short8*)&Lb[12288 + (wn + ni*16 + l15)*32 + rq];
      #pragma unroll
      for (int mi=0;mi<4;mi++)
        #pragma unroll
        for (int ni=0;ni<4;ni++){
          acc[mi][ni] = __builtin_amdgcn_mfma_f32_16x16x32_bf16(afh[mi], bfl[ni], acc[mi][ni], 0,0,0);
          acc[mi][ni] = __builtin_amdgcn_mfma_f32_16x16x32_bf16(afl[mi], bfh[ni], acc[mi][ni], 0,0,0);
        }
    }
    __syncthreads();
    cur ^= 1;
  }
  #pragma unroll
  for (int mi=0;mi<4;mi++){
    #pragma unroll
    for (int ni=0;ni<4;ni++){
      const int col = n0 + wn + ni*16 + l15;
      const int rb_ = m0 + wm + mi*16 + quad*4;
      #pragma unroll
      for (int r=0;r<4;r++){
        float v = acc[mi][ni][r];
        const int row = rb_ + r;
        if (col < 448) v = fast_htanh(v);
        else if (col >= 832 && col < 848) v = fast_sigmoid(v + bias[col-832]);
        C[(size_t)row*ldc + col] = v;
      }
    }
  }
}

// =================== output GEMM: bf16 A/Bt -> fp32 C (dbuf pipeline, K=128) ===================
__global__ __launch_bounds__(256) void gemm_out_kernel(
    const u16* __restrict__ A, const u16* __restrict__ Bt, float* __restrict__ C)
{
  __shared__ u16 L[2*2*4096];
  const int tid = threadIdx.x;
  const int wave = tid >> 6;
  const int lane = tid & 63;
  const int quad = lane >> 4, l15 = lane & 15;
  const int m0 = blockIdx.x * 128, n0 = blockIdx.y * 128;
  const int wm = (wave >> 1) * 64, wn = (wave & 1) * 64;
  const int K = 128, ldc = 1024;
  const int sr = tid >> 2;
  const int sc = tid & 3;
  const int fS = (sr & 3) ^ ((sr >> 2) & 3);
  const int scS = ((sc ^ fS) << 3);
  const size_t gA0 = (size_t)(m0 + sr)*K + scS, gA1 = gA0 + (size_t)64*K;
  const size_t gB0 = (size_t)(n0 + sr)*K + scS, gB1 = gB0 + (size_t)64*K;
  const int d0 = tid*8, d1 = d0 + 2048;
  const int fR = (l15 & 3) ^ ((l15 >> 2) & 3);
  const int rq = ((quad ^ fR) << 3);

  auto STAGE = [&](int buf, int kb){
    u16* Lb = L + buf*8192;
    gl16(A  + gA0 + kb, Lb + d0);
    gl16(A  + gA1 + kb, Lb + d1);
    gl16(Bt + gB0 + kb, Lb + 4096 + d0);
    gl16(Bt + gB1 + kb, Lb + 4096 + d1);
  };

  f32x4 acc[4][4] = {};
  STAGE(0, 0);
  __syncthreads();
  int cur = 0;
  for (int kb = 0; kb < K; kb += 32){
    if (kb + 32 < K) STAGE(cur^1, kb + 32);
    u16* Lb = L + cur*8192;
    short8 af[4], bf8[4];
    #pragma unroll
    for (int mi=0;mi<4;mi++) af[mi] = *(const short8*)&Lb[(wm + mi*16 + l15)*32 + rq];
    #pragma unroll
    for (int ni=0;ni<4;ni++) bf8[ni] = *(const short8*)&Lb[4096 + (wn + ni*16 + l15)*32 + rq];
    #pragma unroll
    for (int mi=0;mi<4;mi++)
      #pragma unroll
      for (int ni=0;ni<4;ni++)
        acc[mi][ni] = __builtin_amdgcn_mfma_f32_16x16x32_bf16(af[mi], bf8[ni], acc[mi][ni], 0,0,0);
    __syncthreads();
    cur ^= 1;
  }
  #pragma unroll
  for (int mi=0;mi<4;mi++)
    #pragma unroll
    for (int ni=0;ni<4;ni++){
      const int col = n0 + wn + ni*16 + l15;
      const int rb_ = m0 + wm + mi*16 + quad*4;
      #pragma unroll
      for (int r=0;r<4;r++)
        C[(size_t)(rb_ + r)*ldc + col] = acc[mi][ni][r];
    }
}

// =================== fused expm + chunk prefix scan ===================
// One block per (seq s, chunk c). Phase 1: expm (2 lanes/matrix, threads 0..127) -> LDS row-major.
// Phase 2: Hillis-Steele inclusive scan over 64 matrices, S_i <- S_i * S_{i-2^d} (newer LEFT),
//          ping-pong LDS, 6 levels. Phase 3: write P_c(t) col-major to OR.
__device__ constexpr int TRI_I[28] = {0,0,0,0,0,0,0, 1,1,1,1,1,1, 2,2,2,2,2, 3,3,3,3, 4,4,4, 5,5, 6};
__device__ constexpr int TRI_J[28] = {1,2,3,4,5,6,7, 2,3,4,5,6,7, 3,4,5,6,7, 4,5,6,7, 5,6,7, 6,7, 7};

DEV void pair_matmul(const float XA[4][4], const float XB[4][4], const float Mm[4][8], float Tm[4][8]){
  float Yo[4][8];
  #pragma unroll
  for (int r=0;r<4;r++)
    #pragma unroll
    for (int jj=0;jj<8;jj++) Yo[r][jj] = __shfl_xor(Mm[r][jj], 1);
  #pragma unroll
  for (int i=0;i<4;i++)
    #pragma unroll
    for (int jj=0;jj<8;jj++){
      float acc = 0.f;
      #pragma unroll
      for (int r=0;r<4;r++){ acc = fmaf(XA[i][r], Mm[r][jj], acc); acc = fmaf(XB[i][r], Yo[r][jj], acc); }
      Tm[i][jj] = acc;
    }
}

__global__ __launch_bounds__(256) void expm_scan_kernel(const float* __restrict__ proj, float* __restrict__ OR)
{
  __shared__ float S0[64*68];
  __shared__ float S1[64*68];
  const int tid = threadIdx.x;
  const int s = blockIdx.x >> 6, c = blockIdx.x & 63;   // 4096 blocks
  const int b = s >> 4, h = s & 15;

  if (tid < 128){
    const int m = tid >> 1;        // timestep within chunk
    const int p = tid & 1;         // rows 4p..4p+3
    const int row = b*4096 + c*64 + m;
    const float* sk = proj + (size_t)row*896 + h*28;
    float Bm[4][8];
    #pragma unroll
    for (int i=0;i<4;i++)
      #pragma unroll
      for (int jj=0;jj<8;jj++) Bm[i][jj] = 0.f;
    #pragma unroll
    for (int cc=0;cc<28;cc++){
      const int ti = TRI_I[cc], tj = TRI_J[cc];
      float v = sk[cc] * 0.0625f;      // A/16 (scaling-and-squaring s=4)
      if (p==0){
        if (ti < 4) Bm[ti][tj] = v;
        if (tj < 4) Bm[tj][ti] = -v;
      } else {
        if (ti >= 4) Bm[ti-4][tj] = v;
        if (tj >= 4) Bm[tj-4][ti] = -v;
      }
    }
    float BA[4][4], BB[4][4];
    #pragma unroll
    for (int i=0;i<4;i++)
      #pragma unroll
      for (int r=0;r<4;r++){ float lo=Bm[i][r], hi=Bm[i][4+r]; BA[i][r] = p? hi: lo; BB[i][r] = p? lo: hi; }

    float Mm[4][8], Tm[4][8];
    #pragma unroll
    for (int i=0;i<4;i++)
      #pragma unroll
      for (int jj=0;jj<8;jj++) Mm[i][jj] = Bm[i][jj]*(1.f/6.f) + (((4*p+i)==jj)?1.f:0.f);
    const float coef[5] = {0.2f, 0.25f, 1.f/3.f, 0.5f, 1.f};
    #pragma unroll
    for (int st=0; st<5; st++){
      pair_matmul(BA, BB, Mm, Tm);
      #pragma unroll
      for (int i=0;i<4;i++)
        #pragma unroll
        for (int jj=0;jj<8;jj++) Mm[i][jj] = Tm[i][jj]*coef[st] + (((4*p+i)==jj)?1.f:0.f);
    }
    #pragma unroll
    for (int sq=0; sq<4; sq++){
      float MA[4][4], MB[4][4];
      #pragma unroll
      for (int i=0;i<4;i++)
        #pragma unroll
        for (int r=0;r<4;r++){ float lo=Mm[i][r], hi=Mm[i][4+r]; MA[i][r] = p? hi: lo; MB[i][r] = p? lo: hi; }
      pair_matmul(MA, MB, Mm, Tm);
      #pragma unroll
      for (int i=0;i<4;i++)
        #pragma unroll
        for (int jj=0;jj<8;jj++) Mm[i][jj] = Tm[i][jj];
    }
    float* dst = S0 + m*68;
    #pragma unroll
    for (int i=0;i<4;i++)
      #pragma unroll
      for (int jj=0;jj<8;jj++) dst[(4*p+i)*8 + jj] = Mm[i][jj];
  }
  __syncthreads();

  // Hillis-Steele: 6 levels. Level d even: S0->S1, odd: S1->S0. Result in S0.
  const int mi = tid >> 2, q = tid & 3;     // thread owns rows 2q,2q+1 of matrix mi
  #pragma unroll
  for (int d=0; d<6; d++){
    const int off = 1 << d;
    const float* src = (d & 1) ? S1 : S0;
    float* dstb = (d & 1) ? S0 : S1;
    float r0[8], r1[8];
    if (mi >= off){
      const float* A = src + mi*68 + q*16;
      const float* Bp = src + (mi-off)*68;
      float a0[8], a1[8];
      #pragma unroll
      for (int a2=0;a2<8;a2++){ a0[a2]=A[a2]; a1[a2]=A[8+a2]; }
      #pragma unroll
      for (int cc=0;cc<8;cc++){ r0[cc]=0.f; r1[cc]=0.f; }
      #pragma unroll
      for (int a2=0;a2<8;a2++){
        #pragma unroll
        for (int cc=0;cc<8;cc++){
          float bv = Bp[a2*8+cc];
          r0[cc] = fmaf(a0[a2], bv, r0[cc]);
          r1[cc] = fmaf(a1[a2], bv, r1[cc]);
        }
      }
    } else {
      const float* A = src + mi*68 + q*16;
      #pragma unroll
      for (int cc=0;cc<8;cc++){ r0[cc]=A[cc]; r1[cc]=A[8+cc]; }
    }
    float* D = dstb + mi*68 + q*16;
    #pragma unroll
    for (int cc=0;cc<8;cc++){ D[cc]=r0[cc]; D[8+cc]=r1[cc]; }
    __syncthreads();
  }

  // write-out: P_c(t) col-major (slot flat a*8+i = S_t[i][a])
  const int t = tid >> 2, qq = tid & 3;
  const size_t base = ((size_t)s*4096 + (size_t)c*64 + t)*64 + qq*16;
  float out[16];
  #pragma unroll
  for (int f=0; f<16; f++){
    int a = 2*qq + (f>>3), i = f&7;
    out[f] = S0[t*68 + i*8 + a];
  }
  f32x4 o0={out[0],out[1],out[2],out[3]},  o1={out[4],out[5],out[6],out[7]};
  f32x4 o2={out[8],out[9],out[10],out[11]}, o3={out[12],out[13],out[14],out[15]};
  *(f32x4*)(OR + base)      = o0;
  *(f32x4*)(OR + base + 4)  = o1;
  *(f32x4*)(OR + base + 8)  = o2;
  *(f32x4*)(OR + base + 12) = o3;
}

// helpers: 8x8 matvec with 16 f32x4 regs
DEV void load16(const float* p, f32x4* M){
  #pragma unroll
  for (int q=0;q<16;q++) M[q] = *(const f32x4*)(p + 4*q);
}
// flat[i*8+a]*x[a]: for col-major storage this is M^T x; for row-major it's M x
DEV void rm_matvec8(const f32x4* M16, const float* x, float* res){
  #pragma unroll
  for (int i=0;i<8;i++){
    float acc = 0.f;
    #pragma unroll
    for (int a=0;a<8;a++) acc = fmaf(M16[2*i + (a>>2)][a&3], x[a], acc);
    res[i] = acc;
  }
}
// flat[a*8+i]*x[a]: for col-major storage this is M x
DEV void cm_matvec8(const f32x4* M16, const float* x, float* res){
  #pragma unroll
  for (int i=0;i<8;i++){
    float acc = 0.f;
    #pragma unroll
    for (int a=0;a<8;a++) acc = fmaf(M16[2*a + (i>>2)][i&3], x[a], acc);
    res[i] = acc;
  }
}

// =================== C2: scan of chunk products -> Rbase_c ===================
__global__ __launch_bounds__(256) void chunkscan_kernel(const float* __restrict__ OR, float* __restrict__ Rbase)
{
  int tid = blockIdx.x*256 + threadIdx.x;   // 512 = 64 seqs * 8 lanes
  int s = tid >> 3, j = tid & 7;
  float Rb[8], Rn[8];
  #pragma unroll
  for (int a=0;a<8;a++) Rb[a] = (a==j) ? 1.f : 0.f;
  for (int c=0;c<64;c++){
    float* dst = Rbase + ((size_t)s*64 + c)*64 + j*8;
    f32x4 s0 = {Rb[0],Rb[1],Rb[2],Rb[3]}, s1 = {Rb[4],Rb[5],Rb[6],Rb[7]};
    *(f32x4*)(dst) = s0; *(f32x4*)(dst+4) = s1;     // col-major Rbase_c
    if (c < 63){
      const float* qs = OR + ((size_t)s*4096 + (size_t)(c*64+63))*64;  // Q_c col-major
      f32x4 Q[16];
      load16(qs, Q);
      cm_matvec8(Q, Rb, Rn);       // Rb <- Q_c * Rb
      #pragma unroll
      for (int a=0;a<8;a++) Rb[a] = Rn[a];
    }
  }
}

// =================== C3: rotate k/v/q via R_t^T = Rbase^T (P^T .) — no R materialization ===================
__global__ __launch_bounds__(256) void rotate_kvq_kernel(const float* __restrict__ OR, const float* __restrict__ Rbase,
    float* __restrict__ proj)
{
  int tid = blockIdx.x*256 + threadIdx.x;   // 262144
  int s = tid >> 12, t = tid & 4095;
  int c = t >> 6;
  int b = s >> 4, h = s & 15;
  int row = b*4096 + t;
  const float* slot = OR + ((size_t)s*4096 + t)*64;
  float* pr = proj + (size_t)row*896;
  float k[8], v[8], q[8];
  { f32x4 a = *(const f32x4*)(pr+448+h*8), b2 = *(const f32x4*)(pr+452+h*8);
    #pragma unroll
    for (int i=0;i<4;i++){ k[i]=a[i]; k[4+i]=b2[i]; } }
  { f32x4 a = *(const f32x4*)(pr+576+h*8), b2 = *(const f32x4*)(pr+580+h*8);
    #pragma unroll
    for (int i=0;i<4;i++){ v[i]=a[i]; v[4+i]=b2[i]; } }
  { f32x4 a = *(const f32x4*)(pr+704+h*8), b2 = *(const f32x4*)(pr+708+h*8);
    #pragma unroll
    for (int i=0;i<4;i++){ q[i]=a[i]; q[4+i]=b2[i]; } }
  float nn = 0.f;
  #pragma unroll
  for (int i=0;i<8;i++) nn = fmaf(k[i],k[i],nn);
  float inv = 1.f / fmaxf(sqrtf(nn), 1e-6f);
  #pragma unroll
  for (int i=0;i<8;i++) k[i] *= inv;

  f32x4 M[16];
  load16(slot, M);                           // P col-major -> rm gives P^T x
  float uk[8], uv[8], uq[8];
  rm_matvec8(M, k, uk);
  rm_matvec8(M, v, uv);
  rm_matvec8(M, q, uq);
  load16(Rbase + ((size_t)s*64 + c)*64, M);  // Rbase col-major -> rm gives Rbase^T x
  float kt[8], vt[8], qt[8];
  rm_matvec8(M, uk, kt);
  rm_matvec8(M, uv, vt);
  rm_matvec8(M, uq, qt);

  float beta = pr[832+h];
  float qk = 0.f;
  #pragma unroll
  for (int j=0;j<8;j++) qk = fmaf(kt[j], qt[j], qk);
  float* sip = pr + h*28;     // dead skew slot of this (row,h); writes <448, reads >=448
  f32x4 w0={kt[0],kt[1],kt[2],kt[3]}, w1={kt[4],kt[5],kt[6],kt[7]};
  f32x4 w2={vt[0],vt[1],vt[2],vt[3]}, w3={vt[4],vt[5],vt[6],vt[7]};
  f32x4 w4={qt[0],qt[1],qt[2],qt[3]}, w5={qt[4],qt[5],qt[6],qt[7]};
  f32x4 w6={beta, qk, 0.f, 0.f};
  *(f32x4*)(sip)=w0; *(f32x4*)(sip+4)=w1; *(f32x4*)(sip+8)=w2; *(f32x4*)(sip+12)=w3;
  *(f32x4*)(sip+16)=w4; *(f32x4*)(sip+20)=w5; *(f32x4*)(sip+24)=w6;
}

// =================== D: chunk-parallel delta scan (128 chunks x 32 steps) ===================
__global__ __launch_bounds__(256) void scan_pass1_kernel(const float* __restrict__ proj,
    float* __restrict__ Mbuf, float* __restrict__ wbuf)
{
  int tid = blockIdx.x*256 + threadIdx.x;   // 65536 = 8192 tasks * 8 lanes
  int task = tid >> 3, j = tid & 7;         // task = s*128 + c
  int s = task >> 7, c = task & 127;
  int b = s >> 4, h = s & 15;
  const float* rec = proj + ((size_t)b*4096 + (size_t)c*32)*896 + h*28;
  float m[8], w[8];
  #pragma unroll
  for (int i=0;i<8;i++){ m[i] = (i==j)?1.f:0.f; w[i] = 0.f; }
  f32x4 k0 = *(const f32x4*)(rec), k1 = *(const f32x4*)(rec+4);
  float vt = rec[8+j];
  float beta = rec[24];
  for (int tt=0; tt<32; tt++){
    const float* pn = rec + (size_t)(tt+1)*896;   // prefetch (last iter reads in-ws garbage, unused)
    f32x4 nk0 = *(const f32x4*)(pn), nk1 = *(const f32x4*)(pn+4);
    float nvt = pn[8+j];
    float nbeta = pn[24];
    float s1, s2;
    s1 = ((k0[0]*m[0] + k0[1]*m[1]) + (k0[2]*m[2] + k0[3]*m[3]))
       + ((k1[0]*m[4] + k1[1]*m[5]) + (k1[2]*m[6] + k1[3]*m[7]));
    s2 = ((k0[0]*w[0] + k0[1]*w[1]) + (k0[2]*w[2] + k0[3]*w[3]))
       + ((k1[0]*w[4] + k1[1]*w[5]) + (k1[2]*w[6] + k1[3]*w[7]));
    float c1 = -beta*s1, c2 = beta*(vt - s2);
    #pragma unroll
    for (int i=0;i<4;i++){ m[i] = fmaf(k0[i], c1, m[i]); m[4+i] = fmaf(k1[i], c1, m[4+i]); }
    #pragma unroll
    for (int i=0;i<4;i++){ w[i] = fmaf(k0[i], c2, w[i]); w[4+i] = fmaf(k1[i], c2, w[4+i]); }
    k0=nk0; k1=nk1; vt=nvt; beta=nbeta;
  }
  float* md = Mbuf + (size_t)task*64 + j*8;
  float* wd = wbuf + (size_t)task*64 + j*8;
  f32x4 m0={m[0],m[1],m[2],m[3]}, m1={m[4],m[5],m[6],m[7]};
  f32x4 w0={w[0],w[1],w[2],w[3]}, w1={w[4],w[5],w[6],w[7]};
  *(f32x4*)(md) = m0; *(f32x4*)(md+4) = m1;
  *(f32x4*)(wd) = w0; *(f32x4*)(wd+4) = w1;
}

__global__ __launch_bounds__(64) void scan_mid_kernel(const float* __restrict__ Mbuf,
    const float* __restrict__ wbuf, float* __restrict__ dstart)
{
  int tid = blockIdx.x*64 + threadIdx.x;    // 512 = 64 seqs * 8 lanes
  int s = tid >> 3, j = tid & 7;
  float d[8];
  #pragma unroll
  for (int i=0;i<8;i++) d[i] = 0.f;
  size_t base = (size_t)s*128*64;
  f32x4 M[16]; load16(Mbuf + base, M);
  f32x4 wv0 = *(const f32x4*)(wbuf + base + j*8), wv1 = *(const f32x4*)(wbuf + base + j*8 + 4);
  for (int c=0; c<128; c++){
    float* dd = dstart + base + (size_t)c*64 + j*8;
    f32x4 s0 = {d[0],d[1],d[2],d[3]}, s1 = {d[4],d[5],d[6],d[7]};
    *(f32x4*)(dd) = s0; *(f32x4*)(dd+4) = s1;
    float dn[8];
    cm_matvec8(M, d, dn);
    #pragma unroll
    for (int i=0;i<4;i++){ d[i] = dn[i] + wv0[i]; d[4+i] = dn[4+i] + wv1[i]; }
    if (c < 127){
      size_t nb = base + (size_t)(c+1)*64;
      load16(Mbuf + nb, M);
      wv0 = *(const f32x4*)(wbuf + nb + j*8); wv1 = *(const f32x4*)(wbuf + nb + j*8 + 4);
    }
  }
}

__global__ __launch_bounds__(256) void scan_pass2_kernel(const float* __restrict__ proj,
    const float* __restrict__ dstart, float* __restrict__ oo)
{
  int tid = blockIdx.x*256 + threadIdx.x;   // 65536
  int task = tid >> 3, j = tid & 7;
  int s = task >> 7, c = task & 127;
  int b = s >> 4, h = s & 15;
  const float* rec = proj + ((size_t)b*4096 + (size_t)c*32)*896 + h*28;
  float* op = oo + (((size_t)s*4096 + (size_t)c*32)*8) + j;
  float d[8];
  { const float* ds = dstart + (size_t)task*64 + j*8;
    f32x4 a = *(const f32x4*)(ds), b2 = *(const f32x4*)(ds+4);
    #pragma unroll
    for (int i=0;i<4;i++){ d[i]=a[i]; d[4+i]=b2[i]; } }
  f32x4 k0 = *(const f32x4*)(rec),    k1 = *(const f32x4*)(rec+4);
  f32x4 q0 = *(const f32x4*)(rec+16), q1 = *(const f32x4*)(rec+20);
  f32x4 mb = *(const f32x4*)(rec+24);
  float vt = rec[8+j];
  for (int tt=0; tt<32; tt++){
    const float* pn = rec + (size_t)(tt+1)*896;   // prefetch
    f32x4 nk0 = *(const f32x4*)(pn),    nk1 = *(const f32x4*)(pn+4);
    f32x4 nq0 = *(const f32x4*)(pn+16), nq1 = *(const f32x4*)(pn+20);
    f32x4 nmb = *(const f32x4*)(pn+24);
    float nvt = pn[8+j];
    float kd, qd;
    kd = ((k0[0]*d[0] + k0[1]*d[1]) + (k0[2]*d[2] + k0[3]*d[3]))
       + ((k1[0]*d[4] + k1[1]*d[5]) + (k1[2]*d[6] + k1[3]*d[7]));
    qd = ((q0[0]*d[0] + q0[1]*d[1]) + (q0[2]*d[2] + q0[3]*d[3]))
       + ((q1[0]*d[4] + q1[1]*d[5]) + (q1[2]*d[6] + q1[3]*d[7]));
    float w_ = mb[0] * (vt - kd);
    #pragma unroll
    for (int i=0;i<4;i++){ d[i] = fmaf(k0[i], w_, d[i]); d[4+i] = fmaf(k1[i], w_, d[4+i]); }
    op[(size_t)tt*8] = fmaf(mb[1], w_, qd);
    k0=nk0; k1=nk1; q0=nq0; q1=nq1; mb=nmb; vt=nvt;
  }
}

// =================== E: rotate outputs back: o = P (Rbase o~), write bf16 ===================
__global__ __launch_bounds__(256) void rotout_kernel(const float* __restrict__ OR, const float* __restrict__ Rbase,
                                                     const float* __restrict__ oo, u16* __restrict__ obf)
{
  int tid = blockIdx.x*256 + threadIdx.x;   // 262144
  int s = tid >> 12, t = tid & 4095;
  int c = t >> 6;
  int b = s >> 4, h = s & 15;
  int row = b*4096 + t;
  float u[8];
  { const float* up = oo + ((size_t)s*4096 + t)*8;
    f32x4 a = *(const f32x4*)(up), b2 = *(const f32x4*)(up+4);
    #pragma unroll
    for (int i=0;i<4;i++){ u[i]=a[i]; u[4+i]=b2[i]; } }
  f32x4 M[16];
  load16(Rbase + ((size_t)s*64 + c)*64, M);  // col-major -> cm gives Rbase * u
  float w[8];
  cm_matvec8(M, u, w);
  load16(OR + ((size_t)s*4096 + t)*64, M);   // P col-major -> cm gives P * w
  float o[8];
  cm_matvec8(M, w, o);
  u32 p0 = (u32)f2bf(o[0]) | ((u32)f2bf(o[1])<<16);
  u32 p1 = (u32)f2bf(o[2]) | ((u32)f2bf(o[3])<<16);
  u32 p2 = (u32)f2bf(o[4]) | ((u32)f2bf(o[5])<<16);
  u32 p3 = (u32)f2bf(o[6]) | ((u32)f2bf(o[7])<<16);
  u32x4 pk = {p0,p1,p2,p3};
  *(u32x4*)(void*)(obf + (size_t)row*128 + h*8) = pk;
}

// =================== launch ===================
extern "C" void kernel_launch(void* const* d_in, const int* in_sizes, int n_in,
                              void* d_out, int out_size, void* d_ws, size_t ws_size,
                              hipStream_t stream)
{
  const float* x     = (const float*)d_in[0];
  const float* Wskew = (const float*)d_in[1];
  const float* Wk    = (const float*)d_in[2];
  const float* Wv    = (const float*)d_in[3];
  const float* Wq    = (const float*)d_in[4];
  const float* Wbeta = (const float*)d_in[5];
  const float* bbeta = (const float*)d_in[6];
  const float* Wo    = (const float*)d_in[7];

  char* w = (char*)d_ws; size_t off = 0;
  auto alloc = [&](size_t bytes)->void*{ void* p = w + off; off += (bytes + 255) & ~(size_t)255; return p; };
  u16*   Wh     = (u16*)  alloc((size_t)896*1024*2);
  u16*   Wl     = (u16*)  alloc((size_t)896*1024*2);
  u16*   WoT    = (u16*)  alloc((size_t)1024*128*2);
  float* proj   = (float*)alloc((size_t)16384*896*4);
  float* OR     = (float*)alloc((size_t)262144*64*4);
  float* Rbase  = (float*)alloc((size_t)64*64*64*4);
  float* oo     = (float*)alloc((size_t)262144*8*4);
  float* Mbuf   = (float*)alloc((size_t)8192*64*4);
  float* wbuf   = (float*)alloc((size_t)8192*64*4);
  float* dstart = (float*)alloc((size_t)8192*64*4);
  // aliases: xh/xl live only until gemm_proj; OR is written first by expm_scan (after)
  u16*   xh     = (u16*)OR;                       // 32 MB
  u16*   xl     = xh + (size_t)16384*1024;        // 32 MB  (OR region is 64 MB)
  u16*   obf    = (u16*)proj;   // proj fully dead after scan pass2

  hipLaunchKernelGGL(splitx_kernel, dim3(8192), dim3(256), 0, stream, x, xh, xl);
  hipLaunchKernelGGL(concat_kernel, dim3(4096), dim3(256), 0, stream,
                     Wskew, Wk, Wv, Wq, Wbeta, Wo, Wh, Wl, WoT);
  hipLaunchKernelGGL(gemm_proj_kernel, dim3(128,7), dim3(256), 0, stream,
                     xh, xl, Wh, Wl, proj, bbeta);
  hipLaunchKernelGGL(expm_scan_kernel, dim3(4096), dim3(256), 0, stream, proj, OR);
  hipLaunchKernelGGL(chunkscan_kernel, dim3(2), dim3(256), 0, stream, OR, Rbase);
  hipLaunchKernelGGL(rotate_kvq_kernel, dim3(1024), dim3(256), 0, stream, OR, Rbase, proj);
  hipLaunchKernelGGL(scan_pass1_kernel, dim3(256), dim3(256), 0, stream, proj, Mbuf, wbuf);
  hipLaunchKernelGGL(scan_mid_kernel, dim3(8), dim3(64), 0, stream, Mbuf, wbuf, dstart);
  hipLaunchKernelGGL(scan_pass2_kernel, dim3(256), dim3(256), 0, stream, proj, dstart, oo);
  hipLaunchKernelGGL(rotout_kernel, dim3(1024), dim3(256), 0, stream, OR, Rbase, oo, obf);
  hipLaunchKernelGGL(gemm_out_kernel, dim3(128,8), dim3(256), 0, stream,
                     obf, WoT, (float*)d_out);
}

// Round 4
// 476.685 us; speedup vs baseline: 1.2045x; 1.0759x over previous
//
#include <hip/hip_runtime.h>

typedef unsigned short u16;
typedef unsigned int u32;
typedef __attribute__((ext_vector_type(4))) float f32x4;
typedef __attribute__((ext_vector_type(8))) short short8;
typedef __attribute__((ext_vector_type(4))) unsigned int u32x4;

#define DEV __device__ __forceinline__

DEV float bf2f(u16 u){ union{u32 i; float f;} x; x.i = ((u32)u)<<16; return x.f; }
DEV u16 f2bf(float f){ union{u32 i; float f;} x; x.f = f; u32 r = x.i + 0x7fffu + ((x.i>>16)&1u); return (u16)(r>>16); }

union U8 { u16 u[8]; short8 s; };

// async global -> LDS, 16B per lane (dest must be wave-uniform base + lane*16; ours is tid*16)
DEV void gl16(const u16* g, u16* l){
  __builtin_amdgcn_global_load_lds(
      (const __attribute__((address_space(1))) u32*)g,
      (__attribute__((address_space(3))) u32*)l, 16, 0, 0);
}

// fast tanh/sigmoid via v_exp + v_rcp (err ~1e-6, dwarfed by bf16 input rounding)
DEV float fast_htanh(float v){           // 0.5*tanh(v)
  float vc = fminf(fmaxf(v, -15.f), 15.f);
  float e = __expf(2.f*vc);
  return 0.5f*(e - 1.f)*__builtin_amdgcn_rcpf(e + 1.f);
}
DEV float fast_sigmoid(float v){
  float e = __expf(-v);
  return __builtin_amdgcn_rcpf(1.f + e);
}

// =================== split x into hi/lo bf16 planes ===================
__global__ __launch_bounds__(256) void splitx_kernel(const float* __restrict__ x,
    u16* __restrict__ xh, u16* __restrict__ xl)
{
  size_t base = ((size_t)blockIdx.x*256 + threadIdx.x) * 8;   // 16384*1024/8 threads
  f32x4 a = *(const f32x4*)(x + base), b = *(const f32x4*)(x + base + 4);
  U8 h, l;
  #pragma unroll
  for (int e=0;e<4;e++){
    u16 hh = f2bf(a[e]); h.u[e]   = hh; l.u[e]   = f2bf(a[e] - bf2f(hh));
    u16 gg = f2bf(b[e]); h.u[4+e] = gg; l.u[4+e] = f2bf(b[e] - bf2f(gg));
  }
  *(short8*)(xh + base) = h.s;
  *(short8*)(xl + base) = l.s;
}

// =================== weight concat / transpose -> hi/lo bf16 planes ===================
__global__ __launch_bounds__(256) void concat_kernel(
    const float* __restrict__ Wskew, const float* __restrict__ Wk, const float* __restrict__ Wv,
    const float* __restrict__ Wq, const float* __restrict__ Wbeta, const float* __restrict__ Wo,
    u16* __restrict__ Wh, u16* __restrict__ Wl, u16* __restrict__ WoT)
{
  int idx = blockIdx.x*256 + threadIdx.x;
  if (idx < 896*1024){
    int n = idx >> 10, kk = idx & 1023;
    float v;
    if (n < 448)      v = Wskew[kk*448 + n];
    else if (n < 576) v = Wk[kk*128 + (n-448)];
    else if (n < 704) v = Wv[kk*128 + (n-576)];
    else if (n < 832) v = Wq[kk*128 + (n-704)];
    else if (n < 848) v = Wbeta[kk*16 + (n-832)];
    else              v = 0.f;
    u16 h = f2bf(v);
    Wh[idx] = h;
    Wl[idx] = f2bf(v - bf2f(h));
  } else {
    int r = idx - 896*1024;
    int n = r >> 7, kk = r & 127;
    WoT[r] = f2bf(Wo[kk*1024 + n]);
  }
}

// =================== proj GEMM: double-buffered global_load_lds pipeline ===================
__global__ __launch_bounds__(256) void gemm_proj_kernel(
    const u16* __restrict__ Ah, const u16* __restrict__ Al,
    const u16* __restrict__ Bh, const u16* __restrict__ Bl,
    float* __restrict__ C, const float* __restrict__ bias)
{
  __shared__ u16 L[2*4*4096];
  const int tid = threadIdx.x;
  const int wave = tid >> 6;
  const int lane = tid & 63;
  const int quad = lane >> 4, l15 = lane & 15;
  const int m0 = blockIdx.x * 128, n0 = blockIdx.y * 128;
  const bool full = (blockIdx.y < 4);
  const int wm = (wave >> 1) * 64, wn = (wave & 1) * 64;
  const bool wantLow = full && !(blockIdx.y == 3 && wn == 64);
  const bool skipBl1 = (blockIdx.y == 3);
  const int K = 1024, ldc = 896;
  const int sr = tid >> 2;
  const int sc = tid & 3;
  const int fS = (sr & 3) ^ ((sr >> 2) & 3);
  const int scS = ((sc ^ fS) << 3);
  const size_t gA0 = (size_t)(m0 + sr)*K + scS, gA1 = gA0 + (size_t)64*K;
  const size_t gB0 = (size_t)(n0 + sr)*K + scS, gB1 = gB0 + (size_t)64*K;
  const int d0 = tid*8, d1 = d0 + 2048;
  const int fR = (l15 & 3) ^ ((l15 >> 2) & 3);
  const int rq = ((quad ^ fR) << 3);

  auto STAGE = [&](int buf, int kb){
    u16* Lb = L + buf*16384;
    gl16(Ah + gA0 + kb, Lb + d0);
    gl16(Ah + gA1 + kb, Lb + d1);
    gl16(Bh + gB0 + kb, Lb + 4096 + d0);
    gl16(Bh + gB1 + kb, Lb + 4096 + d1);
    if (full){
      gl16(Al + gA0 + kb, Lb + 8192 + d0);
      gl16(Al + gA1 + kb, Lb + 8192 + d1);
      gl16(Bl + gB0 + kb, Lb + 12288 + d0);
      if (!skipBl1) gl16(Bl + gB1 + kb, Lb + 12288 + d1);
    }
  };

  f32x4 acc[4][4] = {};
  STAGE(0, 0);
  __syncthreads();
  int cur = 0;
  for (int kb = 0; kb < K; kb += 32){
    if (kb + 32 < K) STAGE(cur^1, kb + 32);
    u16* Lb = L + cur*16384;
    short8 afh[4], bfh[4];
    #pragma unroll
    for (int mi=0;mi<4;mi++) afh[mi] = *(const short8*)&Lb[(wm + mi*16 + l15)*32 + rq];
    #pragma unroll
    for (int ni=0;ni<4;ni++) bfh[ni] = *(const short8*)&Lb[4096 + (wn + ni*16 + l15)*32 + rq];
    #pragma unroll
    for (int mi=0;mi<4;mi++)
      #pragma unroll
      for (int ni=0;ni<4;ni++)
        acc[mi][ni] = __builtin_amdgcn_mfma_f32_16x16x32_bf16(afh[mi], bfh[ni], acc[mi][ni], 0,0,0);
    if (wantLow){
      short8 afl[4], bfl[4];
      #pragma unroll
      for (int mi=0;mi<4;mi++) afl[mi] = *(const short8*)&Lb[8192 + (wm + mi*16 + l15)*32 + rq];
      #pragma unroll
      for (int ni=0;ni<4;ni++) bfl[ni] = *(const short8*)&Lb[12288 + (wn + ni*16 + l15)*32 + rq];
      #pragma unroll
      for (int mi=0;mi<4;mi++)
        #pragma unroll
        for (int ni=0;ni<4;ni++){
          acc[mi][ni] = __builtin_amdgcn_mfma_f32_16x16x32_bf16(afh[mi], bfl[ni], acc[mi][ni], 0,0,0);
          acc[mi][ni] = __builtin_amdgcn_mfma_f32_16x16x32_bf16(afl[mi], bfh[ni], acc[mi][ni], 0,0,0);
        }
    }
    __syncthreads();
    cur ^= 1;
  }
  #pragma unroll
  for (int mi=0;mi<4;mi++){
    #pragma unroll
    for (int ni=0;ni<4;ni++){
      const int col = n0 + wn + ni*16 + l15;
      const int rb_ = m0 + wm + mi*16 + quad*4;
      #pragma unroll
      for (int r=0;r<4;r++){
        float v = acc[mi][ni][r];
        const int row = rb_ + r;
        if (col < 448) v = fast_htanh(v);
        else if (col >= 832 && col < 848) v = fast_sigmoid(v + bias[col-832]);
        C[(size_t)row*ldc + col] = v;
      }
    }
  }
}

// =================== output GEMM: bf16 A/Bt -> fp32 C (dbuf pipeline, K=128) ===================
__global__ __launch_bounds__(256) void gemm_out_kernel(
    const u16* __restrict__ A, const u16* __restrict__ Bt, float* __restrict__ C)
{
  __shared__ u16 L[2*2*4096];
  const int tid = threadIdx.x;
  const int wave = tid >> 6;
  const int lane = tid & 63;
  const int quad = lane >> 4, l15 = lane & 15;
  const int m0 = blockIdx.x * 128, n0 = blockIdx.y * 128;
  const int wm = (wave >> 1) * 64, wn = (wave & 1) * 64;
  const int K = 128, ldc = 1024;
  const int sr = tid >> 2;
  const int sc = tid & 3;
  const int fS = (sr & 3) ^ ((sr >> 2) & 3);
  const int scS = ((sc ^ fS) << 3);
  const size_t gA0 = (size_t)(m0 + sr)*K + scS, gA1 = gA0 + (size_t)64*K;
  const size_t gB0 = (size_t)(n0 + sr)*K + scS, gB1 = gB0 + (size_t)64*K;
  const int d0 = tid*8, d1 = d0 + 2048;
  const int fR = (l15 & 3) ^ ((l15 >> 2) & 3);
  const int rq = ((quad ^ fR) << 3);

  auto STAGE = [&](int buf, int kb){
    u16* Lb = L + buf*8192;
    gl16(A  + gA0 + kb, Lb + d0);
    gl16(A  + gA1 + kb, Lb + d1);
    gl16(Bt + gB0 + kb, Lb + 4096 + d0);
    gl16(Bt + gB1 + kb, Lb + 4096 + d1);
  };

  f32x4 acc[4][4] = {};
  STAGE(0, 0);
  __syncthreads();
  int cur = 0;
  for (int kb = 0; kb < K; kb += 32){
    if (kb + 32 < K) STAGE(cur^1, kb + 32);
    u16* Lb = L + cur*8192;
    short8 af[4], bf8[4];
    #pragma unroll
    for (int mi=0;mi<4;mi++) af[mi] = *(const short8*)&Lb[(wm + mi*16 + l15)*32 + rq];
    #pragma unroll
    for (int ni=0;ni<4;ni++) bf8[ni] = *(const short8*)&Lb[4096 + (wn + ni*16 + l15)*32 + rq];
    #pragma unroll
    for (int mi=0;mi<4;mi++)
      #pragma unroll
      for (int ni=0;ni<4;ni++)
        acc[mi][ni] = __builtin_amdgcn_mfma_f32_16x16x32_bf16(af[mi], bf8[ni], acc[mi][ni], 0,0,0);
    __syncthreads();
    cur ^= 1;
  }
  #pragma unroll
  for (int mi=0;mi<4;mi++)
    #pragma unroll
    for (int ni=0;ni<4;ni++){
      const int col = n0 + wn + ni*16 + l15;
      const int rb_ = m0 + wm + mi*16 + quad*4;
      #pragma unroll
      for (int r=0;r<4;r++)
        C[(size_t)(rb_ + r)*ldc + col] = acc[mi][ni][r];
    }
}

// =================== fused expm + chunk prefix scan (1 thread = 1 matrix) ===================
// Block = 1 wave = 1 chunk of 64 timesteps. Phase A: per-thread expm fully in registers
// (skew kept as v[28], signs folded into fma; B never materialized). Phase B: warp-synchronous
// in-place Hillis-Steele over 64 matrices: own prefix lives in regs; per level only the partner
// matrix is read (16 b128) and own is written (16 b128), both lane-coalesced via [vec][t] LDS
// layout (lane t <-> 16B slot t: conflict-free). Intra-level RAW is impossible (writes depend on
// reads via dataflow); inter-level ordering via __syncthreads (single wave: ~free).
// Upper-tri index of (i,j), i<j, in TRI order: i*7 - i(i-1)/2 + (j-i-1).
__global__ __launch_bounds__(64) void expm_scan_kernel(const float* __restrict__ proj, float* __restrict__ OR)
{
  __shared__ float S0[16*64*4];   // [j(0..15)][t(0..63)] f32x4: float idx (j*64+t)*4
  const int t = threadIdx.x;
  const int s = blockIdx.x >> 6, c = blockIdx.x & 63;   // 4096 blocks
  const int b = s >> 4, h = s & 15;
  const int row = b*4096 + c*64 + t;
  const float* sk = proj + (size_t)row*896 + h*28;

  // ---- load skew (28 contiguous floats, 16B aligned), scale by 1/16 (s=4 scaling-squaring)
  float v[28];
  {
    f32x4 vv[7];
    #pragma unroll
    for (int i=0;i<7;i++) vv[i] = *(const f32x4*)(sk + 4*i);
    #pragma unroll
    for (int i=0;i<28;i++) v[i] = vv[i>>2][i&3] * 0.0625f;
  }

  // ---- expm via Horner degree-6 + 4 squarings (parity with previous version)
  float M[64], T[64];
  // T = B*M (B skew from v; diagonal zero)
  auto bmul = [&](const float* Min, float* Tout){
    #pragma unroll
    for (int i=0;i<8;i++){
      #pragma unroll
      for (int cc=0;cc<8;cc++){
        float acc = 0.f;
        #pragma unroll
        for (int a=0;a<8;a++){
          if (a == i) continue;
          const int k = (i<a) ? (i*7 - (i*(i-1))/2 + a - i - 1)
                              : (a*7 - (a*(a-1))/2 + i - a - 1);
          if (i<a) acc = fmaf( v[k], Min[a*8+cc], acc);
          else     acc = fmaf(-v[k], Min[a*8+cc], acc);
        }
        Tout[i*8+cc] = acc;
      }
    }
  };
  // init M = B/6 + I
  #pragma unroll
  for (int i=0;i<8;i++){
    #pragma unroll
    for (int jj=0;jj<8;jj++){
      float bv = 0.f;
      if (i < jj){ const int k = i*7 - (i*(i-1))/2 + jj - i - 1; bv =  v[k]; }
      if (i > jj){ const int k = jj*7 - (jj*(jj-1))/2 + i - jj - 1; bv = -v[k]; }
      M[i*8+jj] = bv*(1.f/6.f) + ((i==jj)?1.f:0.f);
    }
  }
  const float coef[5] = {0.2f, 0.25f, 1.f/3.f, 0.5f, 1.f};
  #pragma unroll
  for (int st=0; st<5; st++){
    bmul(M, T);
    #pragma unroll
    for (int i=0;i<8;i++)
      #pragma unroll
      for (int jj=0;jj<8;jj++)
        M[i*8+jj] = T[i*8+jj]*coef[st] + ((i==jj)?1.f:0.f);
  }
  #pragma unroll
  for (int sq=0; sq<4; sq++){
    #pragma unroll
    for (int i=0;i<8;i++)
      #pragma unroll
      for (int cc=0;cc<8;cc++){
        float acc = 0.f;
        #pragma unroll
        for (int a=0;a<8;a++) acc = fmaf(M[i*8+a], M[a*8+cc], acc);
        T[i*8+cc] = acc;
      }
    #pragma unroll
    for (int f=0;f<64;f++) M[f] = T[f];
  }
  // M = O_t (row-major). Seed scan buffer.
  #pragma unroll
  for (int j=0;j<16;j++){
    f32x4 w = {M[4*j], M[4*j+1], M[4*j+2], M[4*j+3]};
    *(f32x4*)&S0[(j*64 + t)*4] = w;
  }
  __syncthreads();

  // ---- in-place Hillis-Steele: P_t <- P_t * P_{t-off} (own on LEFT: covers newer steps)
  #pragma unroll
  for (int d=0; d<6; d++){
    const int off = 1 << d;
    if (t >= off){
      float Q[64];
      #pragma unroll
      for (int j=0;j<16;j++){
        f32x4 x = *(const f32x4*)&S0[(j*64 + (t-off))*4];
        Q[4*j]=x[0]; Q[4*j+1]=x[1]; Q[4*j+2]=x[2]; Q[4*j+3]=x[3];
      }
      // M <- M * Q, row-wise in place (row i of result needs only row i of M + all Q)
      #pragma unroll
      for (int i=0;i<8;i++){
        float r[8];
        #pragma unroll
        for (int cc=0;cc<8;cc++){
          float acc = 0.f;
          #pragma unroll
          for (int a=0;a<8;a++) acc = fmaf(M[i*8+a], Q[a*8+cc], acc);
          r[cc] = acc;
        }
        #pragma unroll
        for (int cc=0;cc<8;cc++) M[i*8+cc] = r[cc];
      }
    }
    if (d < 5){
      #pragma unroll
      for (int j=0;j<16;j++){
        f32x4 w = {M[4*j], M[4*j+1], M[4*j+2], M[4*j+3]};
        *(f32x4*)&S0[(j*64 + t)*4] = w;
      }
      __syncthreads();
    }
  }

  // ---- write P_c(t) col-major: OR[slot + a*8 + i] = M[i][a]
  float* dst = OR + ((size_t)s*4096 + (size_t)c*64 + t)*64;
  #pragma unroll
  for (int j=0;j<16;j++){
    const int rb = 4*(j&1), col = j>>1;
    f32x4 w = {M[(rb+0)*8 + col], M[(rb+1)*8 + col], M[(rb+2)*8 + col], M[(rb+3)*8 + col]};
    *(f32x4*)(dst + 4*j) = w;
  }
}

// helpers: 8x8 matvec with 16 f32x4 regs
DEV void load16(const float* p, f32x4* M){
  #pragma unroll
  for (int q=0;q<16;q++) M[q] = *(const f32x4*)(p + 4*q);
}
// flat[i*8+a]*x[a]: for col-major storage this is M^T x; for row-major it's M x
DEV void rm_matvec8(const f32x4* M16, const float* x, float* res){
  #pragma unroll
  for (int i=0;i<8;i++){
    float acc = 0.f;
    #pragma unroll
    for (int a=0;a<8;a++) acc = fmaf(M16[2*i + (a>>2)][a&3], x[a], acc);
    res[i] = acc;
  }
}
// flat[a*8+i]*x[a]: for col-major storage this is M x
DEV void cm_matvec8(const f32x4* M16, const float* x, float* res){
  #pragma unroll
  for (int i=0;i<8;i++){
    float acc = 0.f;
    #pragma unroll
    for (int a=0;a<8;a++) acc = fmaf(M16[2*a + (i>>2)][i&3], x[a], acc);
    res[i] = acc;
  }
}

// =================== C2: scan of chunk products -> Rbase_c ===================
__global__ __launch_bounds__(256) void chunkscan_kernel(const float* __restrict__ OR, float* __restrict__ Rbase)
{
  int tid = blockIdx.x*256 + threadIdx.x;   // 512 = 64 seqs * 8 lanes
  int s = tid >> 3, j = tid & 7;
  float Rb[8], Rn[8];
  #pragma unroll
  for (int a=0;a<8;a++) Rb[a] = (a==j) ? 1.f : 0.f;
  for (int c=0;c<64;c++){
    float* dst = Rbase + ((size_t)s*64 + c)*64 + j*8;
    f32x4 s0 = {Rb[0],Rb[1],Rb[2],Rb[3]}, s1 = {Rb[4],Rb[5],Rb[6],Rb[7]};
    *(f32x4*)(dst) = s0; *(f32x4*)(dst+4) = s1;     // col-major Rbase_c
    if (c < 63){
      const float* qs = OR + ((size_t)s*4096 + (size_t)(c*64+63))*64;  // Q_c col-major
      f32x4 Q[16];
      load16(qs, Q);
      cm_matvec8(Q, Rb, Rn);       // Rb <- Q_c * Rb
      #pragma unroll
      for (int a=0;a<8;a++) Rb[a] = Rn[a];
    }
  }
}

// =================== C3: rotate k/v/q via R_t^T = Rbase^T (P^T .) — no R materialization ===================
__global__ __launch_bounds__(256) void rotate_kvq_kernel(const float* __restrict__ OR, const float* __restrict__ Rbase,
    float* __restrict__ proj)
{
  int tid = blockIdx.x*256 + threadIdx.x;   // 262144
  int s = tid >> 12, t = tid & 4095;
  int c = t >> 6;
  int b = s >> 4, h = s & 15;
  int row = b*4096 + t;
  const float* slot = OR + ((size_t)s*4096 + t)*64;
  float* pr = proj + (size_t)row*896;
  float k[8], v[8], q[8];
  { f32x4 a = *(const f32x4*)(pr+448+h*8), b2 = *(const f32x4*)(pr+452+h*8);
    #pragma unroll
    for (int i=0;i<4;i++){ k[i]=a[i]; k[4+i]=b2[i]; } }
  { f32x4 a = *(const f32x4*)(pr+576+h*8), b2 = *(const f32x4*)(pr+580+h*8);
    #pragma unroll
    for (int i=0;i<4;i++){ v[i]=a[i]; v[4+i]=b2[i]; } }
  { f32x4 a = *(const f32x4*)(pr+704+h*8), b2 = *(const f32x4*)(pr+708+h*8);
    #pragma unroll
    for (int i=0;i<4;i++){ q[i]=a[i]; q[4+i]=b2[i]; } }
  float nn = 0.f;
  #pragma unroll
  for (int i=0;i<8;i++) nn = fmaf(k[i],k[i],nn);
  float inv = 1.f / fmaxf(sqrtf(nn), 1e-6f);
  #pragma unroll
  for (int i=0;i<8;i++) k[i] *= inv;

  f32x4 M[16];
  load16(slot, M);                           // P col-major -> rm gives P^T x
  float uk[8], uv[8], uq[8];
  rm_matvec8(M, k, uk);
  rm_matvec8(M, v, uv);
  rm_matvec8(M, q, uq);
  load16(Rbase + ((size_t)s*64 + c)*64, M);  // Rbase col-major -> rm gives Rbase^T x
  float kt[8], vt[8], qt[8];
  rm_matvec8(M, uk, kt);
  rm_matvec8(M, uv, vt);
  rm_matvec8(M, uq, qt);

  float beta = pr[832+h];
  float qk = 0.f;
  #pragma unroll
  for (int j=0;j<8;j++) qk = fmaf(kt[j], qt[j], qk);
  float* sip = pr + h*28;     // dead skew slot of this (row,h); writes <448, reads >=448
  f32x4 w0={kt[0],kt[1],kt[2],kt[3]}, w1={kt[4],kt[5],kt[6],kt[7]};
  f32x4 w2={vt[0],vt[1],vt[2],vt[3]}, w3={vt[4],vt[5],vt[6],vt[7]};
  f32x4 w4={qt[0],qt[1],qt[2],qt[3]}, w5={qt[4],qt[5],qt[6],qt[7]};
  f32x4 w6={beta, qk, 0.f, 0.f};
  *(f32x4*)(sip)=w0; *(f32x4*)(sip+4)=w1; *(f32x4*)(sip+8)=w2; *(f32x4*)(sip+12)=w3;
  *(f32x4*)(sip+16)=w4; *(f32x4*)(sip+20)=w5; *(f32x4*)(sip+24)=w6;
}

// =================== D: chunk-parallel delta scan (128 chunks x 32 steps) ===================
__global__ __launch_bounds__(256) void scan_pass1_kernel(const float* __restrict__ proj,
    float* __restrict__ Mbuf, float* __restrict__ wbuf)
{
  int tid = blockIdx.x*256 + threadIdx.x;   // 65536 = 8192 tasks * 8 lanes
  int task = tid >> 3, j = tid & 7;         // task = s*128 + c
  int s = task >> 7, c = task & 127;
  int b = s >> 4, h = s & 15;
  const float* rec = proj + ((size_t)b*4096 + (size_t)c*32)*896 + h*28;
  float m[8], w[8];
  #pragma unroll
  for (int i=0;i<8;i++){ m[i] = (i==j)?1.f:0.f; w[i] = 0.f; }
  f32x4 k0 = *(const f32x4*)(rec), k1 = *(const f32x4*)(rec+4);
  float vt = rec[8+j];
  float beta = rec[24];
  for (int tt=0; tt<32; tt++){
    const float* pn = rec + (size_t)(tt+1)*896;   // prefetch (last iter reads in-ws garbage, unused)
    f32x4 nk0 = *(const f32x4*)(pn), nk1 = *(const f32x4*)(pn+4);
    float nvt = pn[8+j];
    float nbeta = pn[24];
    float s1, s2;
    s1 = ((k0[0]*m[0] + k0[1]*m[1]) + (k0[2]*m[2] + k0[3]*m[3]))
       + ((k1[0]*m[4] + k1[1]*m[5]) + (k1[2]*m[6] + k1[3]*m[7]));
    s2 = ((k0[0]*w[0] + k0[1]*w[1]) + (k0[2]*w[2] + k0[3]*w[3]))
       + ((k1[0]*w[4] + k1[1]*w[5]) + (k1[2]*w[6] + k1[3]*w[7]));
    float c1 = -beta*s1, c2 = beta*(vt - s2);
    #pragma unroll
    for (int i=0;i<4;i++){ m[i] = fmaf(k0[i], c1, m[i]); m[4+i] = fmaf(k1[i], c1, m[4+i]); }
    #pragma unroll
    for (int i=0;i<4;i++){ w[i] = fmaf(k0[i], c2, w[i]); w[4+i] = fmaf(k1[i], c2, w[4+i]); }
    k0=nk0; k1=nk1; vt=nvt; beta=nbeta;
  }
  float* md = Mbuf + (size_t)task*64 + j*8;
  float* wd = wbuf + (size_t)task*64 + j*8;
  f32x4 m0={m[0],m[1],m[2],m[3]}, m1={m[4],m[5],m[6],m[7]};
  f32x4 w0={w[0],w[1],w[2],w[3]}, w1={w[4],w[5],w[6],w[7]};
  *(f32x4*)(md) = m0; *(f32x4*)(md+4) = m1;
  *(f32x4*)(wd) = w0; *(f32x4*)(wd+4) = w1;
}

__global__ __launch_bounds__(64) void scan_mid_kernel(const float* __restrict__ Mbuf,
    const float* __restrict__ wbuf, float* __restrict__ dstart)
{
  int tid = blockIdx.x*64 + threadIdx.x;    // 512 = 64 seqs * 8 lanes
  int s = tid >> 3, j = tid & 7;
  float d[8];
  #pragma unroll
  for (int i=0;i<8;i++) d[i] = 0.f;
  size_t base = (size_t)s*128*64;
  f32x4 M[16]; load16(Mbuf + base, M);
  f32x4 wv0 = *(const f32x4*)(wbuf + base + j*8), wv1 = *(const f32x4*)(wbuf + base + j*8 + 4);
  for (int c=0; c<128; c++){
    float* dd = dstart + base + (size_t)c*64 + j*8;
    f32x4 s0 = {d[0],d[1],d[2],d[3]}, s1 = {d[4],d[5],d[6],d[7]};
    *(f32x4*)(dd) = s0; *(f32x4*)(dd+4) = s1;
    float dn[8];
    cm_matvec8(M, d, dn);
    #pragma unroll
    for (int i=0;i<4;i++){ d[i] = dn[i] + wv0[i]; d[4+i] = dn[4+i] + wv1[i]; }
    if (c < 127){
      size_t nb = base + (size_t)(c+1)*64;
      load16(Mbuf + nb, M);
      wv0 = *(const f32x4*)(wbuf + nb + j*8); wv1 = *(const f32x4*)(wbuf + nb + j*8 + 4);
    }
  }
}

__global__ __launch_bounds__(256) void scan_pass2_kernel(const float* __restrict__ proj,
    const float* __restrict__ dstart, float* __restrict__ oo)
{
  int tid = blockIdx.x*256 + threadIdx.x;   // 65536
  int task = tid >> 3, j = tid & 7;
  int s = task >> 7, c = task & 127;
  int b = s >> 4, h = s & 15;
  const float* rec = proj + ((size_t)b*4096 + (size_t)c*32)*896 + h*28;
  float* op = oo + (((size_t)s*4096 + (size_t)c*32)*8) + j;
  float d[8];
  { const float* ds = dstart + (size_t)task*64 + j*8;
    f32x4 a = *(const f32x4*)(ds), b2 = *(const f32x4*)(ds+4);
    #pragma unroll
    for (int i=0;i<4;i++){ d[i]=a[i]; d[4+i]=b2[i]; } }
  f32x4 k0 = *(const f32x4*)(rec),    k1 = *(const f32x4*)(rec+4);
  f32x4 q0 = *(const f32x4*)(rec+16), q1 = *(const f32x4*)(rec+20);
  f32x4 mb = *(const f32x4*)(rec+24);
  float vt = rec[8+j];
  for (int tt=0; tt<32; tt++){
    const float* pn = rec + (size_t)(tt+1)*896;   // prefetch
    f32x4 nk0 = *(const f32x4*)(pn),    nk1 = *(const f32x4*)(pn+4);
    f32x4 nq0 = *(const f32x4*)(pn+16), nq1 = *(const f32x4*)(pn+20);
    f32x4 nmb = *(const f32x4*)(pn+24);
    float nvt = pn[8+j];
    float kd, qd;
    kd = ((k0[0]*d[0] + k0[1]*d[1]) + (k0[2]*d[2] + k0[3]*d[3]))
       + ((k1[0]*d[4] + k1[1]*d[5]) + (k1[2]*d[6] + k1[3]*d[7]));
    qd = ((q0[0]*d[0] + q0[1]*d[1]) + (q0[2]*d[2] + q0[3]*d[3]))
       + ((q1[0]*d[4] + q1[1]*d[5]) + (q1[2]*d[6] + q1[3]*d[7]));
    float w_ = mb[0] * (vt - kd);
    #pragma unroll
    for (int i=0;i<4;i++){ d[i] = fmaf(k0[i], w_, d[i]); d[4+i] = fmaf(k1[i], w_, d[4+i]); }
    op[(size_t)tt*8] = fmaf(mb[1], w_, qd);
    k0=nk0; k1=nk1; q0=nq0; q1=nq1; mb=nmb; vt=nvt;
  }
}

// =================== E: rotate outputs back: o = P (Rbase o~), write bf16 ===================
__global__ __launch_bounds__(256) void rotout_kernel(const float* __restrict__ OR, const float* __restrict__ Rbase,
                                                     const float* __restrict__ oo, u16* __restrict__ obf)
{
  int tid = blockIdx.x*256 + threadIdx.x;   // 262144
  int s = tid >> 12, t = tid & 4095;
  int c = t >> 6;
  int b = s >> 4, h = s & 15;
  int row = b*4096 + t;
  float u[8];
  { const float* up = oo + ((size_t)s*4096 + t)*8;
    f32x4 a = *(const f32x4*)(up), b2 = *(const f32x4*)(up+4);
    #pragma unroll
    for (int i=0;i<4;i++){ u[i]=a[i]; u[4+i]=b2[i]; } }
  f32x4 M[16];
  load16(Rbase + ((size_t)s*64 + c)*64, M);  // col-major -> cm gives Rbase * u
  float w[8];
  cm_matvec8(M, u, w);
  load16(OR + ((size_t)s*4096 + t)*64, M);   // P col-major -> cm gives P * w
  float o[8];
  cm_matvec8(M, w, o);
  u32 p0 = (u32)f2bf(o[0]) | ((u32)f2bf(o[1])<<16);
  u32 p1 = (u32)f2bf(o[2]) | ((u32)f2bf(o[3])<<16);
  u32 p2 = (u32)f2bf(o[4]) | ((u32)f2bf(o[5])<<16);
  u32 p3 = (u32)f2bf(o[6]) | ((u32)f2bf(o[7])<<16);
  u32x4 pk = {p0,p1,p2,p3};
  *(u32x4*)(void*)(obf + (size_t)row*128 + h*8) = pk;
}

// =================== launch ===================
extern "C" void kernel_launch(void* const* d_in, const int* in_sizes, int n_in,
                              void* d_out, int out_size, void* d_ws, size_t ws_size,
                              hipStream_t stream)
{
  const float* x     = (const float*)d_in[0];
  const float* Wskew = (const float*)d_in[1];
  const float* Wk    = (const float*)d_in[2];
  const float* Wv    = (const float*)d_in[3];
  const float* Wq    = (const float*)d_in[4];
  const float* Wbeta = (const float*)d_in[5];
  const float* bbeta = (const float*)d_in[6];
  const float* Wo    = (const float*)d_in[7];

  char* w = (char*)d_ws; size_t off = 0;
  auto alloc = [&](size_t bytes)->void*{ void* p = w + off; off += (bytes + 255) & ~(size_t)255; return p; };
  u16*   Wh     = (u16*)  alloc((size_t)896*1024*2);
  u16*   Wl     = (u16*)  alloc((size_t)896*1024*2);
  u16*   WoT    = (u16*)  alloc((size_t)1024*128*2);
  float* proj   = (float*)alloc((size_t)16384*896*4);
  float* OR     = (float*)alloc((size_t)262144*64*4);
  float* Rbase  = (float*)alloc((size_t)64*64*64*4);
  float* oo     = (float*)alloc((size_t)262144*8*4);
  float* Mbuf   = (float*)alloc((size_t)8192*64*4);
  float* wbuf   = (float*)alloc((size_t)8192*64*4);
  float* dstart = (float*)alloc((size_t)8192*64*4);
  // aliases: xh/xl live only until gemm_proj; OR is written first by expm_scan (after)
  u16*   xh     = (u16*)OR;                       // 32 MB
  u16*   xl     = xh + (size_t)16384*1024;        // 32 MB  (OR region is 64 MB)
  u16*   obf    = (u16*)proj;   // proj fully dead after scan pass2

  hipLaunchKernelGGL(splitx_kernel, dim3(8192), dim3(256), 0, stream, x, xh, xl);
  hipLaunchKernelGGL(concat_kernel, dim3(4096), dim3(256), 0, stream,
                     Wskew, Wk, Wv, Wq, Wbeta, Wo, Wh, Wl, WoT);
  hipLaunchKernelGGL(gemm_proj_kernel, dim3(128,7), dim3(256), 0, stream,
                     xh, xl, Wh, Wl, proj, bbeta);
  hipLaunchKernelGGL(expm_scan_kernel, dim3(4096), dim3(64), 0, stream, proj, OR);
  hipLaunchKernelGGL(chunkscan_kernel, dim3(2), dim3(256), 0, stream, OR, Rbase);
  hipLaunchKernelGGL(rotate_kvq_kernel, dim3(1024), dim3(256), 0, stream, OR, Rbase, proj);
  hipLaunchKernelGGL(scan_pass1_kernel, dim3(256), dim3(256), 0, stream, proj, Mbuf, wbuf);
  hipLaunchKernelGGL(scan_mid_kernel, dim3(8), dim3(64), 0, stream, Mbuf, wbuf, dstart);
  hipLaunchKernelGGL(scan_pass2_kernel, dim3(256), dim3(256), 0, stream, proj, dstart, oo);
  hipLaunchKernelGGL(rotout_kernel, dim3(1024), dim3(256), 0, stream, OR, Rbase, oo, obf);
  hipLaunchKernelGGL(gemm_out_kernel, dim3(128,8), dim3(256), 0, stream,
                     obf, WoT, (float*)d_out);
}

// Round 5
// 432.682 us; speedup vs baseline: 1.3269x; 1.1017x over previous
//
#include <hip/hip_runtime.h>

typedef unsigned short u16;
typedef unsigned int u32;
typedef __attribute__((ext_vector_type(4))) float f32x4;
typedef __attribute__((ext_vector_type(8))) short short8;
typedef __attribute__((ext_vector_type(4))) unsigned int u32x4;

#define DEV __device__ __forceinline__

DEV float bf2f(u16 u){ union{u32 i; float f;} x; x.i = ((u32)u)<<16; return x.f; }
DEV u16 f2bf(float f){ union{u32 i; float f;} x; x.f = f; u32 r = x.i + 0x7fffu + ((x.i>>16)&1u); return (u16)(r>>16); }

union U8 { u16 u[8]; short8 s; };

// async global -> LDS, 16B per lane (dest must be wave-uniform base + lane*16; ours is tid*16)
DEV void gl16(const u16* g, u16* l){
  __builtin_amdgcn_global_load_lds(
      (const __attribute__((address_space(1))) u32*)g,
      (__attribute__((address_space(3))) u32*)l, 16, 0, 0);
}

// fast tanh/sigmoid via v_exp + v_rcp (err ~1e-6, dwarfed by bf16 input rounding)
DEV float fast_htanh(float v){           // 0.5*tanh(v)
  float vc = fminf(fmaxf(v, -15.f), 15.f);
  float e = __expf(2.f*vc);
  return 0.5f*(e - 1.f)*__builtin_amdgcn_rcpf(e + 1.f);
}
DEV float fast_sigmoid(float v){
  float e = __expf(-v);
  return __builtin_amdgcn_rcpf(1.f + e);
}

// =================== weight concat / transpose -> hi/lo bf16 planes ===================
__global__ __launch_bounds__(256) void concat_kernel(
    const float* __restrict__ Wskew, const float* __restrict__ Wk, const float* __restrict__ Wv,
    const float* __restrict__ Wq, const float* __restrict__ Wbeta, const float* __restrict__ Wo,
    u16* __restrict__ Wh, u16* __restrict__ Wl, u16* __restrict__ WoT)
{
  int idx = blockIdx.x*256 + threadIdx.x;
  if (idx < 896*1024){
    int n = idx >> 10, kk = idx & 1023;
    float v;
    if (n < 448)      v = Wskew[kk*448 + n];
    else if (n < 576) v = Wk[kk*128 + (n-448)];
    else if (n < 704) v = Wv[kk*128 + (n-576)];
    else if (n < 832) v = Wq[kk*128 + (n-704)];
    else if (n < 848) v = Wbeta[kk*16 + (n-832)];
    else              v = 0.f;
    u16 h = f2bf(v);
    Wh[idx] = h;
    Wl[idx] = f2bf(v - bf2f(h));
  } else {
    int r = idx - 896*1024;
    int n = r >> 7, kk = r & 127;
    WoT[r] = f2bf(Wo[kk*1024 + n]);
  }
}

// =================== proj GEMM: fused x-split + dbuf pipeline ===================
// A-side: reg-staged from f32 x with on-the-fly hi/lo bf16 split (T14: load early, ds_write late).
// B-side: global_load_lds. Same swizzle discipline as before (linear LDS, pre-swizzled source col).
__global__ __launch_bounds__(256) void gemm_proj_kernel(
    const float* __restrict__ X,
    const u16* __restrict__ Bh, const u16* __restrict__ Bl,
    float* __restrict__ C, const float* __restrict__ bias)
{
  __shared__ u16 L[2*4*4096];   // [buf][plane Ah,Bh,Al,Bl][4096 u16]
  const int tid = threadIdx.x;
  const int wave = tid >> 6;
  const int lane = tid & 63;
  const int quad = lane >> 4, l15 = lane & 15;
  const int m0 = blockIdx.x * 128, n0 = blockIdx.y * 128;
  const bool full = (blockIdx.y < 4);
  const int wm = (wave >> 1) * 64, wn = (wave & 1) * 64;
  const bool wantLow = full && !(blockIdx.y == 3 && wn == 64);
  const bool skipBl1 = (blockIdx.y == 3);
  const int K = 1024, ldc = 896;
  const int sr = tid >> 2;
  const int sc = tid & 3;
  const int fS = (sr & 3) ^ ((sr >> 2) & 3);
  const int scS = ((sc ^ fS) << 3);            // swizzled k-offset (elements)
  const size_t gA0 = (size_t)(m0 + sr)*K + scS, gA1 = gA0 + (size_t)64*K;   // f32 on X
  const size_t gB0 = (size_t)(n0 + sr)*K + scS, gB1 = gB0 + (size_t)64*K;   // u16 on B
  const int d0 = tid*8, d1 = d0 + 2048;        // lane-linear LDS dest (byte = tid*16)
  const int fR = (l15 & 3) ^ ((l15 >> 2) & 3);
  const int rq = ((quad ^ fR) << 3);

  auto LOADA = [&](int kb, f32x4* va){
    va[0] = *(const f32x4*)(X + gA0 + kb);
    va[1] = *(const f32x4*)(X + gA0 + kb + 4);
    va[2] = *(const f32x4*)(X + gA1 + kb);
    va[3] = *(const f32x4*)(X + gA1 + kb + 4);
  };
  auto WRITEA = [&](int buf, const f32x4* va){
    u16* Lb = L + buf*16384;
    U8 h0, h1;
    #pragma unroll
    for (int e=0;e<4;e++){
      h0.u[e]   = f2bf(va[0][e]);
      h0.u[4+e] = f2bf(va[1][e]);
      h1.u[e]   = f2bf(va[2][e]);
      h1.u[4+e] = f2bf(va[3][e]);
    }
    *(short8*)&Lb[d0] = h0.s; *(short8*)&Lb[d1] = h1.s;
    if (full){
      U8 l0, l1;
      #pragma unroll
      for (int e=0;e<4;e++){
        l0.u[e]   = f2bf(va[0][e] - bf2f(h0.u[e]));
        l0.u[4+e] = f2bf(va[1][e] - bf2f(h0.u[4+e]));
        l1.u[e]   = f2bf(va[2][e] - bf2f(h1.u[e]));
        l1.u[4+e] = f2bf(va[3][e] - bf2f(h1.u[4+e]));
      }
      *(short8*)&Lb[8192+d0] = l0.s; *(short8*)&Lb[8192+d1] = l1.s;
    }
  };
  auto STAGEB = [&](int buf, int kb){
    u16* Lb = L + buf*16384;
    gl16(Bh + gB0 + kb, Lb + 4096 + d0);
    gl16(Bh + gB1 + kb, Lb + 4096 + d1);
    if (full){
      gl16(Bl + gB0 + kb, Lb + 12288 + d0);
      if (!skipBl1) gl16(Bl + gB1 + kb, Lb + 12288 + d1);
    }
  };

  f32x4 acc[4][4] = {};
  { f32x4 va[4]; LOADA(0, va); STAGEB(0, 0); WRITEA(0, va); }
  __syncthreads();
  int cur = 0;
  for (int kb = 0; kb < K; kb += 32){
    const bool hasNext = (kb + 32 < K);
    f32x4 vn[4];
    if (hasNext){ LOADA(kb + 32, vn); STAGEB(cur^1, kb + 32); }   // issue loads FIRST
    u16* Lb = L + cur*16384;
    short8 afh[4], bfh[4];
    #pragma unroll
    for (int mi=0;mi<4;mi++) afh[mi] = *(const short8*)&Lb[(wm + mi*16 + l15)*32 + rq];
    #pragma unroll
    for (int ni=0;ni<4;ni++) bfh[ni] = *(const short8*)&Lb[4096 + (wn + ni*16 + l15)*32 + rq];
    #pragma unroll
    for (int mi=0;mi<4;mi++)
      #pragma unroll
      for (int ni=0;ni<4;ni++)
        acc[mi][ni] = __builtin_amdgcn_mfma_f32_16x16x32_bf16(afh[mi], bfh[ni], acc[mi][ni], 0,0,0);
    if (wantLow){
      short8 afl[4], bfl[4];
      #pragma unroll
      for (int mi=0;mi<4;mi++) afl[mi] = *(const short8*)&Lb[8192 + (wm + mi*16 + l15)*32 + rq];
      #pragma unroll
      for (int ni=0;ni<4;ni++) bfl[ni] = *(const short8*)&Lb[12288 + (wn + ni*16 + l15)*32 + rq];
      #pragma unroll
      for (int mi=0;mi<4;mi++)
        #pragma unroll
        for (int ni=0;ni<4;ni++){
          acc[mi][ni] = __builtin_amdgcn_mfma_f32_16x16x32_bf16(afh[mi], bfl[ni], acc[mi][ni], 0,0,0);
          acc[mi][ni] = __builtin_amdgcn_mfma_f32_16x16x32_bf16(afl[mi], bfh[ni], acc[mi][ni], 0,0,0);
        }
    }
    if (hasNext) WRITEA(cur^1, vn);   // LDS write late: buffer free since prev-iter barrier
    __syncthreads();
    cur ^= 1;
  }
  #pragma unroll
  for (int mi=0;mi<4;mi++){
    #pragma unroll
    for (int ni=0;ni<4;ni++){
      const int col = n0 + wn + ni*16 + l15;
      const int rb_ = m0 + wm + mi*16 + quad*4;
      #pragma unroll
      for (int r=0;r<4;r++){
        float v = acc[mi][ni][r];
        const int row = rb_ + r;
        if (col < 448) v = fast_htanh(v);
        else if (col >= 832 && col < 848) v = fast_sigmoid(v + bias[col-832]);
        C[(size_t)row*ldc + col] = v;
      }
    }
  }
}

// =================== output GEMM: bf16 A/Bt -> fp32 C (dbuf pipeline, K=128) ===================
__global__ __launch_bounds__(256) void gemm_out_kernel(
    const u16* __restrict__ A, const u16* __restrict__ Bt, float* __restrict__ C)
{
  __shared__ u16 L[2*2*4096];
  const int tid = threadIdx.x;
  const int wave = tid >> 6;
  const int lane = tid & 63;
  const int quad = lane >> 4, l15 = lane & 15;
  const int m0 = blockIdx.x * 128, n0 = blockIdx.y * 128;
  const int wm = (wave >> 1) * 64, wn = (wave & 1) * 64;
  const int K = 128, ldc = 1024;
  const int sr = tid >> 2;
  const int sc = tid & 3;
  const int fS = (sr & 3) ^ ((sr >> 2) & 3);
  const int scS = ((sc ^ fS) << 3);
  const size_t gA0 = (size_t)(m0 + sr)*K + scS, gA1 = gA0 + (size_t)64*K;
  const size_t gB0 = (size_t)(n0 + sr)*K + scS, gB1 = gB0 + (size_t)64*K;
  const int d0 = tid*8, d1 = d0 + 2048;
  const int fR = (l15 & 3) ^ ((l15 >> 2) & 3);
  const int rq = ((quad ^ fR) << 3);

  auto STAGE = [&](int buf, int kb){
    u16* Lb = L + buf*8192;
    gl16(A  + gA0 + kb, Lb + d0);
    gl16(A  + gA1 + kb, Lb + d1);
    gl16(Bt + gB0 + kb, Lb + 4096 + d0);
    gl16(Bt + gB1 + kb, Lb + 4096 + d1);
  };

  f32x4 acc[4][4] = {};
  STAGE(0, 0);
  __syncthreads();
  int cur = 0;
  for (int kb = 0; kb < K; kb += 32){
    if (kb + 32 < K) STAGE(cur^1, kb + 32);
    u16* Lb = L + cur*8192;
    short8 af[4], bf8[4];
    #pragma unroll
    for (int mi=0;mi<4;mi++) af[mi] = *(const short8*)&Lb[(wm + mi*16 + l15)*32 + rq];
    #pragma unroll
    for (int ni=0;ni<4;ni++) bf8[ni] = *(const short8*)&Lb[4096 + (wn + ni*16 + l15)*32 + rq];
    #pragma unroll
    for (int mi=0;mi<4;mi++)
      #pragma unroll
      for (int ni=0;ni<4;ni++)
        acc[mi][ni] = __builtin_amdgcn_mfma_f32_16x16x32_bf16(af[mi], bf8[ni], acc[mi][ni], 0,0,0);
    __syncthreads();
    cur ^= 1;
  }
  #pragma unroll
  for (int mi=0;mi<4;mi++)
    #pragma unroll
    for (int ni=0;ni<4;ni++){
      const int col = n0 + wn + ni*16 + l15;
      const int rb_ = m0 + wm + mi*16 + quad*4;
      #pragma unroll
      for (int r=0;r<4;r++)
        C[(size_t)(rb_ + r)*ldc + col] = acc[mi][ni][r];
    }
}

// =================== fused expm + chunk prefix scan (1 thread = 1 matrix) ===================
__device__ constexpr int TRI_I[28] = {0,0,0,0,0,0,0, 1,1,1,1,1,1, 2,2,2,2,2, 3,3,3,3, 4,4,4, 5,5, 6};
__device__ constexpr int TRI_J[28] = {1,2,3,4,5,6,7, 2,3,4,5,6,7, 3,4,5,6,7, 4,5,6,7, 5,6,7, 6,7, 7};

__global__ __launch_bounds__(64) void expm_scan_kernel(const float* __restrict__ proj, float* __restrict__ OR)
{
  __shared__ float S0[16*64*4];   // [j(0..15)][t(0..63)] f32x4
  const int t = threadIdx.x;
  const int s = blockIdx.x >> 6, c = blockIdx.x & 63;   // 4096 blocks
  const int b = s >> 4, h = s & 15;
  const int row = b*4096 + c*64 + t;
  const float* sk = proj + (size_t)row*896 + h*28;

  float v[28];
  {
    f32x4 vv[7];
    #pragma unroll
    for (int i=0;i<7;i++) vv[i] = *(const f32x4*)(sk + 4*i);
    #pragma unroll
    for (int i=0;i<28;i++) v[i] = vv[i>>2][i&3] * 0.0625f;
  }

  float M[64], T[64];
  auto bmul = [&](const float* Min, float* Tout){
    #pragma unroll
    for (int i=0;i<8;i++){
      #pragma unroll
      for (int cc=0;cc<8;cc++){
        float acc = 0.f;
        #pragma unroll
        for (int a=0;a<8;a++){
          if (a == i) continue;
          const int k = (i<a) ? (i*7 - (i*(i-1))/2 + a - i - 1)
                              : (a*7 - (a*(a-1))/2 + i - a - 1);
          if (i<a) acc = fmaf( v[k], Min[a*8+cc], acc);
          else     acc = fmaf(-v[k], Min[a*8+cc], acc);
        }
        Tout[i*8+cc] = acc;
      }
    }
  };
  #pragma unroll
  for (int i=0;i<8;i++){
    #pragma unroll
    for (int jj=0;jj<8;jj++){
      float bv = 0.f;
      if (i < jj){ const int k = i*7 - (i*(i-1))/2 + jj - i - 1; bv =  v[k]; }
      if (i > jj){ const int k = jj*7 - (jj*(jj-1))/2 + i - jj - 1; bv = -v[k]; }
      M[i*8+jj] = bv*(1.f/6.f) + ((i==jj)?1.f:0.f);
    }
  }
  const float coef[5] = {0.2f, 0.25f, 1.f/3.f, 0.5f, 1.f};
  #pragma unroll
  for (int st=0; st<5; st++){
    bmul(M, T);
    #pragma unroll
    for (int i=0;i<8;i++)
      #pragma unroll
      for (int jj=0;jj<8;jj++)
        M[i*8+jj] = T[i*8+jj]*coef[st] + ((i==jj)?1.f:0.f);
  }
  #pragma unroll
  for (int sq=0; sq<4; sq++){
    #pragma unroll
    for (int i=0;i<8;i++)
      #pragma unroll
      for (int cc=0;cc<8;cc++){
        float acc = 0.f;
        #pragma unroll
        for (int a=0;a<8;a++) acc = fmaf(M[i*8+a], M[a*8+cc], acc);
        T[i*8+cc] = acc;
      }
    #pragma unroll
    for (int f=0;f<64;f++) M[f] = T[f];
  }
  #pragma unroll
  for (int j=0;j<16;j++){
    f32x4 w = {M[4*j], M[4*j+1], M[4*j+2], M[4*j+3]};
    *(f32x4*)&S0[(j*64 + t)*4] = w;
  }
  __syncthreads();

  #pragma unroll
  for (int d=0; d<6; d++){
    const int off = 1 << d;
    if (t >= off){
      float Q[64];
      #pragma unroll
      for (int j=0;j<16;j++){
        f32x4 x = *(const f32x4*)&S0[(j*64 + (t-off))*4];
        Q[4*j]=x[0]; Q[4*j+1]=x[1]; Q[4*j+2]=x[2]; Q[4*j+3]=x[3];
      }
      #pragma unroll
      for (int i=0;i<8;i++){
        float r[8];
        #pragma unroll
        for (int cc=0;cc<8;cc++){
          float acc = 0.f;
          #pragma unroll
          for (int a=0;a<8;a++) acc = fmaf(M[i*8+a], Q[a*8+cc], acc);
          r[cc] = acc;
        }
        #pragma unroll
        for (int cc=0;cc<8;cc++) M[i*8+cc] = r[cc];
      }
    }
    if (d < 5){
      #pragma unroll
      for (int j=0;j<16;j++){
        f32x4 w = {M[4*j], M[4*j+1], M[4*j+2], M[4*j+3]};
        *(f32x4*)&S0[(j*64 + t)*4] = w;
      }
      __syncthreads();
    }
  }

  float* dst = OR + ((size_t)s*4096 + (size_t)c*64 + t)*64;
  #pragma unroll
  for (int j=0;j<16;j++){
    const int rb = 4*(j&1), col = j>>1;
    f32x4 w = {M[(rb+0)*8 + col], M[(rb+1)*8 + col], M[(rb+2)*8 + col], M[(rb+3)*8 + col]};
    *(f32x4*)(dst + 4*j) = w;
  }
}

// helpers: 8x8 matvec with 16 f32x4 regs
DEV void load16(const float* p, f32x4* M){
  #pragma unroll
  for (int q=0;q<16;q++) M[q] = *(const f32x4*)(p + 4*q);
}
DEV void rm_matvec8(const f32x4* M16, const float* x, float* res){
  #pragma unroll
  for (int i=0;i<8;i++){
    float acc = 0.f;
    #pragma unroll
    for (int a=0;a<8;a++) acc = fmaf(M16[2*i + (a>>2)][a&3], x[a], acc);
    res[i] = acc;
  }
}
DEV void cm_matvec8(const f32x4* M16, const float* x, float* res){
  #pragma unroll
  for (int i=0;i<8;i++){
    float acc = 0.f;
    #pragma unroll
    for (int a=0;a<8;a++) acc = fmaf(M16[2*a + (i>>2)][i&3], x[a], acc);
    res[i] = acc;
  }
}

// =================== C2: parallel Hillis-Steele scan of chunk products -> Rbase_c ===================
// 1 block = 1 seq, 1 wave, thread t = chunk t. Inclusive I_t = Q_t·...·Q_0 (own on LEFT);
// Rbase_{t+1} = I_t, Rbase_0 = Id. All matrices col-major (flat[c*8+i] = M[i][c]).
// In-place single-wave lockstep (reads of a level precede writes in program order).
__global__ __launch_bounds__(64) void chunkscan_kernel(const float* __restrict__ OR, float* __restrict__ Rbase)
{
  __shared__ float S[64*68];
  const int t = threadIdx.x;
  const int s = blockIdx.x;
  float M[64];
  const float* qs = OR + ((size_t)s*4096 + (size_t)t*64 + 63)*64;   // Q_t (chunk-final P)
  #pragma unroll
  for (int j=0;j<16;j++){
    f32x4 x = *(const f32x4*)(qs + 4*j);
    M[4*j]=x[0]; M[4*j+1]=x[1]; M[4*j+2]=x[2]; M[4*j+3]=x[3];
  }
  #pragma unroll
  for (int j=0;j<16;j++){
    f32x4 w = {M[4*j],M[4*j+1],M[4*j+2],M[4*j+3]};
    *(f32x4*)&S[t*68 + 4*j] = w;
  }
  __syncthreads();
  #pragma unroll
  for (int d=0; d<6; d++){
    const int off = 1 << d;
    if (t >= off){
      float Q[64];
      const float* p = &S[(t-off)*68];
      #pragma unroll
      for (int j=0;j<16;j++){
        f32x4 x = *(const f32x4*)(p + 4*j);
        Q[4*j]=x[0]; Q[4*j+1]=x[1]; Q[4*j+2]=x[2]; Q[4*j+3]=x[3];
      }
      // col-major product R = M·Q: R[:,c] = M · Q[:,c]
      float R[64];
      #pragma unroll
      for (int cc=0;cc<8;cc++)
        #pragma unroll
        for (int i=0;i<8;i++){
          float acc = 0.f;
          #pragma unroll
          for (int a=0;a<8;a++) acc = fmaf(M[a*8+i], Q[cc*8+a], acc);
          R[cc*8+i] = acc;
        }
      #pragma unroll
      for (int f=0;f<64;f++) M[f] = R[f];
    }
    if (d < 5){
      #pragma unroll
      for (int j=0;j<16;j++){
        f32x4 w = {M[4*j],M[4*j+1],M[4*j+2],M[4*j+3]};
        *(f32x4*)&S[t*68 + 4*j] = w;
      }
      __syncthreads();
    }
  }
  if (t < 63){
    float* dst = Rbase + ((size_t)s*64 + t + 1)*64;
    #pragma unroll
    for (int j=0;j<16;j++){
      f32x4 w = {M[4*j],M[4*j+1],M[4*j+2],M[4*j+3]};
      *(f32x4*)(dst + 4*j) = w;
    }
  }
  if (t == 0){
    float* dst = Rbase + (size_t)s*64*64;
    #pragma unroll
    for (int cc=0;cc<8;cc++)
      #pragma unroll
      for (int i=0;i<8;i++) dst[cc*8+i] = (i==cc) ? 1.f : 0.f;
  }
}

// =================== C3: rotate k/v/q via R_t^T = Rbase^T (P^T .) — no R materialization ===================
__global__ __launch_bounds__(256) void rotate_kvq_kernel(const float* __restrict__ OR, const float* __restrict__ Rbase,
    float* __restrict__ proj)
{
  int tid = blockIdx.x*256 + threadIdx.x;   // 262144
  int s = tid >> 12, t = tid & 4095;
  int c = t >> 6;
  int b = s >> 4, h = s & 15;
  int row = b*4096 + t;
  const float* slot = OR + ((size_t)s*4096 + t)*64;
  float* pr = proj + (size_t)row*896;
  float k[8], v[8], q[8];
  { f32x4 a = *(const f32x4*)(pr+448+h*8), b2 = *(const f32x4*)(pr+452+h*8);
    #pragma unroll
    for (int i=0;i<4;i++){ k[i]=a[i]; k[4+i]=b2[i]; } }
  { f32x4 a = *(const f32x4*)(pr+576+h*8), b2 = *(const f32x4*)(pr+580+h*8);
    #pragma unroll
    for (int i=0;i<4;i++){ v[i]=a[i]; v[4+i]=b2[i]; } }
  { f32x4 a = *(const f32x4*)(pr+704+h*8), b2 = *(const f32x4*)(pr+708+h*8);
    #pragma unroll
    for (int i=0;i<4;i++){ q[i]=a[i]; q[4+i]=b2[i]; } }
  float nn = 0.f;
  #pragma unroll
  for (int i=0;i<8;i++) nn = fmaf(k[i],k[i],nn);
  float inv = 1.f / fmaxf(sqrtf(nn), 1e-6f);
  #pragma unroll
  for (int i=0;i<8;i++) k[i] *= inv;

  f32x4 M[16];
  load16(slot, M);                           // P col-major -> rm gives P^T x
  float uk[8], uv[8], uq[8];
  rm_matvec8(M, k, uk);
  rm_matvec8(M, v, uv);
  rm_matvec8(M, q, uq);
  load16(Rbase + ((size_t)s*64 + c)*64, M);  // Rbase col-major -> rm gives Rbase^T x
  float kt[8], vt[8], qt[8];
  rm_matvec8(M, uk, kt);
  rm_matvec8(M, uv, vt);
  rm_matvec8(M, uq, qt);

  float beta = pr[832+h];
  float qk = 0.f;
  #pragma unroll
  for (int j=0;j<8;j++) qk = fmaf(kt[j], qt[j], qk);
  float* sip = pr + h*28;     // dead skew slot of this (row,h); writes <448, reads >=448
  f32x4 w0={kt[0],kt[1],kt[2],kt[3]}, w1={kt[4],kt[5],kt[6],kt[7]};
  f32x4 w2={vt[0],vt[1],vt[2],vt[3]}, w3={vt[4],vt[5],vt[6],vt[7]};
  f32x4 w4={qt[0],qt[1],qt[2],qt[3]}, w5={qt[4],qt[5],qt[6],qt[7]};
  f32x4 w6={beta, qk, 0.f, 0.f};
  *(f32x4*)(sip)=w0; *(f32x4*)(sip+4)=w1; *(f32x4*)(sip+8)=w2; *(f32x4*)(sip+12)=w3;
  *(f32x4*)(sip+16)=w4; *(f32x4*)(sip+20)=w5; *(f32x4*)(sip+24)=w6;
}

// =================== D: chunk-parallel delta scan (128 chunks x 32 steps) ===================
__global__ __launch_bounds__(256) void scan_pass1_kernel(const float* __restrict__ proj,
    float* __restrict__ Mbuf, float* __restrict__ wbuf)
{
  int tid = blockIdx.x*256 + threadIdx.x;   // 65536 = 8192 tasks * 8 lanes
  int task = tid >> 3, j = tid & 7;         // task = s*128 + c
  int s = task >> 7, c = task & 127;
  int b = s >> 4, h = s & 15;
  const float* rec = proj + ((size_t)b*4096 + (size_t)c*32)*896 + h*28;
  float m[8], w[8];
  #pragma unroll
  for (int i=0;i<8;i++){ m[i] = (i==j)?1.f:0.f; w[i] = 0.f; }
  f32x4 k0 = *(const f32x4*)(rec), k1 = *(const f32x4*)(rec+4);
  float vt = rec[8+j];
  float beta = rec[24];
  for (int tt=0; tt<32; tt++){
    const float* pn = rec + (size_t)(tt+1)*896;   // prefetch (last iter value unused)
    f32x4 nk0 = *(const f32x4*)(pn), nk1 = *(const f32x4*)(pn+4);
    float nvt = pn[8+j];
    float nbeta = pn[24];
    float s1, s2;
    s1 = ((k0[0]*m[0] + k0[1]*m[1]) + (k0[2]*m[2] + k0[3]*m[3]))
       + ((k1[0]*m[4] + k1[1]*m[5]) + (k1[2]*m[6] + k1[3]*m[7]));
    s2 = ((k0[0]*w[0] + k0[1]*w[1]) + (k0[2]*w[2] + k0[3]*w[3]))
       + ((k1[0]*w[4] + k1[1]*w[5]) + (k1[2]*w[6] + k1[3]*w[7]));
    float c1 = -beta*s1, c2 = beta*(vt - s2);
    #pragma unroll
    for (int i=0;i<4;i++){ m[i] = fmaf(k0[i], c1, m[i]); m[4+i] = fmaf(k1[i], c1, m[4+i]); }
    #pragma unroll
    for (int i=0;i<4;i++){ w[i] = fmaf(k0[i], c2, w[i]); w[4+i] = fmaf(k1[i], c2, w[4+i]); }
    k0=nk0; k1=nk1; vt=nvt; beta=nbeta;
  }
  float* md = Mbuf + (size_t)task*64 + j*8;
  float* wd = wbuf + (size_t)task*64 + j*8;
  f32x4 m0={m[0],m[1],m[2],m[3]}, m1={m[4],m[5],m[6],m[7]};
  f32x4 w0={w[0],w[1],w[2],w[3]}, w1={w[4],w[5],w[6],w[7]};
  *(f32x4*)(md) = m0; *(f32x4*)(md+4) = m1;
  *(f32x4*)(wd) = w0; *(f32x4*)(wd+4) = w1;
}

// =================== scan_mid: parallel affine scan over 128 chunks ===================
// Item c = (M_c, W_c) with state update C' = M_c C + W_c (both 8x8, col-major in Mbuf/wbuf).
// Compose own(newer)∘partner(older): M <- M·Mp, W <- M·Wp + W.
// 1 block = 1 seq, 512 threads: thread (c, g) owns columns 2g,2g+1 of item c.
// Double-barrier in-place LDS (2 waves+ require read-phase/write-phase separation).
// dstart_{c+1} = W-part of inclusive prefix at c; dstart_0 = 0.
__global__ __launch_bounds__(512) void scan_mid_kernel(const float* __restrict__ Mbuf,
    const float* __restrict__ wbuf, float* __restrict__ dstart)
{
  __shared__ float SM[128*68];
  __shared__ float SW[128*68];
  const int tid = threadIdx.x;
  const int c = tid >> 2, g = tid & 3;
  const int s = blockIdx.x;
  const size_t base = (size_t)s*128*64;
  const float* mp = Mbuf + base + (size_t)c*64 + (2*g)*8;
  const float* wp = wbuf + base + (size_t)c*64 + (2*g)*8;
  float W[16];
  {
    f32x4 a0 = *(const f32x4*)(mp),   a1 = *(const f32x4*)(mp+4);
    f32x4 a2 = *(const f32x4*)(mp+8), a3 = *(const f32x4*)(mp+12);
    f32x4 b0 = *(const f32x4*)(wp),   b1 = *(const f32x4*)(wp+4);
    f32x4 b2 = *(const f32x4*)(wp+8), b3 = *(const f32x4*)(wp+12);
    float* sm = &SM[c*68 + (2*g)*8];
    float* sw = &SW[c*68 + (2*g)*8];
    *(f32x4*)(sm) = a0; *(f32x4*)(sm+4) = a1; *(f32x4*)(sm+8) = a2; *(f32x4*)(sm+12) = a3;
    *(f32x4*)(sw) = b0; *(f32x4*)(sw+4) = b1; *(f32x4*)(sw+8) = b2; *(f32x4*)(sw+12) = b3;
    #pragma unroll
    for (int i=0;i<4;i++){ W[i]=b0[i]; W[4+i]=b1[i]; W[8+i]=b2[i]; W[12+i]=b3[i]; }
  }
  __syncthreads();
  for (int d=0; d<7; d++){
    const int off = 1 << d;
    const bool act = (c >= off);
    float Mo[64], pM[16], pW[16];
    if (act){
      const float* om = &SM[c*68];
      #pragma unroll
      for (int j=0;j<16;j++){
        f32x4 x = *(const f32x4*)(om + 4*j);
        Mo[4*j]=x[0]; Mo[4*j+1]=x[1]; Mo[4*j+2]=x[2]; Mo[4*j+3]=x[3];
      }
      const float* qm = &SM[(c-off)*68 + (2*g)*8];
      const float* qw = &SW[(c-off)*68 + (2*g)*8];
      #pragma unroll
      for (int j=0;j<4;j++){
        f32x4 x = *(const f32x4*)(qm + 4*j);
        f32x4 y = *(const f32x4*)(qw + 4*j);
        pM[4*j]=x[0]; pM[4*j+1]=x[1]; pM[4*j+2]=x[2]; pM[4*j+3]=x[3];
        pW[4*j]=y[0]; pW[4*j+1]=y[1]; pW[4*j+2]=y[2]; pW[4*j+3]=y[3];
      }
    }
    __syncthreads();
    if (act){
      float nM[16], nW[16];
      #pragma unroll
      for (int cl=0; cl<2; cl++){
        #pragma unroll
        for (int i=0;i<8;i++){
          float aM = 0.f, aW = 0.f;
          #pragma unroll
          for (int a=0;a<8;a++){
            aM = fmaf(Mo[a*8+i], pM[cl*8+a], aM);
            aW = fmaf(Mo[a*8+i], pW[cl*8+a], aW);
          }
          nM[cl*8+i] = aM;
          nW[cl*8+i] = aW + W[cl*8+i];
        }
      }
      float* sm = &SM[c*68 + (2*g)*8];
      float* sw = &SW[c*68 + (2*g)*8];
      #pragma unroll
      for (int j=0;j<4;j++){
        f32x4 x = {nM[4*j], nM[4*j+1], nM[4*j+2], nM[4*j+3]};
        f32x4 y = {nW[4*j], nW[4*j+1], nW[4*j+2], nW[4*j+3]};
        *(f32x4*)(sm + 4*j) = x;
        *(f32x4*)(sw + 4*j) = y;
      }
      #pragma unroll
      for (int f=0;f<16;f++) W[f] = nW[f];
    }
    __syncthreads();
  }
  if (c < 127){
    float* dd = dstart + base + (size_t)(c+1)*64 + (2*g)*8;
    f32x4 y0 = {W[0],W[1],W[2],W[3]}, y1 = {W[4],W[5],W[6],W[7]};
    f32x4 y2 = {W[8],W[9],W[10],W[11]}, y3 = {W[12],W[13],W[14],W[15]};
    *(f32x4*)(dd) = y0; *(f32x4*)(dd+4) = y1; *(f32x4*)(dd+8) = y2; *(f32x4*)(dd+12) = y3;
  }
  if (c == 0){
    float* dd = dstart + base + (2*g)*8;
    f32x4 z = {0.f,0.f,0.f,0.f};
    *(f32x4*)(dd) = z; *(f32x4*)(dd+4) = z; *(f32x4*)(dd+8) = z; *(f32x4*)(dd+12) = z;
  }
}

__global__ __launch_bounds__(256) void scan_pass2_kernel(const float* __restrict__ proj,
    const float* __restrict__ dstart, float* __restrict__ oo)
{
  int tid = blockIdx.x*256 + threadIdx.x;   // 65536
  int task = tid >> 3, j = tid & 7;
  int s = task >> 7, c = task & 127;
  int b = s >> 4, h = s & 15;
  const float* rec = proj + ((size_t)b*4096 + (size_t)c*32)*896 + h*28;
  float* op = oo + (((size_t)s*4096 + (size_t)c*32)*8) + j;
  float d[8];
  { const float* ds = dstart + (size_t)task*64 + j*8;
    f32x4 a = *(const f32x4*)(ds), b2 = *(const f32x4*)(ds+4);
    #pragma unroll
    for (int i=0;i<4;i++){ d[i]=a[i]; d[4+i]=b2[i]; } }
  f32x4 k0 = *(const f32x4*)(rec),    k1 = *(const f32x4*)(rec+4);
  f32x4 q0 = *(const f32x4*)(rec+16), q1 = *(const f32x4*)(rec+20);
  f32x4 mb = *(const f32x4*)(rec+24);
  float vt = rec[8+j];
  for (int tt=0; tt<32; tt++){
    const float* pn = rec + (size_t)(tt+1)*896;   // prefetch
    f32x4 nk0 = *(const f32x4*)(pn),    nk1 = *(const f32x4*)(pn+4);
    f32x4 nq0 = *(const f32x4*)(pn+16), nq1 = *(const f32x4*)(pn+20);
    f32x4 nmb = *(const f32x4*)(pn+24);
    float nvt = pn[8+j];
    float kd, qd;
    kd = ((k0[0]*d[0] + k0[1]*d[1]) + (k0[2]*d[2] + k0[3]*d[3]))
       + ((k1[0]*d[4] + k1[1]*d[5]) + (k1[2]*d[6] + k1[3]*d[7]));
    qd = ((q0[0]*d[0] + q0[1]*d[1]) + (q0[2]*d[2] + q0[3]*d[3]))
       + ((q1[0]*d[4] + q1[1]*d[5]) + (q1[2]*d[6] + q1[3]*d[7]));
    float w_ = mb[0] * (vt - kd);
    #pragma unroll
    for (int i=0;i<4;i++){ d[i] = fmaf(k0[i], w_, d[i]); d[4+i] = fmaf(k1[i], w_, d[4+i]); }
    op[(size_t)tt*8] = fmaf(mb[1], w_, qd);
    k0=nk0; k1=nk1; q0=nq0; q1=nq1; mb=nmb; vt=nvt;
  }
}

// =================== E: rotate outputs back: o = P (Rbase o~), write bf16 ===================
__global__ __launch_bounds__(256) void rotout_kernel(const float* __restrict__ OR, const float* __restrict__ Rbase,
                                                     const float* __restrict__ oo, u16* __restrict__ obf)
{
  int tid = blockIdx.x*256 + threadIdx.x;   // 262144
  int s = tid >> 12, t = tid & 4095;
  int c = t >> 6;
  int b = s >> 4, h = s & 15;
  int row = b*4096 + t;
  float u[8];
  { const float* up = oo + ((size_t)s*4096 + t)*8;
    f32x4 a = *(const f32x4*)(up), b2 = *(const f32x4*)(up+4);
    #pragma unroll
    for (int i=0;i<4;i++){ u[i]=a[i]; u[4+i]=b2[i]; } }
  f32x4 M[16];
  load16(Rbase + ((size_t)s*64 + c)*64, M);  // col-major -> cm gives Rbase * u
  float w[8];
  cm_matvec8(M, u, w);
  load16(OR + ((size_t)s*4096 + t)*64, M);   // P col-major -> cm gives P * w
  float o[8];
  cm_matvec8(M, w, o);
  u32 p0 = (u32)f2bf(o[0]) | ((u32)f2bf(o[1])<<16);
  u32 p1 = (u32)f2bf(o[2]) | ((u32)f2bf(o[3])<<16);
  u32 p2 = (u32)f2bf(o[4]) | ((u32)f2bf(o[5])<<16);
  u32 p3 = (u32)f2bf(o[6]) | ((u32)f2bf(o[7])<<16);
  u32x4 pk = {p0,p1,p2,p3};
  *(u32x4*)(void*)(obf + (size_t)row*128 + h*8) = pk;
}

// =================== launch ===================
extern "C" void kernel_launch(void* const* d_in, const int* in_sizes, int n_in,
                              void* d_out, int out_size, void* d_ws, size_t ws_size,
                              hipStream_t stream)
{
  const float* x     = (const float*)d_in[0];
  const float* Wskew = (const float*)d_in[1];
  const float* Wk    = (const float*)d_in[2];
  const float* Wv    = (const float*)d_in[3];
  const float* Wq    = (const float*)d_in[4];
  const float* Wbeta = (const float*)d_in[5];
  const float* bbeta = (const float*)d_in[6];
  const float* Wo    = (const float*)d_in[7];

  char* w = (char*)d_ws; size_t off = 0;
  auto alloc = [&](size_t bytes)->void*{ void* p = w + off; off += (bytes + 255) & ~(size_t)255; return p; };
  u16*   Wh     = (u16*)  alloc((size_t)896*1024*2);
  u16*   Wl     = (u16*)  alloc((size_t)896*1024*2);
  u16*   WoT    = (u16*)  alloc((size_t)1024*128*2);
  float* proj   = (float*)alloc((size_t)16384*896*4);
  float* OR     = (float*)alloc((size_t)262144*64*4);
  float* Rbase  = (float*)alloc((size_t)64*64*64*4);
  float* oo     = (float*)alloc((size_t)262144*8*4);
  float* Mbuf   = (float*)alloc((size_t)8192*64*4);
  float* wbuf   = (float*)alloc((size_t)8192*64*4);
  float* dstart = (float*)alloc((size_t)8192*64*4);
  u16*   obf    = (u16*)proj;   // proj fully dead after scan pass2

  hipLaunchKernelGGL(concat_kernel, dim3(4096), dim3(256), 0, stream,
                     Wskew, Wk, Wv, Wq, Wbeta, Wo, Wh, Wl, WoT);
  hipLaunchKernelGGL(gemm_proj_kernel, dim3(128,7), dim3(256), 0, stream,
                     x, Wh, Wl, proj, bbeta);
  hipLaunchKernelGGL(expm_scan_kernel, dim3(4096), dim3(64), 0, stream, proj, OR);
  hipLaunchKernelGGL(chunkscan_kernel, dim3(64), dim3(64), 0, stream, OR, Rbase);
  hipLaunchKernelGGL(rotate_kvq_kernel, dim3(1024), dim3(256), 0, stream, OR, Rbase, proj);
  hipLaunchKernelGGL(scan_pass1_kernel, dim3(256), dim3(256), 0, stream, proj, Mbuf, wbuf);
  hipLaunchKernelGGL(scan_mid_kernel, dim3(64), dim3(512), 0, stream, Mbuf, wbuf, dstart);
  hipLaunchKernelGGL(scan_pass2_kernel, dim3(256), dim3(256), 0, stream, proj, dstart, oo);
  hipLaunchKernelGGL(rotout_kernel, dim3(1024), dim3(256), 0, stream, OR, Rbase, oo, obf);
  hipLaunchKernelGGL(gemm_out_kernel, dim3(128,8), dim3(256), 0, stream,
                     obf, WoT, (float*)d_out);
}

// Round 6
// 363.776 us; speedup vs baseline: 1.5783x; 1.1894x over previous
//
#include <hip/hip_runtime.h>

typedef unsigned short u16;
typedef unsigned int u32;
typedef __attribute__((ext_vector_type(4))) float f32x4;
typedef __attribute__((ext_vector_type(8))) short short8;
typedef __attribute__((ext_vector_type(4))) unsigned int u32x4;

#define DEV __device__ __forceinline__

DEV float bf2f(u16 u){ union{u32 i; float f;} x; x.i = ((u32)u)<<16; return x.f; }
DEV u16 f2bf(float f){ union{u32 i; float f;} x; x.f = f; u32 r = x.i + 0x7fffu + ((x.i>>16)&1u); return (u16)(r>>16); }

union U8 { u16 u[8]; short8 s; };

// async global -> LDS, 16B per lane (dest must be wave-uniform base + lane*16; ours is tid*16)
DEV void gl16(const u16* g, u16* l){
  __builtin_amdgcn_global_load_lds(
      (const __attribute__((address_space(1))) u32*)g,
      (__attribute__((address_space(3))) u32*)l, 16, 0, 0);
}

// fast tanh/sigmoid via v_exp + v_rcp (err ~1e-6, dwarfed by bf16 input rounding)
DEV float fast_htanh(float v){           // 0.5*tanh(v)
  float vc = fminf(fmaxf(v, -15.f), 15.f);
  float e = __expf(2.f*vc);
  return 0.5f*(e - 1.f)*__builtin_amdgcn_rcpf(e + 1.f);
}
DEV float fast_sigmoid(float v){
  float e = __expf(-v);
  return __builtin_amdgcn_rcpf(1.f + e);
}

// =================== weight concat / transpose -> hi/lo bf16 planes ===================
__global__ __launch_bounds__(256) void concat_kernel(
    const float* __restrict__ Wskew, const float* __restrict__ Wk, const float* __restrict__ Wv,
    const float* __restrict__ Wq, const float* __restrict__ Wbeta, const float* __restrict__ Wo,
    u16* __restrict__ Wh, u16* __restrict__ Wl, u16* __restrict__ WoT)
{
  int idx = blockIdx.x*256 + threadIdx.x;
  if (idx < 896*1024){
    int n = idx >> 10, kk = idx & 1023;
    float v;
    if (n < 448)      v = Wskew[kk*448 + n];
    else if (n < 576) v = Wk[kk*128 + (n-448)];
    else if (n < 704) v = Wv[kk*128 + (n-576)];
    else if (n < 832) v = Wq[kk*128 + (n-704)];
    else if (n < 848) v = Wbeta[kk*16 + (n-832)];
    else              v = 0.f;
    u16 h = f2bf(v);
    Wh[idx] = h;
    Wl[idx] = f2bf(v - bf2f(h));
  } else {
    int r = idx - 896*1024;
    int n = r >> 7, kk = r & 127;
    WoT[r] = f2bf(Wo[kk*1024 + n]);
  }
}

// =================== proj GEMM: fused x-split + dbuf pipeline ===================
__global__ __launch_bounds__(256) void gemm_proj_kernel(
    const float* __restrict__ X,
    const u16* __restrict__ Bh, const u16* __restrict__ Bl,
    float* __restrict__ C, const float* __restrict__ bias)
{
  __shared__ u16 L[2*4*4096];   // [buf][plane Ah,Bh,Al,Bl][4096 u16]
  const int tid = threadIdx.x;
  const int wave = tid >> 6;
  const int lane = tid & 63;
  const int quad = lane >> 4, l15 = lane & 15;
  const int m0 = blockIdx.x * 128, n0 = blockIdx.y * 128;
  const bool full = (blockIdx.y < 4);
  const int wm = (wave >> 1) * 64, wn = (wave & 1) * 64;
  const bool wantLow = full && !(blockIdx.y == 3 && wn == 64);
  const bool skipBl1 = (blockIdx.y == 3);
  const int K = 1024, ldc = 896;
  const int sr = tid >> 2;
  const int sc = tid & 3;
  const int fS = (sr & 3) ^ ((sr >> 2) & 3);
  const int scS = ((sc ^ fS) << 3);            // swizzled k-offset (elements)
  const size_t gA0 = (size_t)(m0 + sr)*K + scS, gA1 = gA0 + (size_t)64*K;   // f32 on X
  const size_t gB0 = (size_t)(n0 + sr)*K + scS, gB1 = gB0 + (size_t)64*K;   // u16 on B
  const int d0 = tid*8, d1 = d0 + 2048;        // lane-linear LDS dest (byte = tid*16)
  const int fR = (l15 & 3) ^ ((l15 >> 2) & 3);
  const int rq = ((quad ^ fR) << 3);

  auto LOADA = [&](int kb, f32x4* va){
    va[0] = *(const f32x4*)(X + gA0 + kb);
    va[1] = *(const f32x4*)(X + gA0 + kb + 4);
    va[2] = *(const f32x4*)(X + gA1 + kb);
    va[3] = *(const f32x4*)(X + gA1 + kb + 4);
  };
  auto WRITEA = [&](int buf, const f32x4* va){
    u16* Lb = L + buf*16384;
    U8 h0, h1;
    #pragma unroll
    for (int e=0;e<4;e++){
      h0.u[e]   = f2bf(va[0][e]);
      h0.u[4+e] = f2bf(va[1][e]);
      h1.u[e]   = f2bf(va[2][e]);
      h1.u[4+e] = f2bf(va[3][e]);
    }
    *(short8*)&Lb[d0] = h0.s; *(short8*)&Lb[d1] = h1.s;
    if (full){
      U8 l0, l1;
      #pragma unroll
      for (int e=0;e<4;e++){
        l0.u[e]   = f2bf(va[0][e] - bf2f(h0.u[e]));
        l0.u[4+e] = f2bf(va[1][e] - bf2f(h0.u[4+e]));
        l1.u[e]   = f2bf(va[2][e] - bf2f(h1.u[e]));
        l1.u[4+e] = f2bf(va[3][e] - bf2f(h1.u[4+e]));
      }
      *(short8*)&Lb[8192+d0] = l0.s; *(short8*)&Lb[8192+d1] = l1.s;
    }
  };
  auto STAGEB = [&](int buf, int kb){
    u16* Lb = L + buf*16384;
    gl16(Bh + gB0 + kb, Lb + 4096 + d0);
    gl16(Bh + gB1 + kb, Lb + 4096 + d1);
    if (full){
      gl16(Bl + gB0 + kb, Lb + 12288 + d0);
      if (!skipBl1) gl16(Bl + gB1 + kb, Lb + 12288 + d1);
    }
  };

  f32x4 acc[4][4] = {};
  { f32x4 va[4]; LOADA(0, va); STAGEB(0, 0); WRITEA(0, va); }
  __syncthreads();
  int cur = 0;
  for (int kb = 0; kb < K; kb += 32){
    const bool hasNext = (kb + 32 < K);
    f32x4 vn[4];
    if (hasNext){ LOADA(kb + 32, vn); STAGEB(cur^1, kb + 32); }   // issue loads FIRST
    u16* Lb = L + cur*16384;
    short8 afh[4], bfh[4];
    #pragma unroll
    for (int mi=0;mi<4;mi++) afh[mi] = *(const short8*)&Lb[(wm + mi*16 + l15)*32 + rq];
    #pragma unroll
    for (int ni=0;ni<4;ni++) bfh[ni] = *(const short8*)&Lb[4096 + (wn + ni*16 + l15)*32 + rq];
    #pragma unroll
    for (int mi=0;mi<4;mi++)
      #pragma unroll
      for (int ni=0;ni<4;ni++)
        acc[mi][ni] = __builtin_amdgcn_mfma_f32_16x16x32_bf16(afh[mi], bfh[ni], acc[mi][ni], 0,0,0);
    if (wantLow){
      short8 afl[4], bfl[4];
      #pragma unroll
      for (int mi=0;mi<4;mi++) afl[mi] = *(const short8*)&Lb[8192 + (wm + mi*16 + l15)*32 + rq];
      #pragma unroll
      for (int ni=0;ni<4;ni++) bfl[ni] = *(const short8*)&Lb[12288 + (wn + ni*16 + l15)*32 + rq];
      #pragma unroll
      for (int mi=0;mi<4;mi++)
        #pragma unroll
        for (int ni=0;ni<4;ni++){
          acc[mi][ni] = __builtin_amdgcn_mfma_f32_16x16x32_bf16(afh[mi], bfl[ni], acc[mi][ni], 0,0,0);
          acc[mi][ni] = __builtin_amdgcn_mfma_f32_16x16x32_bf16(afl[mi], bfh[ni], acc[mi][ni], 0,0,0);
        }
    }
    if (hasNext) WRITEA(cur^1, vn);   // LDS write late: buffer free since prev-iter barrier
    __syncthreads();
    cur ^= 1;
  }
  #pragma unroll
  for (int mi=0;mi<4;mi++){
    #pragma unroll
    for (int ni=0;ni<4;ni++){
      const int col = n0 + wn + ni*16 + l15;
      const int rb_ = m0 + wm + mi*16 + quad*4;
      #pragma unroll
      for (int r=0;r<4;r++){
        float v = acc[mi][ni][r];
        const int row = rb_ + r;
        if (col < 448) v = fast_htanh(v);
        else if (col >= 832 && col < 848) v = fast_sigmoid(v + bias[col-832]);
        C[(size_t)row*ldc + col] = v;
      }
    }
  }
}

// =================== output GEMM: bf16 A/Bt -> fp32 C (dbuf pipeline, K=128) ===================
__global__ __launch_bounds__(256) void gemm_out_kernel(
    const u16* __restrict__ A, const u16* __restrict__ Bt, float* __restrict__ C)
{
  __shared__ u16 L[2*2*4096];
  const int tid = threadIdx.x;
  const int wave = tid >> 6;
  const int lane = tid & 63;
  const int quad = lane >> 4, l15 = lane & 15;
  const int m0 = blockIdx.x * 128, n0 = blockIdx.y * 128;
  const int wm = (wave >> 1) * 64, wn = (wave & 1) * 64;
  const int K = 128, ldc = 1024;
  const int sr = tid >> 2;
  const int sc = tid & 3;
  const int fS = (sr & 3) ^ ((sr >> 2) & 3);
  const int scS = ((sc ^ fS) << 3);
  const size_t gA0 = (size_t)(m0 + sr)*K + scS, gA1 = gA0 + (size_t)64*K;
  const size_t gB0 = (size_t)(n0 + sr)*K + scS, gB1 = gB0 + (size_t)64*K;
  const int d0 = tid*8, d1 = d0 + 2048;
  const int fR = (l15 & 3) ^ ((l15 >> 2) & 3);
  const int rq = ((quad ^ fR) << 3);

  auto STAGE = [&](int buf, int kb){
    u16* Lb = L + buf*8192;
    gl16(A  + gA0 + kb, Lb + d0);
    gl16(A  + gA1 + kb, Lb + d1);
    gl16(Bt + gB0 + kb, Lb + 4096 + d0);
    gl16(Bt + gB1 + kb, Lb + 4096 + d1);
  };

  f32x4 acc[4][4] = {};
  STAGE(0, 0);
  __syncthreads();
  int cur = 0;
  for (int kb = 0; kb < K; kb += 32){
    if (kb + 32 < K) STAGE(cur^1, kb + 32);
    u16* Lb = L + cur*8192;
    short8 af[4], bf8[4];
    #pragma unroll
    for (int mi=0;mi<4;mi++) af[mi] = *(const short8*)&Lb[(wm + mi*16 + l15)*32 + rq];
    #pragma unroll
    for (int ni=0;ni<4;ni++) bf8[ni] = *(const short8*)&Lb[4096 + (wn + ni*16 + l15)*32 + rq];
    #pragma unroll
    for (int mi=0;mi<4;mi++)
      #pragma unroll
      for (int ni=0;ni<4;ni++)
        acc[mi][ni] = __builtin_amdgcn_mfma_f32_16x16x32_bf16(af[mi], bf8[ni], acc[mi][ni], 0,0,0);
    __syncthreads();
    cur ^= 1;
  }
  #pragma unroll
  for (int mi=0;mi<4;mi++)
    #pragma unroll
    for (int ni=0;ni<4;ni++){
      const int col = n0 + wn + ni*16 + l15;
      const int rb_ = m0 + wm + mi*16 + quad*4;
      #pragma unroll
      for (int r=0;r<4;r++)
        C[(size_t)(rb_ + r)*ldc + col] = acc[mi][ni][r];
    }
}

// =================== fused expm + chunk prefix scan (1 thread = 1 matrix) ===================
// __launch_bounds__(64, 1): 1 wave/EU min -> VGPR budget ~512. The kernel's live set is
// ~200 regs (M[64]+Q[64]+addr); without this the allocator capped at 96 and spilled
// (R5 counters: VGPR=96, WRITE_SIZE 77MB vs 64MB expected, dur 2x).
__device__ constexpr int TRI_I[28] = {0,0,0,0,0,0,0, 1,1,1,1,1,1, 2,2,2,2,2, 3,3,3,3, 4,4,4, 5,5, 6};
__device__ constexpr int TRI_J[28] = {1,2,3,4,5,6,7, 2,3,4,5,6,7, 3,4,5,6,7, 4,5,6,7, 5,6,7, 6,7, 7};

__global__ __launch_bounds__(64, 1) void expm_scan_kernel(const float* __restrict__ proj, float* __restrict__ OR)
{
  __shared__ float S0[16*64*4];   // [j(0..15)][t(0..63)] f32x4
  const int t = threadIdx.x;
  const int s = blockIdx.x >> 6, c = blockIdx.x & 63;   // 4096 blocks
  const int b = s >> 4, h = s & 15;
  const int row = b*4096 + c*64 + t;
  const float* sk = proj + (size_t)row*896 + h*28;

  float v[28];
  {
    f32x4 vv[7];
    #pragma unroll
    for (int i=0;i<7;i++) vv[i] = *(const f32x4*)(sk + 4*i);
    #pragma unroll
    for (int i=0;i<28;i++) v[i] = vv[i>>2][i&3] * 0.0625f;
  }

  float M[64], T[64];
  auto bmul = [&](const float* Min, float* Tout){
    #pragma unroll
    for (int i=0;i<8;i++){
      #pragma unroll
      for (int cc=0;cc<8;cc++){
        float acc = 0.f;
        #pragma unroll
        for (int a=0;a<8;a++){
          if (a == i) continue;
          const int k = (i<a) ? (i*7 - (i*(i-1))/2 + a - i - 1)
                              : (a*7 - (a*(a-1))/2 + i - a - 1);
          if (i<a) acc = fmaf( v[k], Min[a*8+cc], acc);
          else     acc = fmaf(-v[k], Min[a*8+cc], acc);
        }
        Tout[i*8+cc] = acc;
      }
    }
  };
  #pragma unroll
  for (int i=0;i<8;i++){
    #pragma unroll
    for (int jj=0;jj<8;jj++){
      float bv = 0.f;
      if (i < jj){ const int k = i*7 - (i*(i-1))/2 + jj - i - 1; bv =  v[k]; }
      if (i > jj){ const int k = jj*7 - (jj*(jj-1))/2 + i - jj - 1; bv = -v[k]; }
      M[i*8+jj] = bv*(1.f/6.f) + ((i==jj)?1.f:0.f);
    }
  }
  const float coef[5] = {0.2f, 0.25f, 1.f/3.f, 0.5f, 1.f};
  #pragma unroll
  for (int st=0; st<5; st++){
    bmul(M, T);
    #pragma unroll
    for (int i=0;i<8;i++)
      #pragma unroll
      for (int jj=0;jj<8;jj++)
        M[i*8+jj] = T[i*8+jj]*coef[st] + ((i==jj)?1.f:0.f);
  }
  #pragma unroll
  for (int sq=0; sq<4; sq++){
    #pragma unroll
    for (int i=0;i<8;i++)
      #pragma unroll
      for (int cc=0;cc<8;cc++){
        float acc = 0.f;
        #pragma unroll
        for (int a=0;a<8;a++) acc = fmaf(M[i*8+a], M[a*8+cc], acc);
        T[i*8+cc] = acc;
      }
    #pragma unroll
    for (int f=0;f<64;f++) M[f] = T[f];
  }
  #pragma unroll
  for (int j=0;j<16;j++){
    f32x4 w = {M[4*j], M[4*j+1], M[4*j+2], M[4*j+3]};
    *(f32x4*)&S0[(j*64 + t)*4] = w;
  }
  __syncthreads();

  #pragma unroll
  for (int d=0; d<6; d++){
    const int off = 1 << d;
    if (t >= off){
      float Q[64];
      #pragma unroll
      for (int j=0;j<16;j++){
        f32x4 x = *(const f32x4*)&S0[(j*64 + (t-off))*4];
        Q[4*j]=x[0]; Q[4*j+1]=x[1]; Q[4*j+2]=x[2]; Q[4*j+3]=x[3];
      }
      #pragma unroll
      for (int i=0;i<8;i++){
        float r[8];
        #pragma unroll
        for (int cc=0;cc<8;cc++){
          float acc = 0.f;
          #pragma unroll
          for (int a=0;a<8;a++) acc = fmaf(M[i*8+a], Q[a*8+cc], acc);
          r[cc] = acc;
        }
        #pragma unroll
        for (int cc=0;cc<8;cc++) M[i*8+cc] = r[cc];
      }
    }
    if (d < 5){
      #pragma unroll
      for (int j=0;j<16;j++){
        f32x4 w = {M[4*j], M[4*j+1], M[4*j+2], M[4*j+3]};
        *(f32x4*)&S0[(j*64 + t)*4] = w;
      }
      __syncthreads();
    }
  }

  float* dst = OR + ((size_t)s*4096 + (size_t)c*64 + t)*64;
  #pragma unroll
  for (int j=0;j<16;j++){
    const int rb = 4*(j&1), col = j>>1;
    f32x4 w = {M[(rb+0)*8 + col], M[(rb+1)*8 + col], M[(rb+2)*8 + col], M[(rb+3)*8 + col]};
    *(f32x4*)(dst + 4*j) = w;
  }
}

// helpers: 8x8 matvec with 16 f32x4 regs
DEV void load16(const float* p, f32x4* M){
  #pragma unroll
  for (int q=0;q<16;q++) M[q] = *(const f32x4*)(p + 4*q);
}
DEV void rm_matvec8(const f32x4* M16, const float* x, float* res){
  #pragma unroll
  for (int i=0;i<8;i++){
    float acc = 0.f;
    #pragma unroll
    for (int a=0;a<8;a++) acc = fmaf(M16[2*i + (a>>2)][a&3], x[a], acc);
    res[i] = acc;
  }
}
DEV void cm_matvec8(const f32x4* M16, const float* x, float* res){
  #pragma unroll
  for (int i=0;i<8;i++){
    float acc = 0.f;
    #pragma unroll
    for (int a=0;a<8;a++) acc = fmaf(M16[2*a + (i>>2)][i&3], x[a], acc);
    res[i] = acc;
  }
}

// =================== C2: parallel Hillis-Steele scan of chunk products -> Rbase_c ===================
__global__ __launch_bounds__(64, 1) void chunkscan_kernel(const float* __restrict__ OR, float* __restrict__ Rbase)
{
  __shared__ float S[64*68];
  const int t = threadIdx.x;
  const int s = blockIdx.x;
  float M[64];
  const float* qs = OR + ((size_t)s*4096 + (size_t)t*64 + 63)*64;   // Q_t (chunk-final P)
  #pragma unroll
  for (int j=0;j<16;j++){
    f32x4 x = *(const f32x4*)(qs + 4*j);
    M[4*j]=x[0]; M[4*j+1]=x[1]; M[4*j+2]=x[2]; M[4*j+3]=x[3];
  }
  #pragma unroll
  for (int j=0;j<16;j++){
    f32x4 w = {M[4*j],M[4*j+1],M[4*j+2],M[4*j+3]};
    *(f32x4*)&S[t*68 + 4*j] = w;
  }
  __syncthreads();
  #pragma unroll
  for (int d=0; d<6; d++){
    const int off = 1 << d;
    if (t >= off){
      float Q[64];
      const float* p = &S[(t-off)*68];
      #pragma unroll
      for (int j=0;j<16;j++){
        f32x4 x = *(const f32x4*)(p + 4*j);
        Q[4*j]=x[0]; Q[4*j+1]=x[1]; Q[4*j+2]=x[2]; Q[4*j+3]=x[3];
      }
      // col-major product R = M·Q: R[:,c] = M · Q[:,c]
      float R[64];
      #pragma unroll
      for (int cc=0;cc<8;cc++)
        #pragma unroll
        for (int i=0;i<8;i++){
          float acc = 0.f;
          #pragma unroll
          for (int a=0;a<8;a++) acc = fmaf(M[a*8+i], Q[cc*8+a], acc);
          R[cc*8+i] = acc;
        }
      #pragma unroll
      for (int f=0;f<64;f++) M[f] = R[f];
    }
    if (d < 5){
      #pragma unroll
      for (int j=0;j<16;j++){
        f32x4 w = {M[4*j],M[4*j+1],M[4*j+2],M[4*j+3]};
        *(f32x4*)&S[t*68 + 4*j] = w;
      }
      __syncthreads();
    }
  }
  if (t < 63){
    float* dst = Rbase + ((size_t)s*64 + t + 1)*64;
    #pragma unroll
    for (int j=0;j<16;j++){
      f32x4 w = {M[4*j],M[4*j+1],M[4*j+2],M[4*j+3]};
      *(f32x4*)(dst + 4*j) = w;
    }
  }
  if (t == 0){
    float* dst = Rbase + (size_t)s*64*64;
    #pragma unroll
    for (int cc=0;cc<8;cc++)
      #pragma unroll
      for (int i=0;i<8;i++) dst[cc*8+i] = (i==cc) ? 1.f : 0.f;
  }
}

// =================== C3: rotate k/v/q via R_t^T = Rbase^T (P^T .) — no R materialization ===================
__global__ __launch_bounds__(256) void rotate_kvq_kernel(const float* __restrict__ OR, const float* __restrict__ Rbase,
    float* __restrict__ proj)
{
  int tid = blockIdx.x*256 + threadIdx.x;   // 262144
  int s = tid >> 12, t = tid & 4095;
  int c = t >> 6;
  int b = s >> 4, h = s & 15;
  int row = b*4096 + t;
  const float* slot = OR + ((size_t)s*4096 + t)*64;
  float* pr = proj + (size_t)row*896;
  float k[8], v[8], q[8];
  { f32x4 a = *(const f32x4*)(pr+448+h*8), b2 = *(const f32x4*)(pr+452+h*8);
    #pragma unroll
    for (int i=0;i<4;i++){ k[i]=a[i]; k[4+i]=b2[i]; } }
  { f32x4 a = *(const f32x4*)(pr+576+h*8), b2 = *(const f32x4*)(pr+580+h*8);
    #pragma unroll
    for (int i=0;i<4;i++){ v[i]=a[i]; v[4+i]=b2[i]; } }
  { f32x4 a = *(const f32x4*)(pr+704+h*8), b2 = *(const f32x4*)(pr+708+h*8);
    #pragma unroll
    for (int i=0;i<4;i++){ q[i]=a[i]; q[4+i]=b2[i]; } }
  float nn = 0.f;
  #pragma unroll
  for (int i=0;i<8;i++) nn = fmaf(k[i],k[i],nn);
  float inv = 1.f / fmaxf(sqrtf(nn), 1e-6f);
  #pragma unroll
  for (int i=0;i<8;i++) k[i] *= inv;

  f32x4 M[16];
  load16(slot, M);                           // P col-major -> rm gives P^T x
  float uk[8], uv[8], uq[8];
  rm_matvec8(M, k, uk);
  rm_matvec8(M, v, uv);
  rm_matvec8(M, q, uq);
  load16(Rbase + ((size_t)s*64 + c)*64, M);  // Rbase col-major -> rm gives Rbase^T x
  float kt[8], vt[8], qt[8];
  rm_matvec8(M, uk, kt);
  rm_matvec8(M, uv, vt);
  rm_matvec8(M, uq, qt);

  float beta = pr[832+h];
  float qk = 0.f;
  #pragma unroll
  for (int j=0;j<8;j++) qk = fmaf(kt[j], qt[j], qk);
  float* sip = pr + h*28;     // dead skew slot of this (row,h); writes <448, reads >=448
  f32x4 w0={kt[0],kt[1],kt[2],kt[3]}, w1={kt[4],kt[5],kt[6],kt[7]};
  f32x4 w2={vt[0],vt[1],vt[2],vt[3]}, w3={vt[4],vt[5],vt[6],vt[7]};
  f32x4 w4={qt[0],qt[1],qt[2],qt[3]}, w5={qt[4],qt[5],qt[6],qt[7]};
  f32x4 w6={beta, qk, 0.f, 0.f};
  *(f32x4*)(sip)=w0; *(f32x4*)(sip+4)=w1; *(f32x4*)(sip+8)=w2; *(f32x4*)(sip+12)=w3;
  *(f32x4*)(sip+16)=w4; *(f32x4*)(sip+20)=w5; *(f32x4*)(sip+24)=w6;
}

// =================== D: chunk-parallel delta scan (256 chunks x 16 steps) ===================
// 256 chunks doubles resident waves (8/CU) and halves the serial chain vs 128x32.
__global__ __launch_bounds__(256) void scan_pass1_kernel(const float* __restrict__ proj,
    float* __restrict__ Mbuf, float* __restrict__ wbuf)
{
  int tid = blockIdx.x*256 + threadIdx.x;   // 131072 = 16384 tasks * 8 lanes
  int task = tid >> 3, j = tid & 7;         // task = s*256 + c
  int s = task >> 8, c = task & 255;
  int b = s >> 4, h = s & 15;
  const float* rec = proj + ((size_t)b*4096 + (size_t)c*16)*896 + h*28;
  float m[8], w[8];
  #pragma unroll
  for (int i=0;i<8;i++){ m[i] = (i==j)?1.f:0.f; w[i] = 0.f; }
  f32x4 k0 = *(const f32x4*)(rec), k1 = *(const f32x4*)(rec+4);
  float vt = rec[8+j];
  float beta = rec[24];
  for (int tt=0; tt<16; tt++){
    const float* pn = rec + (size_t)(tt+1)*896;   // prefetch (last iter value unused)
    f32x4 nk0 = *(const f32x4*)(pn), nk1 = *(const f32x4*)(pn+4);
    float nvt = pn[8+j];
    float nbeta = pn[24];
    float s1, s2;
    s1 = ((k0[0]*m[0] + k0[1]*m[1]) + (k0[2]*m[2] + k0[3]*m[3]))
       + ((k1[0]*m[4] + k1[1]*m[5]) + (k1[2]*m[6] + k1[3]*m[7]));
    s2 = ((k0[0]*w[0] + k0[1]*w[1]) + (k0[2]*w[2] + k0[3]*w[3]))
       + ((k1[0]*w[4] + k1[1]*w[5]) + (k1[2]*w[6] + k1[3]*w[7]));
    float c1 = -beta*s1, c2 = beta*(vt - s2);
    #pragma unroll
    for (int i=0;i<4;i++){ m[i] = fmaf(k0[i], c1, m[i]); m[4+i] = fmaf(k1[i], c1, m[4+i]); }
    #pragma unroll
    for (int i=0;i<4;i++){ w[i] = fmaf(k0[i], c2, w[i]); w[4+i] = fmaf(k1[i], c2, w[4+i]); }
    k0=nk0; k1=nk1; vt=nvt; beta=nbeta;
  }
  float* md = Mbuf + (size_t)task*64 + j*8;
  float* wd = wbuf + (size_t)task*64 + j*8;
  f32x4 m0={m[0],m[1],m[2],m[3]}, m1={m[4],m[5],m[6],m[7]};
  f32x4 w0={w[0],w[1],w[2],w[3]}, w1={w[4],w[5],w[6],w[7]};
  *(f32x4*)(md) = m0; *(f32x4*)(md+4) = m1;
  *(f32x4*)(wd) = w0; *(f32x4*)(wd+4) = w1;
}

// =================== scan_mid: parallel affine scan over 256 chunks ===================
// Item c = (M_c, W_c): C' = M_c C + W_c. Compose own(newer)∘partner: M<-M·Mp, W<-M·Wp+W.
// 512 threads: thread (c, g) g∈{0,1} owns columns 4g..4g+3 (keeps live set ~200 regs,
// under the 256-VGPR cap at 2 waves/SIMD). 8 levels, double-barrier in-place LDS.
__global__ __launch_bounds__(512) void scan_mid_kernel(const float* __restrict__ Mbuf,
    const float* __restrict__ wbuf, float* __restrict__ dstart)
{
  __shared__ float SM[256*68];
  __shared__ float SW[256*68];
  const int tid = threadIdx.x;
  const int c = tid >> 1, g = tid & 1;
  const int s = blockIdx.x;
  const size_t base = (size_t)s*256*64;
  const float* mp = Mbuf + base + (size_t)c*64 + 32*g;
  const float* wp = wbuf + base + (size_t)c*64 + 32*g;
  float W[32];
  {
    float* sm = &SM[c*68 + 32*g];
    float* sw = &SW[c*68 + 32*g];
    #pragma unroll
    for (int j=0;j<8;j++){
      f32x4 a = *(const f32x4*)(mp + 4*j);
      f32x4 b = *(const f32x4*)(wp + 4*j);
      *(f32x4*)(sm + 4*j) = a;
      *(f32x4*)(sw + 4*j) = b;
      W[4*j]=b[0]; W[4*j+1]=b[1]; W[4*j+2]=b[2]; W[4*j+3]=b[3];
    }
  }
  __syncthreads();
  for (int d=0; d<8; d++){
    const int off = 1 << d;
    const bool act = (c >= off);
    float Mo[64], pM[32], pW[32];
    if (act){
      const float* om = &SM[c*68];
      #pragma unroll
      for (int j=0;j<16;j++){
        f32x4 x = *(const f32x4*)(om + 4*j);
        Mo[4*j]=x[0]; Mo[4*j+1]=x[1]; Mo[4*j+2]=x[2]; Mo[4*j+3]=x[3];
      }
      const float* qm = &SM[(c-off)*68 + 32*g];
      const float* qw = &SW[(c-off)*68 + 32*g];
      #pragma unroll
      for (int j=0;j<8;j++){
        f32x4 x = *(const f32x4*)(qm + 4*j);
        f32x4 y = *(const f32x4*)(qw + 4*j);
        pM[4*j]=x[0]; pM[4*j+1]=x[1]; pM[4*j+2]=x[2]; pM[4*j+3]=x[3];
        pW[4*j]=y[0]; pW[4*j+1]=y[1]; pW[4*j+2]=y[2]; pW[4*j+3]=y[3];
      }
    }
    __syncthreads();
    if (act){
      float nM[32], nW[32];
      #pragma unroll
      for (int cl=0; cl<4; cl++){
        #pragma unroll
        for (int i=0;i<8;i++){
          float aM = 0.f, aW = 0.f;
          #pragma unroll
          for (int a=0;a<8;a++){
            aM = fmaf(Mo[a*8+i], pM[cl*8+a], aM);
            aW = fmaf(Mo[a*8+i], pW[cl*8+a], aW);
          }
          nM[cl*8+i] = aM;
          nW[cl*8+i] = aW + W[cl*8+i];
        }
      }
      float* sm = &SM[c*68 + 32*g];
      float* sw = &SW[c*68 + 32*g];
      #pragma unroll
      for (int j=0;j<8;j++){
        f32x4 x = {nM[4*j], nM[4*j+1], nM[4*j+2], nM[4*j+3]};
        f32x4 y = {nW[4*j], nW[4*j+1], nW[4*j+2], nW[4*j+3]};
        *(f32x4*)(sm + 4*j) = x;
        *(f32x4*)(sw + 4*j) = y;
      }
      #pragma unroll
      for (int f=0;f<32;f++) W[f] = nW[f];
    }
    __syncthreads();
  }
  if (c < 255){
    float* dd = dstart + base + (size_t)(c+1)*64 + 32*g;
    #pragma unroll
    for (int j=0;j<8;j++){
      f32x4 y = {W[4*j],W[4*j+1],W[4*j+2],W[4*j+3]};
      *(f32x4*)(dd + 4*j) = y;
    }
  }
  if (c == 0){
    float* dd = dstart + base + 32*g;
    f32x4 z = {0.f,0.f,0.f,0.f};
    #pragma unroll
    for (int j=0;j<8;j++) *(f32x4*)(dd + 4*j) = z;
  }
}

__global__ __launch_bounds__(256) void scan_pass2_kernel(const float* __restrict__ proj,
    const float* __restrict__ dstart, float* __restrict__ oo)
{
  int tid = blockIdx.x*256 + threadIdx.x;   // 131072
  int task = tid >> 3, j = tid & 7;
  int s = task >> 8, c = task & 255;
  int b = s >> 4, h = s & 15;
  const float* rec = proj + ((size_t)b*4096 + (size_t)c*16)*896 + h*28;
  float* op = oo + (((size_t)s*4096 + (size_t)c*16)*8) + j;
  float d[8];
  { const float* ds = dstart + (size_t)task*64 + j*8;
    f32x4 a = *(const f32x4*)(ds), b2 = *(const f32x4*)(ds+4);
    #pragma unroll
    for (int i=0;i<4;i++){ d[i]=a[i]; d[4+i]=b2[i]; } }
  f32x4 k0 = *(const f32x4*)(rec),    k1 = *(const f32x4*)(rec+4);
  f32x4 q0 = *(const f32x4*)(rec+16), q1 = *(const f32x4*)(rec+20);
  f32x4 mb = *(const f32x4*)(rec+24);
  float vt = rec[8+j];
  for (int tt=0; tt<16; tt++){
    const float* pn = rec + (size_t)(tt+1)*896;   // prefetch
    f32x4 nk0 = *(const f32x4*)(pn),    nk1 = *(const f32x4*)(pn+4);
    f32x4 nq0 = *(const f32x4*)(pn+16), nq1 = *(const f32x4*)(pn+20);
    f32x4 nmb = *(const f32x4*)(pn+24);
    float nvt = pn[8+j];
    float kd, qd;
    kd = ((k0[0]*d[0] + k0[1]*d[1]) + (k0[2]*d[2] + k0[3]*d[3]))
       + ((k1[0]*d[4] + k1[1]*d[5]) + (k1[2]*d[6] + k1[3]*d[7]));
    qd = ((q0[0]*d[0] + q0[1]*d[1]) + (q0[2]*d[2] + q0[3]*d[3]))
       + ((q1[0]*d[4] + q1[1]*d[5]) + (q1[2]*d[6] + q1[3]*d[7]));
    float w_ = mb[0] * (vt - kd);
    #pragma unroll
    for (int i=0;i<4;i++){ d[i] = fmaf(k0[i], w_, d[i]); d[4+i] = fmaf(k1[i], w_, d[4+i]); }
    op[(size_t)tt*8] = fmaf(mb[1], w_, qd);
    k0=nk0; k1=nk1; q0=nq0; q1=nq1; mb=nmb; vt=nvt;
  }
}

// =================== E: rotate outputs back: o = P (Rbase o~), write bf16 ===================
__global__ __launch_bounds__(256) void rotout_kernel(const float* __restrict__ OR, const float* __restrict__ Rbase,
                                                     const float* __restrict__ oo, u16* __restrict__ obf)
{
  int tid = blockIdx.x*256 + threadIdx.x;   // 262144
  int s = tid >> 12, t = tid & 4095;
  int c = t >> 6;
  int b = s >> 4, h = s & 15;
  int row = b*4096 + t;
  float u[8];
  { const float* up = oo + ((size_t)s*4096 + t)*8;
    f32x4 a = *(const f32x4*)(up), b2 = *(const f32x4*)(up+4);
    #pragma unroll
    for (int i=0;i<4;i++){ u[i]=a[i]; u[4+i]=b2[i]; } }
  f32x4 M[16];
  load16(Rbase + ((size_t)s*64 + c)*64, M);  // col-major -> cm gives Rbase * u
  float w[8];
  cm_matvec8(M, u, w);
  load16(OR + ((size_t)s*4096 + t)*64, M);   // P col-major -> cm gives P * w
  float o[8];
  cm_matvec8(M, w, o);
  u32 p0 = (u32)f2bf(o[0]) | ((u32)f2bf(o[1])<<16);
  u32 p1 = (u32)f2bf(o[2]) | ((u32)f2bf(o[3])<<16);
  u32 p2 = (u32)f2bf(o[4]) | ((u32)f2bf(o[5])<<16);
  u32 p3 = (u32)f2bf(o[6]) | ((u32)f2bf(o[7])<<16);
  u32x4 pk = {p0,p1,p2,p3};
  *(u32x4*)(void*)(obf + (size_t)row*128 + h*8) = pk;
}

// =================== launch ===================
extern "C" void kernel_launch(void* const* d_in, const int* in_sizes, int n_in,
                              void* d_out, int out_size, void* d_ws, size_t ws_size,
                              hipStream_t stream)
{
  const float* x     = (const float*)d_in[0];
  const float* Wskew = (const float*)d_in[1];
  const float* Wk    = (const float*)d_in[2];
  const float* Wv    = (const float*)d_in[3];
  const float* Wq    = (const float*)d_in[4];
  const float* Wbeta = (const float*)d_in[5];
  const float* bbeta = (const float*)d_in[6];
  const float* Wo    = (const float*)d_in[7];

  char* w = (char*)d_ws; size_t off = 0;
  auto alloc = [&](size_t bytes)->void*{ void* p = w + off; off += (bytes + 255) & ~(size_t)255; return p; };
  u16*   Wh     = (u16*)  alloc((size_t)896*1024*2);
  u16*   Wl     = (u16*)  alloc((size_t)896*1024*2);
  u16*   WoT    = (u16*)  alloc((size_t)1024*128*2);
  float* proj   = (float*)alloc((size_t)16384*896*4);
  float* OR     = (float*)alloc((size_t)262144*64*4);
  float* Rbase  = (float*)alloc((size_t)64*64*64*4);
  float* oo     = (float*)alloc((size_t)262144*8*4);
  float* Mbuf   = (float*)alloc((size_t)16384*64*4);
  float* wbuf   = (float*)alloc((size_t)16384*64*4);
  float* dstart = (float*)alloc((size_t)16384*64*4);
  u16*   obf    = (u16*)proj;   // proj fully dead after scan pass2

  hipLaunchKernelGGL(concat_kernel, dim3(4096), dim3(256), 0, stream,
                     Wskew, Wk, Wv, Wq, Wbeta, Wo, Wh, Wl, WoT);
  hipLaunchKernelGGL(gemm_proj_kernel, dim3(128,7), dim3(256), 0, stream,
                     x, Wh, Wl, proj, bbeta);
  hipLaunchKernelGGL(expm_scan_kernel, dim3(4096), dim3(64), 0, stream, proj, OR);
  hipLaunchKernelGGL(chunkscan_kernel, dim3(64), dim3(64), 0, stream, OR, Rbase);
  hipLaunchKernelGGL(rotate_kvq_kernel, dim3(1024), dim3(256), 0, stream, OR, Rbase, proj);
  hipLaunchKernelGGL(scan_pass1_kernel, dim3(512), dim3(256), 0, stream, proj, Mbuf, wbuf);
  hipLaunchKernelGGL(scan_mid_kernel, dim3(64), dim3(512), 0, stream, Mbuf, wbuf, dstart);
  hipLaunchKernelGGL(scan_pass2_kernel, dim3(512), dim3(256), 0, stream, proj, dstart, oo);
  hipLaunchKernelGGL(rotout_kernel, dim3(1024), dim3(256), 0, stream, OR, Rbase, oo, obf);
  hipLaunchKernelGGL(gemm_out_kernel, dim3(128,8), dim3(256), 0, stream,
                     obf, WoT, (float*)d_out);
}